// Round 1
// baseline (1228.863 us; speedup 1.0000x reference)
//
#include <hip/hip_runtime.h>
#include <cstddef>

// ---------------------------------------------------------------------------
// _Mutilscal_MHSA fp32 baseline.
// Pipeline:
//  1. gemm_silu   : a01 = SiLU(s01*(w01 @ x)+b01)            [8,128,4096]  (a01 lives in d_out)
//  2. dwconv      : t_i = SiLU(s*(dwconv_dil{3,5,7}(a01))+b) [3][8,128,4096] (ws)
//  3. gemm3branch : B = sum_i SiLU(s_i3*(w_i3 @ t_i)+b_i3)   [8,512,4096]  (B lives in d_out)
//  4. gemm_pool   : pooled = blockmean4x4(SiLU(s3*(w3@B)+b3) * x)  [8,512,256] (atomicAdd, memset first)
//  5. gemm_silu   : kv = SiLU(skv*(wkv @ pooled)+bkv)        [8,1024,256]
//  6. gap / se    : gate = sigmoid(fc2(relu6(fc1(mean(x)))))  [8,512]
//  7. attn        : out = softmax(qk^T/8)@v + gate*x  (flash, fused final add)
// d_ws usage: 62,947,328 bytes (~60.03 MiB).
// ---------------------------------------------------------------------------

static __device__ __forceinline__ float silu_f(float v) {
  return v / (1.f + __expf(-v));
}

#define FMA16(ACC, W4, X4)                                                                     \
  ACC[0][0] += W4.x * X4.x; ACC[0][1] += W4.x * X4.y; ACC[0][2] += W4.x * X4.z; ACC[0][3] += W4.x * X4.w; \
  ACC[1][0] += W4.y * X4.x; ACC[1][1] += W4.y * X4.y; ACC[1][2] += W4.y * X4.z; ACC[1][3] += W4.y * X4.w; \
  ACC[2][0] += W4.z * X4.x; ACC[2][1] += W4.z * X4.y; ACC[2][2] += W4.z * X4.z; ACC[2][3] += W4.z * X4.w; \
  ACC[3][0] += W4.w * X4.x; ACC[3][1] += W4.w * X4.y; ACC[3][2] += W4.w * X4.z; ACC[3][3] += W4.w * X4.w;

// ---------------------------------------------------------------------------
// Generic fp32 GEMM (O[oc][p] = silu(sc*<W[oc,:],X[:,p]>+bi)) per batch.
// grid: (N/64, OC/64, B), block 256.  64x64 tile, 4x4 per thread, K-step 16.
__global__ __launch_bounds__(256)
void gemm_silu_kernel(const float* __restrict__ X, const float* __restrict__ W,
                      const float* __restrict__ sc, const float* __restrict__ bi,
                      float* __restrict__ O, int K, int OC, int N)
{
  const int b   = blockIdx.z;
  const int p0  = blockIdx.x * 64;
  const int oc0 = blockIdx.y * 64;
  const float* Xb = X + (size_t)b * K * N;
  float*       Ob = O + (size_t)b * OC * N;

  __shared__ float Xs [16][68];
  __shared__ float Wst[16][68];   // W transposed: Wst[k][oc]

  const int tid = threadIdx.x;
  const int tx = tid & 15, ty = tid >> 4;
  const int xr = tid >> 4, xc = (tid & 15) * 4;
  const int wo = tid >> 2, wk = (tid & 3) * 4;

  float acc[4][4] = {};

  for (int k0 = 0; k0 < K; k0 += 16) {
    const float4 xv = *reinterpret_cast<const float4*>(Xb + (size_t)(k0 + xr) * N + p0 + xc);
    const float4 wv = *reinterpret_cast<const float4*>(W + (size_t)(oc0 + wo) * K + k0 + wk);
    *reinterpret_cast<float4*>(&Xs[xr][xc]) = xv;
    Wst[wk + 0][wo] = wv.x;
    Wst[wk + 1][wo] = wv.y;
    Wst[wk + 2][wo] = wv.z;
    Wst[wk + 3][wo] = wv.w;
    __syncthreads();
#pragma unroll
    for (int k = 0; k < 16; ++k) {
      const float4 w4 = *reinterpret_cast<const float4*>(&Wst[k][ty * 4]);
      const float4 x4 = *reinterpret_cast<const float4*>(&Xs[k][tx * 4]);
      FMA16(acc, w4, x4)
    }
    __syncthreads();
  }
#pragma unroll
  for (int i = 0; i < 4; ++i) {
    const int oc = oc0 + ty * 4 + i;
    const float s = sc[oc], bb = bi[oc];
    float4 r;
    r.x = silu_f(s * acc[i][0] + bb);
    r.y = silu_f(s * acc[i][1] + bb);
    r.z = silu_f(s * acc[i][2] + bb);
    r.w = silu_f(s * acc[i][3] + bb);
    *reinterpret_cast<float4*>(Ob + (size_t)oc * N + p0 + tx * 4) = r;
  }
}

// ---------------------------------------------------------------------------
// Depthwise dilated 3x3 + SiLU, three branches (dil 3/5/7) selected by blockIdx.z.
// grid: (16, 8*128, 3), block 256. One thread per output pixel.
__global__ __launch_bounds__(256)
void dwconv_kernel(const float* __restrict__ A,
                   const float* __restrict__ w2a, const float* __restrict__ sa, const float* __restrict__ ba,
                   const float* __restrict__ w2b, const float* __restrict__ sb, const float* __restrict__ bb_,
                   const float* __restrict__ w2c, const float* __restrict__ sc_, const float* __restrict__ bc_)
{
  const int br = blockIdx.z;
  const int bc = blockIdx.y;               // b*128 + c
  const int c  = bc & 127;
  const int p  = blockIdx.x * 256 + threadIdx.x;
  const int y  = p >> 6, xx = p & 63;
  const int d  = 3 + 2 * br;

  const float* w = (br == 0 ? w2a : (br == 1 ? w2b : w2c)) + c * 9;
  const float  s = (br == 0 ? sa : (br == 1 ? sb : sc_))[c];
  const float bi = (br == 0 ? ba : (br == 1 ? bb_ : bc_))[c];

  const float* Ab = A + (size_t)bc * 4096;
  float sum = 0.f;
#pragma unroll
  for (int u = -1; u <= 1; ++u) {
    const int yy = y + u * d;
    if ((unsigned)yy < 64u) {
#pragma unroll
      for (int v = -1; v <= 1; ++v) {
        const int xv = xx + v * d;
        if ((unsigned)xv < 64u)
          sum += w[(u + 1) * 3 + (v + 1)] * Ab[yy * 64 + xv];
      }
    }
  }
  const float val = s * sum + bi;
  // T layout: [branch][b][c][p], written via dwconv_out pointer passed in A? ->
  // output pointer is global below (set via separate param) -- see launch.
  // (output pointer passed as w2c? no) -- we write through Tout:
  extern __shared__ float _unused[];  // (no LDS use)
  // Tout is provided via constant-folded pointer arithmetic in launch wrapper:
  // handled by dwconv_out global param below.
  // -- replaced: see dwconv_kernel2 signature note.
  // (This line never executes; real store in dwconv_kernel_out)
  ((float*)nullptr)[0] = val;  // placeholder -- overwritten by real kernel below
}

// Real depthwise kernel (with explicit output pointer).
__global__ __launch_bounds__(256)
void dwconv_out_kernel(const float* __restrict__ A, float* __restrict__ Tout,
                       const float* __restrict__ w2a, const float* __restrict__ sa, const float* __restrict__ ba,
                       const float* __restrict__ w2b, const float* __restrict__ sb, const float* __restrict__ bb_,
                       const float* __restrict__ w2c, const float* __restrict__ sc_, const float* __restrict__ bc_)
{
  const int br = blockIdx.z;
  const int bc = blockIdx.y;               // b*128 + c
  const int c  = bc & 127;
  const int p  = blockIdx.x * 256 + threadIdx.x;
  const int y  = p >> 6, xx = p & 63;
  const int d  = 3 + 2 * br;

  const float* w = (br == 0 ? w2a : (br == 1 ? w2b : w2c)) + c * 9;
  const float  s = (br == 0 ? sa : (br == 1 ? sb : sc_))[c];
  const float bi = (br == 0 ? ba : (br == 1 ? bb_ : bc_))[c];

  const float* Ab = A + (size_t)bc * 4096;
  float sum = 0.f;
#pragma unroll
  for (int u = -1; u <= 1; ++u) {
    const int yy = y + u * d;
    if ((unsigned)yy < 64u) {
#pragma unroll
      for (int v = -1; v <= 1; ++v) {
        const int xv = xx + v * d;
        if ((unsigned)xv < 64u)
          sum += w[(u + 1) * 3 + (v + 1)] * Ab[yy * 64 + xv];
      }
    }
  }
  const float val = s * sum + bi;
  Tout[(size_t)br * (8ull * 128 * 4096) + (size_t)bc * 4096 + p] = silu_f(val);
}

// ---------------------------------------------------------------------------
// Three-branch 128->512 GEMM: B = sum_i silu(s_i*(W_i @ t_i)+b_i).
// grid: (64, 8, 8), block 256.
__global__ __launch_bounds__(256)
void gemm3branch_kernel(const float* __restrict__ T,
                        const float* __restrict__ W0, const float* __restrict__ W1, const float* __restrict__ W2,
                        const float* __restrict__ s0, const float* __restrict__ s1, const float* __restrict__ s2,
                        const float* __restrict__ b0, const float* __restrict__ b1, const float* __restrict__ b2,
                        float* __restrict__ Bout)
{
  const int b = blockIdx.z, p0 = blockIdx.x * 64, oc0 = blockIdx.y * 64;
  const size_t TB = (size_t)8 * 128 * 4096;

  __shared__ float Xs [3][16][68];
  __shared__ float Wst[3][16][68];

  const int tid = threadIdx.x, tx = tid & 15, ty = tid >> 4;
  const int xr = tid >> 4, xc = (tid & 15) * 4;
  const int wo = tid >> 2, wk = (tid & 3) * 4;
  const float* Wp[3] = {W0, W1, W2};

  float acc[3][4][4] = {};

  for (int k0 = 0; k0 < 128; k0 += 16) {
#pragma unroll
    for (int brn = 0; brn < 3; ++brn) {
      const float* Xb = T + brn * TB + (size_t)b * 128 * 4096;
      const float4 xv = *reinterpret_cast<const float4*>(Xb + (size_t)(k0 + xr) * 4096 + p0 + xc);
      const float4 wv = *reinterpret_cast<const float4*>(Wp[brn] + (size_t)(oc0 + wo) * 128 + k0 + wk);
      *reinterpret_cast<float4*>(&Xs[brn][xr][xc]) = xv;
      Wst[brn][wk + 0][wo] = wv.x;
      Wst[brn][wk + 1][wo] = wv.y;
      Wst[brn][wk + 2][wo] = wv.z;
      Wst[brn][wk + 3][wo] = wv.w;
    }
    __syncthreads();
#pragma unroll
    for (int k = 0; k < 16; ++k) {
#pragma unroll
      for (int brn = 0; brn < 3; ++brn) {
        const float4 w4 = *reinterpret_cast<const float4*>(&Wst[brn][k][ty * 4]);
        const float4 x4 = *reinterpret_cast<const float4*>(&Xs[brn][k][tx * 4]);
        FMA16(acc[brn], w4, x4)
      }
    }
    __syncthreads();
  }
#pragma unroll
  for (int i = 0; i < 4; ++i) {
    const int oc = oc0 + ty * 4 + i;
    const float sA = s0[oc], bA = b0[oc];
    const float sB = s1[oc], bB = b1[oc];
    const float sC = s2[oc], bC = b2[oc];
    float4 r;
    r.x = silu_f(sA * acc[0][i][0] + bA) + silu_f(sB * acc[1][i][0] + bB) + silu_f(sC * acc[2][i][0] + bC);
    r.y = silu_f(sA * acc[0][i][1] + bA) + silu_f(sB * acc[1][i][1] + bB) + silu_f(sC * acc[2][i][1] + bC);
    r.z = silu_f(sA * acc[0][i][2] + bA) + silu_f(sB * acc[1][i][2] + bB) + silu_f(sC * acc[2][i][2] + bC);
    r.w = silu_f(sA * acc[0][i][3] + bA) + silu_f(sB * acc[1][i][3] + bB) + silu_f(sC * acc[2][i][3] + bC);
    *reinterpret_cast<float4*>(Bout + ((size_t)b * 512 + oc) * 4096 + p0 + tx * 4) = r;
  }
}

// ---------------------------------------------------------------------------
// w3 GEMM (512->512) with fused attn=silu(..)*x and 4x4 block-mean pooling.
// Never materializes attn. grid: (64, 8, 8) -- blockIdx.x is the image row.
__global__ __launch_bounds__(256)
void gemm_pool_kernel(const float* __restrict__ X, const float* __restrict__ W,
                      const float* __restrict__ sc, const float* __restrict__ bi,
                      const float* __restrict__ xin, float* __restrict__ pooled)
{
  const int b   = blockIdx.z;
  const int y   = blockIdx.x;          // image row 0..63
  const int p0  = y * 64;
  const int oc0 = blockIdx.y * 64;
  const float* Xb = X + (size_t)b * 512 * 4096;

  __shared__ float Xs [16][68];
  __shared__ float Wst[16][68];

  const int tid = threadIdx.x;
  const int tx = tid & 15, ty = tid >> 4;
  const int xr = tid >> 4, xc = (tid & 15) * 4;
  const int wo = tid >> 2, wk = (tid & 3) * 4;

  float acc[4][4] = {};

  for (int k0 = 0; k0 < 512; k0 += 16) {
    const float4 xv = *reinterpret_cast<const float4*>(Xb + (size_t)(k0 + xr) * 4096 + p0 + xc);
    const float4 wv = *reinterpret_cast<const float4*>(W + (size_t)(oc0 + wo) * 512 + k0 + wk);
    *reinterpret_cast<float4*>(&Xs[xr][xc]) = xv;
    Wst[wk + 0][wo] = wv.x;
    Wst[wk + 1][wo] = wv.y;
    Wst[wk + 2][wo] = wv.z;
    Wst[wk + 3][wo] = wv.w;
    __syncthreads();
#pragma unroll
    for (int k = 0; k < 16; ++k) {
      const float4 w4 = *reinterpret_cast<const float4*>(&Wst[k][ty * 4]);
      const float4 x4 = *reinterpret_cast<const float4*>(&Xs[k][tx * 4]);
      FMA16(acc, w4, x4)
    }
    __syncthreads();
  }

  const int ph = y >> 2;
  const int pw = tx;                    // thread's 4 pixels = one pool column
#pragma unroll
  for (int i = 0; i < 4; ++i) {
    const int oc = oc0 + ty * 4 + i;
    const float s = sc[oc], bb = bi[oc];
    const float* xp = xin + ((size_t)b * 512 + oc) * 4096 + (size_t)y * 64 + tx * 4;
    float sum = 0.f;
#pragma unroll
    for (int j = 0; j < 4; ++j)
      sum += silu_f(s * acc[i][j] + bb) * xp[j];
    atomicAdd(&pooled[((size_t)b * 512 + oc) * 256 + ph * 16 + pw], sum * (1.f / 16.f));
  }
}

// ---------------------------------------------------------------------------
// Global average pool of x over spatial. grid 8*512 blocks x 256 threads.
__global__ __launch_bounds__(256)
void gap_kernel(const float* __restrict__ x, float* __restrict__ gap)
{
  const int bc = blockIdx.x;
  const int tid = threadIdx.x;
  const float* p = x + (size_t)bc * 4096;
  float v = 0.f;
#pragma unroll
  for (int j = 0; j < 16; ++j) v += p[j * 256 + tid];
#pragma unroll
  for (int off = 32; off >= 1; off >>= 1) v += __shfl_down(v, off, 64);
  __shared__ float red[4];
  if ((tid & 63) == 0) red[tid >> 6] = v;
  __syncthreads();
  if (tid == 0) gap[bc] = (red[0] + red[1] + red[2] + red[3]) * (1.f / 4096.f);
}

// ---------------------------------------------------------------------------
// SE: y = relu6(gap@fc1^T+b1); gate = sigmoid(y@fc2^T+b2). grid 8 x 512 thr.
__global__ __launch_bounds__(512)
void se_kernel(const float* __restrict__ gap,
               const float* __restrict__ wfc1, const float* __restrict__ bfc1,
               const float* __restrict__ wfc2, const float* __restrict__ bfc2,
               float* __restrict__ gate)
{
  const int b = blockIdx.x, tid = threadIdx.x;
  __shared__ float ylds[128];
  if (tid < 128) {
    float a = 0.f;
    for (int c = 0; c < 512; ++c) a += gap[b * 512 + c] * wfc1[tid * 512 + c];
    a += bfc1[tid];
    ylds[tid] = fminf(fmaxf(a, 0.f), 6.f);
  }
  __syncthreads();
  float g = 0.f;
  for (int j = 0; j < 128; ++j) g += ylds[j] * wfc2[tid * 128 + j];
  g += bfc2[tid];
  gate[b * 512 + tid] = 1.f / (1.f + __expf(-g));
}

// ---------------------------------------------------------------------------
// Flash-style pooled cross-attention + fused SE residual epilogue.
// q = x rows; k/v from kv (channels [0,512) and [512,1024)).
// grid (16, 8, 8): (n-chunk, head, batch). One row per thread, online softmax,
// K/V staged in LDS in 64-wide m chunks. out = o/l + gate*q.
__global__ __launch_bounds__(256)
void attn_kernel(const float* __restrict__ x, const float* __restrict__ kv,
                 const float* __restrict__ gate, float* __restrict__ out)
{
  const int b = blockIdx.z, h = blockIdx.y;
  const int tid = threadIdx.x;
  const int n = blockIdx.x * 256 + tid;

  __shared__ float Ks[64][68];
  __shared__ float Vs[64][68];

  float q[64], o[64];
  const size_t xbase = ((size_t)b * 512 + h * 64) * 4096 + n;
#pragma unroll
  for (int d = 0; d < 64; ++d) { q[d] = x[xbase + (size_t)d * 4096]; o[d] = 0.f; }

  float mx = -3.0e38f, l = 0.f;
  const int mc_l = tid & 63, dg = tid >> 6;
  const size_t kbase = ((size_t)b * 1024 + h * 64) * 256;
  const size_t vbase = ((size_t)b * 1024 + 512 + h * 64) * 256;

  for (int chunk = 0; chunk < 4; ++chunk) {
    const int m0 = chunk * 64;
    __syncthreads();
#pragma unroll
    for (int j = 0; j < 16; ++j) {
      const int d = dg * 16 + j;
      Ks[mc_l][d] = kv[kbase + (size_t)d * 256 + m0 + mc_l];
      Vs[mc_l][d] = kv[vbase + (size_t)d * 256 + m0 + mc_l];
    }
    __syncthreads();
    for (int mc = 0; mc < 64; ++mc) {
      float dot = 0.f;
#pragma unroll
      for (int d4 = 0; d4 < 64; d4 += 4) {
        const float4 k4 = *reinterpret_cast<const float4*>(&Ks[mc][d4]);
        dot += q[d4] * k4.x + q[d4 + 1] * k4.y + q[d4 + 2] * k4.z + q[d4 + 3] * k4.w;
      }
      const float pm = dot * 0.125f;                 // SCALE = 64^-0.5
      const float nm = fmaxf(mx, pm);
      const float corr = __expf(mx - nm);
      const float ex = __expf(pm - nm);
      l = l * corr + ex;
      mx = nm;
#pragma unroll
      for (int d4 = 0; d4 < 64; d4 += 4) {
        const float4 v4 = *reinterpret_cast<const float4*>(&Vs[mc][d4]);
        o[d4]     = o[d4]     * corr + ex * v4.x;
        o[d4 + 1] = o[d4 + 1] * corr + ex * v4.y;
        o[d4 + 2] = o[d4 + 2] * corr + ex * v4.z;
        o[d4 + 3] = o[d4 + 3] * corr + ex * v4.w;
      }
    }
  }
  const float inv = 1.f / l;
#pragma unroll
  for (int d = 0; d < 64; ++d) {
    const float g = gate[b * 512 + h * 64 + d];
    out[xbase + (size_t)d * 4096] = o[d] * inv + g * q[d];
  }
}

// ---------------------------------------------------------------------------
extern "C" void kernel_launch(void* const* d_in, const int* in_sizes, int n_in,
                              void* d_out, int out_size, void* d_ws, size_t ws_size,
                              hipStream_t stream)
{
  const float* x    = (const float*)d_in[0];
  const float* w01  = (const float*)d_in[1];
  const float* s01  = (const float*)d_in[2];
  const float* b01  = (const float*)d_in[3];
  const float* w02  = (const float*)d_in[4];
  const float* s02  = (const float*)d_in[5];
  const float* b02  = (const float*)d_in[6];
  const float* w03  = (const float*)d_in[7];
  const float* s03  = (const float*)d_in[8];
  const float* b03  = (const float*)d_in[9];
  const float* w12  = (const float*)d_in[10];
  const float* s12  = (const float*)d_in[11];
  const float* b12  = (const float*)d_in[12];
  const float* w13  = (const float*)d_in[13];
  const float* s13  = (const float*)d_in[14];
  const float* b13  = (const float*)d_in[15];
  const float* w22  = (const float*)d_in[16];
  const float* s22  = (const float*)d_in[17];
  const float* b22  = (const float*)d_in[18];
  const float* w23  = (const float*)d_in[19];
  const float* s23  = (const float*)d_in[20];
  const float* b23  = (const float*)d_in[21];
  const float* w3   = (const float*)d_in[22];
  const float* s3   = (const float*)d_in[23];
  const float* b3   = (const float*)d_in[24];
  const float* wkv  = (const float*)d_in[25];
  const float* skv  = (const float*)d_in[26];
  const float* bkv  = (const float*)d_in[27];
  const float* wfc1 = (const float*)d_in[28];
  const float* bfc1 = (const float*)d_in[29];
  const float* wfc2 = (const float*)d_in[30];
  const float* bfc2 = (const float*)d_in[31];

  float* out = (float*)d_out;
  float* wsf = (float*)d_ws;

  // workspace layout (floats):
  float* T      = wsf;                 // 3*8*128*4096 = 12,582,912
  float* pooled = wsf + 12582912;      // 8*512*256    =  1,048,576
  float* kvbuf  = wsf + 13631488;      // 8*1024*256   =  2,097,152
  float* gapb   = wsf + 15728640;      // 4096
  float* gateb  = wsf + 15732736;      // 4096  (end: 15,736,832 floats = 60.03 MiB)

  // a01 and B alias d_out at disjoint lifetimes:
  float* a01 = out;   // [8,128,4096], dead once T is built
  float* B   = out;   // [8,512,4096], dead once pooled is built

  // 1. a01 = silu(s01*(w01@x)+b01)
  gemm_silu_kernel<<<dim3(64, 2, 8), 256, 0, stream>>>(x, w01, s01, b01, a01, 512, 128, 4096);
  // 2. depthwise dilated branches
  dwconv_out_kernel<<<dim3(16, 1024, 3), 256, 0, stream>>>(a01, T,
      w02, s02, b02, w12, s12, b12, w22, s22, b22);
  // 3. B = sum of three 128->512 CBS branches (overwrites a01 region of d_out)
  gemm3branch_kernel<<<dim3(64, 8, 8), 256, 0, stream>>>(T, w03, w13, w23,
      s03, s13, s23, b03, b13, b23, B);
  // 4. pooled = blockmean(silu(s3*(w3@B)+b3) * x)
  hipMemsetAsync(pooled, 0, (size_t)1048576 * sizeof(float), stream);
  gemm_pool_kernel<<<dim3(64, 8, 8), 256, 0, stream>>>(B, w3, s3, b3, x, pooled);
  // 5. kv = silu(skv*(wkv@pooled)+bkv)
  gemm_silu_kernel<<<dim3(4, 16, 8), 256, 0, stream>>>(pooled, wkv, skv, bkv, kvbuf, 512, 1024, 256);
  // 6. SE gate
  gap_kernel<<<4096, 256, 0, stream>>>(x, gapb);
  se_kernel<<<8, 512, 0, stream>>>(gapb, wfc1, bfc1, wfc2, bfc2, gateb);
  // 7. attention + gate*x residual -> final output
  attn_kernel<<<dim3(16, 8, 8), 256, 0, stream>>>(x, kvbuf, gateb, out);
}

// Round 2
// 728.398 us; speedup vs baseline: 1.6871x; 1.6871x over previous
//
#include <hip/hip_runtime.h>
#include <cstddef>

// ---------------------------------------------------------------------------
// _Mutilscal_MHSA — round 2: MFMA bf16 attention (swapped-QK^T, lane-local
// softmax, P-in-register PV), rest of pipeline unchanged fp32.
// ---------------------------------------------------------------------------

static __device__ __forceinline__ float silu_f(float v) {
  return v / (1.f + __expf(-v));
}

typedef __attribute__((ext_vector_type(8))) short short8v;   // bf16x8 frag (4 VGPR)
typedef __attribute__((ext_vector_type(4))) float f32x4;     // MFMA acc

union FragU { unsigned u[4]; short8v v; };

static __device__ __forceinline__ unsigned short f2bf(float f) {
  unsigned u = __builtin_bit_cast(unsigned, f);
  u += 0x7fffu + ((u >> 16) & 1u);           // round-to-nearest-even
  return (unsigned short)(u >> 16);
}
static __device__ __forceinline__ unsigned packbf(float lo, float hi) {
  return (unsigned)f2bf(lo) | ((unsigned)f2bf(hi) << 16);
}

#define FMA16(ACC, W4, X4)                                                                     \
  ACC[0][0] += W4.x * X4.x; ACC[0][1] += W4.x * X4.y; ACC[0][2] += W4.x * X4.z; ACC[0][3] += W4.x * X4.w; \
  ACC[1][0] += W4.y * X4.x; ACC[1][1] += W4.y * X4.y; ACC[1][2] += W4.y * X4.z; ACC[1][3] += W4.y * X4.w; \
  ACC[2][0] += W4.z * X4.x; ACC[2][1] += W4.z * X4.y; ACC[2][2] += W4.z * X4.z; ACC[2][3] += W4.z * X4.w; \
  ACC[3][0] += W4.w * X4.x; ACC[3][1] += W4.w * X4.y; ACC[3][2] += W4.w * X4.z; ACC[3][3] += W4.w * X4.w;

// ---------------------------------------------------------------------------
// Generic fp32 GEMM (O[oc][p] = silu(sc*<W[oc,:],X[:,p]>+bi)) per batch.
__global__ __launch_bounds__(256)
void gemm_silu_kernel(const float* __restrict__ X, const float* __restrict__ W,
                      const float* __restrict__ sc, const float* __restrict__ bi,
                      float* __restrict__ O, int K, int OC, int N)
{
  const int b   = blockIdx.z;
  const int p0  = blockIdx.x * 64;
  const int oc0 = blockIdx.y * 64;
  const float* Xb = X + (size_t)b * K * N;
  float*       Ob = O + (size_t)b * OC * N;

  __shared__ float Xs [16][68];
  __shared__ float Wst[16][68];

  const int tid = threadIdx.x;
  const int tx = tid & 15, ty = tid >> 4;
  const int xr = tid >> 4, xc = (tid & 15) * 4;
  const int wo = tid >> 2, wk = (tid & 3) * 4;

  float acc[4][4] = {};

  for (int k0 = 0; k0 < K; k0 += 16) {
    const float4 xv = *reinterpret_cast<const float4*>(Xb + (size_t)(k0 + xr) * N + p0 + xc);
    const float4 wv = *reinterpret_cast<const float4*>(W + (size_t)(oc0 + wo) * K + k0 + wk);
    *reinterpret_cast<float4*>(&Xs[xr][xc]) = xv;
    Wst[wk + 0][wo] = wv.x;
    Wst[wk + 1][wo] = wv.y;
    Wst[wk + 2][wo] = wv.z;
    Wst[wk + 3][wo] = wv.w;
    __syncthreads();
#pragma unroll
    for (int k = 0; k < 16; ++k) {
      const float4 w4 = *reinterpret_cast<const float4*>(&Wst[k][ty * 4]);
      const float4 x4 = *reinterpret_cast<const float4*>(&Xs[k][tx * 4]);
      FMA16(acc, w4, x4)
    }
    __syncthreads();
  }
#pragma unroll
  for (int i = 0; i < 4; ++i) {
    const int oc = oc0 + ty * 4 + i;
    const float s = sc[oc], bb = bi[oc];
    float4 r;
    r.x = silu_f(s * acc[i][0] + bb);
    r.y = silu_f(s * acc[i][1] + bb);
    r.z = silu_f(s * acc[i][2] + bb);
    r.w = silu_f(s * acc[i][3] + bb);
    *reinterpret_cast<float4*>(Ob + (size_t)oc * N + p0 + tx * 4) = r;
  }
}

// ---------------------------------------------------------------------------
// Depthwise dilated 3x3 + SiLU (dil 3/5/7 by blockIdx.z).
__global__ __launch_bounds__(256)
void dwconv_out_kernel(const float* __restrict__ A, float* __restrict__ Tout,
                       const float* __restrict__ w2a, const float* __restrict__ sa, const float* __restrict__ ba,
                       const float* __restrict__ w2b, const float* __restrict__ sb, const float* __restrict__ bb_,
                       const float* __restrict__ w2c, const float* __restrict__ sc_, const float* __restrict__ bc_)
{
  const int br = blockIdx.z;
  const int bc = blockIdx.y;               // b*128 + c
  const int c  = bc & 127;
  const int p  = blockIdx.x * 256 + threadIdx.x;
  const int y  = p >> 6, xx = p & 63;
  const int d  = 3 + 2 * br;

  const float* w = (br == 0 ? w2a : (br == 1 ? w2b : w2c)) + c * 9;
  const float  s = (br == 0 ? sa : (br == 1 ? sb : sc_))[c];
  const float bi = (br == 0 ? ba : (br == 1 ? bb_ : bc_))[c];

  const float* Ab = A + (size_t)bc * 4096;
  float sum = 0.f;
#pragma unroll
  for (int u = -1; u <= 1; ++u) {
    const int yy = y + u * d;
    if ((unsigned)yy < 64u) {
#pragma unroll
      for (int v = -1; v <= 1; ++v) {
        const int xv = xx + v * d;
        if ((unsigned)xv < 64u)
          sum += w[(u + 1) * 3 + (v + 1)] * Ab[yy * 64 + xv];
      }
    }
  }
  const float val = s * sum + bi;
  Tout[(size_t)br * (8ull * 128 * 4096) + (size_t)bc * 4096 + p] = silu_f(val);
}

// ---------------------------------------------------------------------------
// Three-branch 128->512 GEMM: B = sum_i silu(s_i*(W_i @ t_i)+b_i).
__global__ __launch_bounds__(256)
void gemm3branch_kernel(const float* __restrict__ T,
                        const float* __restrict__ W0, const float* __restrict__ W1, const float* __restrict__ W2,
                        const float* __restrict__ s0, const float* __restrict__ s1, const float* __restrict__ s2,
                        const float* __restrict__ b0, const float* __restrict__ b1, const float* __restrict__ b2,
                        float* __restrict__ Bout)
{
  const int b = blockIdx.z, p0 = blockIdx.x * 64, oc0 = blockIdx.y * 64;
  const size_t TB = (size_t)8 * 128 * 4096;

  __shared__ float Xs [3][16][68];
  __shared__ float Wst[3][16][68];

  const int tid = threadIdx.x, tx = tid & 15, ty = tid >> 4;
  const int xr = tid >> 4, xc = (tid & 15) * 4;
  const int wo = tid >> 2, wk = (tid & 3) * 4;
  const float* Wp[3] = {W0, W1, W2};

  float acc[3][4][4] = {};

  for (int k0 = 0; k0 < 128; k0 += 16) {
#pragma unroll
    for (int brn = 0; brn < 3; ++brn) {
      const float* Xb = T + brn * TB + (size_t)b * 128 * 4096;
      const float4 xv = *reinterpret_cast<const float4*>(Xb + (size_t)(k0 + xr) * 4096 + p0 + xc);
      const float4 wv = *reinterpret_cast<const float4*>(Wp[brn] + (size_t)(oc0 + wo) * 128 + k0 + wk);
      *reinterpret_cast<float4*>(&Xs[brn][xr][xc]) = xv;
      Wst[brn][wk + 0][wo] = wv.x;
      Wst[brn][wk + 1][wo] = wv.y;
      Wst[brn][wk + 2][wo] = wv.z;
      Wst[brn][wk + 3][wo] = wv.w;
    }
    __syncthreads();
#pragma unroll
    for (int k = 0; k < 16; ++k) {
#pragma unroll
      for (int brn = 0; brn < 3; ++brn) {
        const float4 w4 = *reinterpret_cast<const float4*>(&Wst[brn][k][ty * 4]);
        const float4 x4 = *reinterpret_cast<const float4*>(&Xs[brn][k][tx * 4]);
        FMA16(acc[brn], w4, x4)
      }
    }
    __syncthreads();
  }
#pragma unroll
  for (int i = 0; i < 4; ++i) {
    const int oc = oc0 + ty * 4 + i;
    const float sA = s0[oc], bA = b0[oc];
    const float sB = s1[oc], bB = b1[oc];
    const float sC = s2[oc], bC = b2[oc];
    float4 r;
    r.x = silu_f(sA * acc[0][i][0] + bA) + silu_f(sB * acc[1][i][0] + bB) + silu_f(sC * acc[2][i][0] + bC);
    r.y = silu_f(sA * acc[0][i][1] + bA) + silu_f(sB * acc[1][i][1] + bB) + silu_f(sC * acc[2][i][1] + bC);
    r.z = silu_f(sA * acc[0][i][2] + bA) + silu_f(sB * acc[1][i][2] + bB) + silu_f(sC * acc[2][i][2] + bC);
    r.w = silu_f(sA * acc[0][i][3] + bA) + silu_f(sB * acc[1][i][3] + bB) + silu_f(sC * acc[2][i][3] + bC);
    *reinterpret_cast<float4*>(Bout + ((size_t)b * 512 + oc) * 4096 + p0 + tx * 4) = r;
  }
}

// ---------------------------------------------------------------------------
// w3 GEMM (512->512) with fused attn=silu(..)*x and 4x4 block-mean pooling.
__global__ __launch_bounds__(256)
void gemm_pool_kernel(const float* __restrict__ X, const float* __restrict__ W,
                      const float* __restrict__ sc, const float* __restrict__ bi,
                      const float* __restrict__ xin, float* __restrict__ pooled)
{
  const int b   = blockIdx.z;
  const int y   = blockIdx.x;          // image row 0..63
  const int p0  = y * 64;
  const int oc0 = blockIdx.y * 64;
  const float* Xb = X + (size_t)b * 512 * 4096;

  __shared__ float Xs [16][68];
  __shared__ float Wst[16][68];

  const int tid = threadIdx.x;
  const int tx = tid & 15, ty = tid >> 4;
  const int xr = tid >> 4, xc = (tid & 15) * 4;
  const int wo = tid >> 2, wk = (tid & 3) * 4;

  float acc[4][4] = {};

  for (int k0 = 0; k0 < 512; k0 += 16) {
    const float4 xv = *reinterpret_cast<const float4*>(Xb + (size_t)(k0 + xr) * 4096 + p0 + xc);
    const float4 wv = *reinterpret_cast<const float4*>(W + (size_t)(oc0 + wo) * 512 + k0 + wk);
    *reinterpret_cast<float4*>(&Xs[xr][xc]) = xv;
    Wst[wk + 0][wo] = wv.x;
    Wst[wk + 1][wo] = wv.y;
    Wst[wk + 2][wo] = wv.z;
    Wst[wk + 3][wo] = wv.w;
    __syncthreads();
#pragma unroll
    for (int k = 0; k < 16; ++k) {
      const float4 w4 = *reinterpret_cast<const float4*>(&Wst[k][ty * 4]);
      const float4 x4 = *reinterpret_cast<const float4*>(&Xs[k][tx * 4]);
      FMA16(acc, w4, x4)
    }
    __syncthreads();
  }

  const int ph = y >> 2;
  const int pw = tx;
#pragma unroll
  for (int i = 0; i < 4; ++i) {
    const int oc = oc0 + ty * 4 + i;
    const float s = sc[oc], bb = bi[oc];
    const float* xp = xin + ((size_t)b * 512 + oc) * 4096 + (size_t)y * 64 + tx * 4;
    float sum = 0.f;
#pragma unroll
    for (int j = 0; j < 4; ++j)
      sum += silu_f(s * acc[i][j] + bb) * xp[j];
    atomicAdd(&pooled[((size_t)b * 512 + oc) * 256 + ph * 16 + pw], sum * (1.f / 16.f));
  }
}

// ---------------------------------------------------------------------------
__global__ __launch_bounds__(256)
void gap_kernel(const float* __restrict__ x, float* __restrict__ gap)
{
  const int bc = blockIdx.x;
  const int tid = threadIdx.x;
  const float* p = x + (size_t)bc * 4096;
  float v = 0.f;
#pragma unroll
  for (int j = 0; j < 16; ++j) v += p[j * 256 + tid];
#pragma unroll
  for (int off = 32; off >= 1; off >>= 1) v += __shfl_down(v, off, 64);
  __shared__ float red[4];
  if ((tid & 63) == 0) red[tid >> 6] = v;
  __syncthreads();
  if (tid == 0) gap[bc] = (red[0] + red[1] + red[2] + red[3]) * (1.f / 4096.f);
}

// ---------------------------------------------------------------------------
__global__ __launch_bounds__(512)
void se_kernel(const float* __restrict__ gap,
               const float* __restrict__ wfc1, const float* __restrict__ bfc1,
               const float* __restrict__ wfc2, const float* __restrict__ bfc2,
               float* __restrict__ gate)
{
  const int b = blockIdx.x, tid = threadIdx.x;
  __shared__ float ylds[128];
  if (tid < 128) {
    float a = 0.f;
    for (int c = 0; c < 512; ++c) a += gap[b * 512 + c] * wfc1[tid * 512 + c];
    a += bfc1[tid];
    ylds[tid] = fminf(fmaxf(a, 0.f), 6.f);
  }
  __syncthreads();
  float g = 0.f;
  for (int j = 0; j < 128; ++j) g += ylds[j] * wfc2[tid * 128 + j];
  g += bfc2[tid];
  gate[b * 512 + tid] = 1.f / (1.f + __expf(-g));
}

// ---------------------------------------------------------------------------
// MFMA bf16 attention, swapped-QK^T (S^T = K.Q^T so each lane owns one q-row):
//  - softmax = lane-local VALU + 2x shfl_xor (across the 4 16-lane groups)
//  - P stays in registers and feeds PV's B-fragment directly
//  - LDS: packed bf16-pair layout [k/4][pos][2] u32, coalesced staged from the
//    natural feature-major global layout, conflict-free(2-way) b64 frag reads.
// Block: 128 q-rows, 8 waves (wave w owns q-cols w*16..w*16+15), keys in 2
// chunks of 128 with online rescale. Epilogue fuses out = O/l + gate*x.
// mfma_f32_16x16x32_bf16: A/B lane l elem e -> k = 4*(l>>4)+(e&3)+16*(e>>2),
// row/col = l&15; C/D: col = l&15, row = 4*(l>>4)+reg.
__global__ __launch_bounds__(512)
void attn_mfma_kernel(const float* __restrict__ x, const float* __restrict__ kv,
                      const float* __restrict__ gate, float* __restrict__ out)
{
  const int b = blockIdx.z, h = blockIdx.y;
  const int n0 = blockIdx.x * 128;
  const int tid = threadIdx.x;
  const int w = tid >> 6, lane = tid & 63;
  const int g = lane >> 4, nl = lane & 15;

  // Kp [16][132][2], Qp [16][132][2], Vp [32][66][2]  (u32 words)
  __shared__ unsigned lds[16 * 132 * 2 * 2 + 32 * 66 * 2];
  unsigned* Kp = lds;
  unsigned* Qp = lds + 16 * 132 * 2;
  unsigned* Vp = lds + 2 * 16 * 132 * 2;
  float* Osm = (float*)lds;            // [64][130] overlay on Kp+Qp (8448 w)

  const size_t xbh = ((size_t)b * 512 + h * 64) * 4096 + n0;
  const size_t kbh = ((size_t)b * 1024 + h * 64) * 256;
  const size_t vbh = ((size_t)b * 1024 + 512 + h * 64) * 256;

  // ---- stage Q once (scaled by SCALE=0.125), packed d-pairs -------------
  {
    const int dq = tid >> 5, nq = (tid & 31) * 4;
    const float4 r0 = *(const float4*)(x + xbh + (size_t)(4 * dq + 0) * 4096 + nq);
    const float4 r1 = *(const float4*)(x + xbh + (size_t)(4 * dq + 1) * 4096 + nq);
    const float4 r2 = *(const float4*)(x + xbh + (size_t)(4 * dq + 2) * 4096 + nq);
    const float4 r3 = *(const float4*)(x + xbh + (size_t)(4 * dq + 3) * 4096 + nq);
    const float sc = 0.125f;
    uint4 w0, w1;
    w0.x = packbf(r0.x * sc, r1.x * sc); w0.y = packbf(r2.x * sc, r3.x * sc);
    w0.z = packbf(r0.y * sc, r1.y * sc); w0.w = packbf(r2.y * sc, r3.y * sc);
    w1.x = packbf(r0.z * sc, r1.z * sc); w1.y = packbf(r2.z * sc, r3.z * sc);
    w1.z = packbf(r0.w * sc, r1.w * sc); w1.w = packbf(r2.w * sc, r3.w * sc);
    *(uint4*)(Qp + (dq * 132 + nq) * 2)     = w0;
    *(uint4*)(Qp + (dq * 132 + nq + 2) * 2) = w1;
  }

  float m_run = -1e30f, l_run = 0.f;
  f32x4 o[4];
#pragma unroll
  for (int i = 0; i < 4; ++i) o[i] = (f32x4){0.f, 0.f, 0.f, 0.f};

#pragma unroll
  for (int ch = 0; ch < 2; ++ch) {
    const int m0 = ch * 128;
    __syncthreads();
    // ---- stage K chunk (packed d-pairs) ----
    {
      const int dq = tid >> 5, mq = (tid & 31) * 4;
      const float4 r0 = *(const float4*)(kv + kbh + (size_t)(4 * dq + 0) * 256 + m0 + mq);
      const float4 r1 = *(const float4*)(kv + kbh + (size_t)(4 * dq + 1) * 256 + m0 + mq);
      const float4 r2 = *(const float4*)(kv + kbh + (size_t)(4 * dq + 2) * 256 + m0 + mq);
      const float4 r3 = *(const float4*)(kv + kbh + (size_t)(4 * dq + 3) * 256 + m0 + mq);
      uint4 w0, w1;
      w0.x = packbf(r0.x, r1.x); w0.y = packbf(r2.x, r3.x);
      w0.z = packbf(r0.y, r1.y); w0.w = packbf(r2.y, r3.y);
      w1.x = packbf(r0.z, r1.z); w1.y = packbf(r2.z, r3.z);
      w1.z = packbf(r0.w, r1.w); w1.w = packbf(r2.w, r3.w);
      *(uint4*)(Kp + (dq * 132 + mq) * 2)     = w0;
      *(uint4*)(Kp + (dq * 132 + mq + 2) * 2) = w1;
    }
    // ---- stage V chunk (packed m-pairs): Vp[m>>2][d][(m>>1)&1] ----
    {
      const int mq = (tid & 31) * 4;
#pragma unroll
      for (int p = 0; p < 4; ++p) {
        const int d = (tid >> 5) + 16 * p;
        const float4 vv = *(const float4*)(kv + vbh + (size_t)d * 256 + m0 + mq);
        uint2 wv;
        wv.x = packbf(vv.x, vv.y);
        wv.y = packbf(vv.z, vv.w);
        *(uint2*)(Vp + ((mq >> 2) * 66 + d) * 2) = wv;
      }
    }
    __syncthreads();

    // ---- S^T = K . Q^T  (per wave: 128 keys x 16 q-cols) ----
    f32x4 s[8];
#pragma unroll
    for (int mb = 0; mb < 8; ++mb) s[mb] = (f32x4){0.f, 0.f, 0.f, 0.f};
#pragma unroll
    for (int ks = 0; ks < 2; ++ks) {
      FragU qf;
      {
        const uint2 lo = *(const uint2*)(Qp + ((8 * ks + g) * 132 + w * 16 + nl) * 2);
        const uint2 hi = *(const uint2*)(Qp + ((8 * ks + 4 + g) * 132 + w * 16 + nl) * 2);
        qf.u[0] = lo.x; qf.u[1] = lo.y; qf.u[2] = hi.x; qf.u[3] = hi.y;
      }
#pragma unroll
      for (int mb = 0; mb < 8; ++mb) {
        FragU kf;
        const uint2 lo = *(const uint2*)(Kp + ((8 * ks + g) * 132 + mb * 16 + nl) * 2);
        const uint2 hi = *(const uint2*)(Kp + ((8 * ks + 4 + g) * 132 + mb * 16 + nl) * 2);
        kf.u[0] = lo.x; kf.u[1] = lo.y; kf.u[2] = hi.x; kf.u[3] = hi.y;
        s[mb] = __builtin_amdgcn_mfma_f32_16x16x32_bf16(kf.v, qf.v, s[mb], 0, 0, 0);
      }
    }

    // ---- online softmax (lane owns q-col nl; keys spread over g-groups) ----
    float cm = -1e30f;
#pragma unroll
    for (int mb = 0; mb < 8; ++mb)
#pragma unroll
      for (int r = 0; r < 4; ++r) cm = fmaxf(cm, s[mb][r]);
    cm = fmaxf(cm, __shfl_xor(cm, 16, 64));
    cm = fmaxf(cm, __shfl_xor(cm, 32, 64));
    const float mnew = fmaxf(m_run, cm);
    const float corr = __expf(m_run - mnew);
    m_run = mnew;
    float cs = 0.f;
#pragma unroll
    for (int mb = 0; mb < 8; ++mb)
#pragma unroll
      for (int r = 0; r < 4; ++r) {
        const float p = __expf(s[mb][r] - mnew);
        s[mb][r] = p;
        cs += p;
      }
    cs += __shfl_xor(cs, 16, 64);
    cs += __shfl_xor(cs, 32, 64);
    l_run = l_run * corr + cs;
#pragma unroll
    for (int db = 0; db < 4; ++db)
#pragma unroll
      for (int r = 0; r < 4; ++r) o[db][r] *= corr;

    // ---- O^T += V^T . P^T  (P from registers) ----
#pragma unroll
    for (int ks = 0; ks < 4; ++ks) {
      FragU pf;
      pf.u[0] = packbf(s[2 * ks][0],     s[2 * ks][1]);
      pf.u[1] = packbf(s[2 * ks][2],     s[2 * ks][3]);
      pf.u[2] = packbf(s[2 * ks + 1][0], s[2 * ks + 1][1]);
      pf.u[3] = packbf(s[2 * ks + 1][2], s[2 * ks + 1][3]);
#pragma unroll
      for (int db = 0; db < 4; ++db) {
        FragU vf;
        const uint2 lo = *(const uint2*)(Vp + ((8 * ks + g) * 66 + db * 16 + nl) * 2);
        const uint2 hi = *(const uint2*)(Vp + ((8 * ks + 4 + g) * 66 + db * 16 + nl) * 2);
        vf.u[0] = lo.x; vf.u[1] = lo.y; vf.u[2] = hi.x; vf.u[3] = hi.y;
        o[db] = __builtin_amdgcn_mfma_f32_16x16x32_bf16(vf.v, pf.v, o[db], 0, 0, 0);
      }
    }
  }

  // ---- O^T -> LDS (overlay), then coalesced fused epilogue ----
  const float inv = 1.f / l_run;
  __syncthreads();
#pragma unroll
  for (int db = 0; db < 4; ++db)
#pragma unroll
    for (int r = 0; r < 4; ++r)
      Osm[(db * 16 + 4 * g + r) * 130 + w * 16 + nl] = o[db][r] * inv;
  __syncthreads();

  {
    const int n = tid & 127;
#pragma unroll
    for (int i = 0; i < 16; ++i) {
      const int d = (tid >> 7) + 4 * i;
      const int c2 = h * 64 + d;
      const size_t off = ((size_t)b * 512 + c2) * 4096 + n0 + n;
      out[off] = Osm[d * 130 + n] + gate[b * 512 + c2] * x[off];
    }
  }
}

// ---------------------------------------------------------------------------
extern "C" void kernel_launch(void* const* d_in, const int* in_sizes, int n_in,
                              void* d_out, int out_size, void* d_ws, size_t ws_size,
                              hipStream_t stream)
{
  const float* x    = (const float*)d_in[0];
  const float* w01  = (const float*)d_in[1];
  const float* s01  = (const float*)d_in[2];
  const float* b01  = (const float*)d_in[3];
  const float* w02  = (const float*)d_in[4];
  const float* s02  = (const float*)d_in[5];
  const float* b02  = (const float*)d_in[6];
  const float* w03  = (const float*)d_in[7];
  const float* s03  = (const float*)d_in[8];
  const float* b03  = (const float*)d_in[9];
  const float* w12  = (const float*)d_in[10];
  const float* s12  = (const float*)d_in[11];
  const float* b12  = (const float*)d_in[12];
  const float* w13  = (const float*)d_in[13];
  const float* s13  = (const float*)d_in[14];
  const float* b13  = (const float*)d_in[15];
  const float* w22  = (const float*)d_in[16];
  const float* s22  = (const float*)d_in[17];
  const float* b22  = (const float*)d_in[18];
  const float* w23  = (const float*)d_in[19];
  const float* s23  = (const float*)d_in[20];
  const float* b23  = (const float*)d_in[21];
  const float* w3   = (const float*)d_in[22];
  const float* s3   = (const float*)d_in[23];
  const float* b3   = (const float*)d_in[24];
  const float* wkv  = (const float*)d_in[25];
  const float* skv  = (const float*)d_in[26];
  const float* bkv  = (const float*)d_in[27];
  const float* wfc1 = (const float*)d_in[28];
  const float* bfc1 = (const float*)d_in[29];
  const float* wfc2 = (const float*)d_in[30];
  const float* bfc2 = (const float*)d_in[31];

  float* out = (float*)d_out;
  float* wsf = (float*)d_ws;

  float* T      = wsf;                 // 3*8*128*4096 = 12,582,912 floats
  float* pooled = wsf + 12582912;      // 8*512*256
  float* kvbuf  = wsf + 13631488;      // 8*1024*256
  float* gapb   = wsf + 15728640;      // 4096
  float* gateb  = wsf + 15732736;      // 4096

  float* a01 = out;   // [8,128,4096], dead once T is built
  float* B   = out;   // [8,512,4096], dead once pooled is built

  gemm_silu_kernel<<<dim3(64, 2, 8), 256, 0, stream>>>(x, w01, s01, b01, a01, 512, 128, 4096);
  dwconv_out_kernel<<<dim3(16, 1024, 3), 256, 0, stream>>>(a01, T,
      w02, s02, b02, w12, s12, b12, w22, s22, b22);
  gemm3branch_kernel<<<dim3(64, 8, 8), 256, 0, stream>>>(T, w03, w13, w23,
      s03, s13, s23, b03, b13, b23, B);
  hipMemsetAsync(pooled, 0, (size_t)1048576 * sizeof(float), stream);
  gemm_pool_kernel<<<dim3(64, 8, 8), 256, 0, stream>>>(B, w3, s3, b3, x, pooled);
  gemm_silu_kernel<<<dim3(4, 16, 8), 256, 0, stream>>>(pooled, wkv, skv, bkv, kvbuf, 512, 1024, 256);
  gap_kernel<<<4096, 256, 0, stream>>>(x, gapb);
  se_kernel<<<8, 512, 0, stream>>>(gapb, wfc1, bfc1, wfc2, bfc2, gateb);
  attn_mfma_kernel<<<dim3(32, 8, 8), 512, 0, stream>>>(x, kvbuf, gateb, out);
}

// Round 3
// 408.654 us; speedup vs baseline: 3.0071x; 1.7824x over previous
//
#include <hip/hip_runtime.h>
#include <cstddef>

// ---------------------------------------------------------------------------
// _Mutilscal_MHSA — round 3: all pointwise GEMMs moved to bf16 MFMA
// (128x128 tile, 8 waves, packed bf16-pair LDS layout identical to the
// verified attention kernel). Epilogues: silu store / 3-branch silu-sum /
// fused silu*x + 4x4 pool (shfl-reduced atomics).
// ---------------------------------------------------------------------------

static __device__ __forceinline__ float silu_f(float v) {
  return v / (1.f + __expf(-v));
}

typedef __attribute__((ext_vector_type(8))) short short8v;   // bf16x8 frag
typedef __attribute__((ext_vector_type(4))) float f32x4;     // MFMA acc

union FragU { unsigned u[4]; short8v v; };

static __device__ __forceinline__ unsigned short f2bf(float f) {
  unsigned u = __builtin_bit_cast(unsigned, f);
  u += 0x7fffu + ((u >> 16) & 1u);           // round-to-nearest-even
  return (unsigned short)(u >> 16);
}
static __device__ __forceinline__ unsigned packbf(float lo, float hi) {
  return (unsigned)f2bf(lo) | ((unsigned)f2bf(hi) << 16);
}

// ---- shared MFMA-GEMM building blocks -------------------------------------
// LDS tile layout: P[(kq*132 + pos)*2 + j], word j = bf16 pair (k=4kq+2j, +1).
// Fragment (mfma_f32_16x16x32_bf16): lane l elem e -> k = 4*(l>>4)+(e&3)+16*(e>>2).

static __device__ __forceinline__ void stage_x64x128(const float* __restrict__ src, int ld,
                                                     unsigned* Xp, int tid) {
  const int kq4 = tid >> 5;             // 0..15 -> k rows 4*kq4..4*kq4+3
  const int pp  = (tid & 31) * 4;       // pos
  const float* base = src + (size_t)(4 * kq4) * ld + pp;
  const float4 r0 = *(const float4*)(base);
  const float4 r1 = *(const float4*)(base + ld);
  const float4 r2 = *(const float4*)(base + 2 * (size_t)ld);
  const float4 r3 = *(const float4*)(base + 3 * (size_t)ld);
  uint4 w0, w1;
  w0.x = packbf(r0.x, r1.x); w0.y = packbf(r2.x, r3.x);
  w0.z = packbf(r0.y, r1.y); w0.w = packbf(r2.y, r3.y);
  w1.x = packbf(r0.z, r1.z); w1.y = packbf(r2.z, r3.z);
  w1.z = packbf(r0.w, r1.w); w1.w = packbf(r2.w, r3.w);
  *(uint4*)(Xp + ((kq4 * 132 + pp) * 2))     = w0;
  *(uint4*)(Xp + ((kq4 * 132 + pp + 2) * 2)) = w1;
}

static __device__ __forceinline__ void stage_w128x64(const float* __restrict__ src, int ld,
                                                     unsigned* Wp, int tid) {
  const int oc = tid & 127;
  const int j  = tid >> 7;              // 0..3 -> k segment j*16
  const float* base = src + (size_t)oc * ld + j * 16;
#pragma unroll
  for (int m = 0; m < 4; ++m) {
    const float4 wv = *(const float4*)(base + 4 * m);
    const int kq = j * 4 + m;
    Wp[(kq * 132 + oc) * 2 + 0] = packbf(wv.x, wv.y);
    Wp[(kq * 132 + oc) * 2 + 1] = packbf(wv.z, wv.w);
  }
}

static __device__ __forceinline__ short8v load_frag(const unsigned* P, int kq0, int pos) {
  FragU f;
  const uint2 lo = *(const uint2*)(P + (kq0 * 132 + pos) * 2);
  const uint2 hi = *(const uint2*)(P + ((kq0 + 4) * 132 + pos) * 2);
  f.u[0] = lo.x; f.u[1] = lo.y; f.u[2] = hi.x; f.u[3] = hi.y;
  return f.v;
}

#define GEMM_IDS                                            \
  const int tid = threadIdx.x;                              \
  const int w = tid >> 6, lane = tid & 63;                  \
  const int g = lane >> 4, nl = lane & 15;                  \
  const int wr = w >> 1, wc = w & 1;

#define GEMM_KSTEP(ACC)                                                            \
  _Pragma("unroll")                                                                \
  for (int ks = 0; ks < 2; ++ks) {                                                 \
    const short8v a0 = load_frag(Wp, ks * 8 + g, wr * 32 + nl);                    \
    const short8v a1 = load_frag(Wp, ks * 8 + g, wr * 32 + 16 + nl);               \
    _Pragma("unroll")                                                              \
    for (int jj = 0; jj < 4; ++jj) {                                               \
      const short8v bf = load_frag(Xp, ks * 8 + g, wc * 64 + jj * 16 + nl);        \
      ACC[0][jj] = __builtin_amdgcn_mfma_f32_16x16x32_bf16(a0, bf, ACC[0][jj], 0, 0, 0); \
      ACC[1][jj] = __builtin_amdgcn_mfma_f32_16x16x32_bf16(a1, bf, ACC[1][jj], 0, 0, 0); \
    }                                                                              \
  }

// ---------------------------------------------------------------------------
// Generic bf16 GEMM + SiLU store: O[oc][p] = silu(sc*<W[oc,:],X[:,p]>+bi).
// grid (N/128, OC/128, B), block 512.
__global__ __launch_bounds__(512)
void gemm_bf16_silu_kernel(const float* __restrict__ X, const float* __restrict__ W,
                           const float* __restrict__ sc, const float* __restrict__ bi,
                           float* __restrict__ O, int K, int OC, int N)
{
  const int b   = blockIdx.z;
  const int p0  = blockIdx.x * 128;
  const int oc0 = blockIdx.y * 128;
  const float* Xb = X + (size_t)b * K * N;
  float*       Ob = O + (size_t)b * OC * N;

  __shared__ unsigned Xp[16 * 132 * 2];
  __shared__ unsigned Wp[16 * 132 * 2];
  GEMM_IDS

  f32x4 acc[2][4];
#pragma unroll
  for (int i = 0; i < 2; ++i)
#pragma unroll
    for (int jj = 0; jj < 4; ++jj) acc[i][jj] = (f32x4){0.f, 0.f, 0.f, 0.f};

  for (int k0 = 0; k0 < K; k0 += 64) {
    __syncthreads();
    stage_x64x128(Xb + (size_t)k0 * N + p0, N, Xp, tid);
    stage_w128x64(W + (size_t)oc0 * K + k0, K, Wp, tid);
    __syncthreads();
    GEMM_KSTEP(acc)
  }

#pragma unroll
  for (int i = 0; i < 2; ++i)
#pragma unroll
    for (int r = 0; r < 4; ++r) {
      const int oc = oc0 + wr * 32 + i * 16 + 4 * g + r;
      const float s = sc[oc], bb = bi[oc];
#pragma unroll
      for (int jj = 0; jj < 4; ++jj) {
        const int pos = p0 + wc * 64 + jj * 16 + nl;
        Ob[(size_t)oc * N + pos] = silu_f(s * acc[i][jj][r] + bb);
      }
    }
}

// ---------------------------------------------------------------------------
// Three-branch 128->512 bf16 GEMM: B = sum_i silu(s_i*(W_i @ t_i)+b_i).
// grid (32, 4, 8), block 512.
__global__ __launch_bounds__(512)
void gemm3branch_bf16_kernel(const float* __restrict__ T,
                             const float* __restrict__ W0, const float* __restrict__ W1, const float* __restrict__ W2,
                             const float* __restrict__ s0, const float* __restrict__ s1, const float* __restrict__ s2,
                             const float* __restrict__ b0, const float* __restrict__ b1, const float* __restrict__ b2,
                             float* __restrict__ Bout)
{
  const int b = blockIdx.z, p0 = blockIdx.x * 128, oc0 = blockIdx.y * 128;
  const size_t TB = (size_t)8 * 128 * 4096;

  __shared__ unsigned Xp[16 * 132 * 2];
  __shared__ unsigned Wp[16 * 132 * 2];
  GEMM_IDS

  float sum[2][4][4] = {};

#pragma unroll
  for (int brn = 0; brn < 3; ++brn) {
    const float* Wsrc = (brn == 0 ? W0 : (brn == 1 ? W1 : W2));
    const float* ssrc = (brn == 0 ? s0 : (brn == 1 ? s1 : s2));
    const float* bsrc = (brn == 0 ? b0 : (brn == 1 ? b1 : b2));

    f32x4 acc[2][4];
#pragma unroll
    for (int i = 0; i < 2; ++i)
#pragma unroll
      for (int jj = 0; jj < 4; ++jj) acc[i][jj] = (f32x4){0.f, 0.f, 0.f, 0.f};

#pragma unroll
    for (int k0 = 0; k0 < 128; k0 += 64) {
      __syncthreads();
      stage_x64x128(T + brn * TB + (size_t)b * 128 * 4096 + (size_t)k0 * 4096 + p0, 4096, Xp, tid);
      stage_w128x64(Wsrc + (size_t)oc0 * 128 + k0, 128, Wp, tid);
      __syncthreads();
      GEMM_KSTEP(acc)
    }

#pragma unroll
    for (int i = 0; i < 2; ++i)
#pragma unroll
      for (int r = 0; r < 4; ++r) {
        const int oc = oc0 + wr * 32 + i * 16 + 4 * g + r;
        const float s = ssrc[oc], bb = bsrc[oc];
#pragma unroll
        for (int jj = 0; jj < 4; ++jj)
          sum[i][jj][r] += silu_f(s * acc[i][jj][r] + bb);
      }
  }

#pragma unroll
  for (int i = 0; i < 2; ++i)
#pragma unroll
    for (int r = 0; r < 4; ++r) {
      const int oc = oc0 + wr * 32 + i * 16 + 4 * g + r;
#pragma unroll
      for (int jj = 0; jj < 4; ++jj) {
        const int pos = p0 + wc * 64 + jj * 16 + nl;
        Bout[((size_t)b * 512 + oc) * 4096 + pos] = sum[i][jj][r];
      }
    }
}

// ---------------------------------------------------------------------------
// w3 bf16 GEMM (512->512) + fused silu*x + 4x4 block-mean pool (atomics).
// grid (32, 4, 8), block 512. Block covers image rows 2bx, 2bx+1 (same ph).
__global__ __launch_bounds__(512)
void gemm_pool_bf16_kernel(const float* __restrict__ X, const float* __restrict__ W,
                           const float* __restrict__ sc, const float* __restrict__ bi,
                           const float* __restrict__ xin, float* __restrict__ pooled)
{
  const int b = blockIdx.z, p0 = blockIdx.x * 128, oc0 = blockIdx.y * 128;
  const float* Xb = X + (size_t)b * 512 * 4096;
  const float* xb = xin + (size_t)b * 512 * 4096;

  __shared__ unsigned Xp[16 * 132 * 2];
  __shared__ unsigned Wp[16 * 132 * 2];
  GEMM_IDS

  f32x4 acc[2][4];
#pragma unroll
  for (int i = 0; i < 2; ++i)
#pragma unroll
    for (int jj = 0; jj < 4; ++jj) acc[i][jj] = (f32x4){0.f, 0.f, 0.f, 0.f};

  for (int k0 = 0; k0 < 512; k0 += 64) {
    __syncthreads();
    stage_x64x128(Xb + (size_t)k0 * 4096 + p0, 4096, Xp, tid);
    stage_w128x64(W + (size_t)oc0 * 512 + k0, 512, Wp, tid);
    __syncthreads();
    GEMM_KSTEP(acc)
  }

#pragma unroll
  for (int i = 0; i < 2; ++i)
#pragma unroll
    for (int r = 0; r < 4; ++r) {
      const int oc = oc0 + wr * 32 + i * 16 + 4 * g + r;
      const float s = sc[oc], bb = bi[oc];
#pragma unroll
      for (int jj = 0; jj < 4; ++jj) {
        const int p = p0 + wc * 64 + jj * 16 + nl;
        float val = silu_f(s * acc[i][jj][r] + bb) * xb[(size_t)oc * 4096 + p];
        val += __shfl_xor(val, 1, 64);
        val += __shfl_xor(val, 2, 64);
        if ((nl & 3) == 0) {
          const int y = p >> 6, col = p & 63;
          atomicAdd(&pooled[((size_t)b * 512 + oc) * 256 + (y >> 2) * 16 + (col >> 2)],
                    val * (1.f / 16.f));
        }
      }
    }
}

// ---------------------------------------------------------------------------
// Depthwise dilated 3x3 + SiLU (dil 3/5/7 by blockIdx.z).
__global__ __launch_bounds__(256)
void dwconv_out_kernel(const float* __restrict__ A, float* __restrict__ Tout,
                       const float* __restrict__ w2a, const float* __restrict__ sa, const float* __restrict__ ba,
                       const float* __restrict__ w2b, const float* __restrict__ sb, const float* __restrict__ bb_,
                       const float* __restrict__ w2c, const float* __restrict__ sc_, const float* __restrict__ bc_)
{
  const int br = blockIdx.z;
  const int bc = blockIdx.y;               // b*128 + c
  const int c  = bc & 127;
  const int p  = blockIdx.x * 256 + threadIdx.x;
  const int y  = p >> 6, xx = p & 63;
  const int d  = 3 + 2 * br;

  const float* w = (br == 0 ? w2a : (br == 1 ? w2b : w2c)) + c * 9;
  const float  s = (br == 0 ? sa : (br == 1 ? sb : sc_))[c];
  const float bi = (br == 0 ? ba : (br == 1 ? bb_ : bc_))[c];

  const float* Ab = A + (size_t)bc * 4096;
  float sum = 0.f;
#pragma unroll
  for (int u = -1; u <= 1; ++u) {
    const int yy = y + u * d;
    if ((unsigned)yy < 64u) {
#pragma unroll
      for (int v = -1; v <= 1; ++v) {
        const int xv = xx + v * d;
        if ((unsigned)xv < 64u)
          sum += w[(u + 1) * 3 + (v + 1)] * Ab[yy * 64 + xv];
      }
    }
  }
  const float val = s * sum + bi;
  Tout[(size_t)br * (8ull * 128 * 4096) + (size_t)bc * 4096 + p] = silu_f(val);
}

// ---------------------------------------------------------------------------
__global__ __launch_bounds__(256)
void gap_kernel(const float* __restrict__ x, float* __restrict__ gap)
{
  const int bc = blockIdx.x;
  const int tid = threadIdx.x;
  const float* p = x + (size_t)bc * 4096;
  float v = 0.f;
#pragma unroll
  for (int j = 0; j < 16; ++j) v += p[j * 256 + tid];
#pragma unroll
  for (int off = 32; off >= 1; off >>= 1) v += __shfl_down(v, off, 64);
  __shared__ float red[4];
  if ((tid & 63) == 0) red[tid >> 6] = v;
  __syncthreads();
  if (tid == 0) gap[bc] = (red[0] + red[1] + red[2] + red[3]) * (1.f / 4096.f);
}

// ---------------------------------------------------------------------------
__global__ __launch_bounds__(512)
void se_kernel(const float* __restrict__ gap,
               const float* __restrict__ wfc1, const float* __restrict__ bfc1,
               const float* __restrict__ wfc2, const float* __restrict__ bfc2,
               float* __restrict__ gate)
{
  const int b = blockIdx.x, tid = threadIdx.x;
  __shared__ float ylds[128];
  if (tid < 128) {
    float a = 0.f;
    for (int c = 0; c < 512; ++c) a += gap[b * 512 + c] * wfc1[tid * 512 + c];
    a += bfc1[tid];
    ylds[tid] = fminf(fmaxf(a, 0.f), 6.f);
  }
  __syncthreads();
  float g = 0.f;
  for (int j = 0; j < 128; ++j) g += ylds[j] * wfc2[tid * 128 + j];
  g += bfc2[tid];
  gate[b * 512 + tid] = 1.f / (1.f + __expf(-g));
}

// ---------------------------------------------------------------------------
// MFMA bf16 attention (swapped-QK^T, lane-local softmax, P-in-register PV),
// fused SE residual epilogue. Unchanged from round 2 (verified).
__global__ __launch_bounds__(512)
void attn_mfma_kernel(const float* __restrict__ x, const float* __restrict__ kv,
                      const float* __restrict__ gate, float* __restrict__ out)
{
  const int b = blockIdx.z, h = blockIdx.y;
  const int n0 = blockIdx.x * 128;
  const int tid = threadIdx.x;
  const int w = tid >> 6, lane = tid & 63;
  const int g = lane >> 4, nl = lane & 15;

  __shared__ unsigned lds[16 * 132 * 2 * 2 + 32 * 66 * 2];
  unsigned* Kp = lds;
  unsigned* Qp = lds + 16 * 132 * 2;
  unsigned* Vp = lds + 2 * 16 * 132 * 2;
  float* Osm = (float*)lds;

  const size_t xbh = ((size_t)b * 512 + h * 64) * 4096 + n0;
  const size_t kbh = ((size_t)b * 1024 + h * 64) * 256;
  const size_t vbh = ((size_t)b * 1024 + 512 + h * 64) * 256;

  {
    const int dq = tid >> 5, nq = (tid & 31) * 4;
    const float4 r0 = *(const float4*)(x + xbh + (size_t)(4 * dq + 0) * 4096 + nq);
    const float4 r1 = *(const float4*)(x + xbh + (size_t)(4 * dq + 1) * 4096 + nq);
    const float4 r2 = *(const float4*)(x + xbh + (size_t)(4 * dq + 2) * 4096 + nq);
    const float4 r3 = *(const float4*)(x + xbh + (size_t)(4 * dq + 3) * 4096 + nq);
    const float sc = 0.125f;
    uint4 w0, w1;
    w0.x = packbf(r0.x * sc, r1.x * sc); w0.y = packbf(r2.x * sc, r3.x * sc);
    w0.z = packbf(r0.y * sc, r1.y * sc); w0.w = packbf(r2.y * sc, r3.y * sc);
    w1.x = packbf(r0.z * sc, r1.z * sc); w1.y = packbf(r2.z * sc, r3.z * sc);
    w1.z = packbf(r0.w * sc, r1.w * sc); w1.w = packbf(r2.w * sc, r3.w * sc);
    *(uint4*)(Qp + (dq * 132 + nq) * 2)     = w0;
    *(uint4*)(Qp + (dq * 132 + nq + 2) * 2) = w1;
  }

  float m_run = -1e30f, l_run = 0.f;
  f32x4 o[4];
#pragma unroll
  for (int i = 0; i < 4; ++i) o[i] = (f32x4){0.f, 0.f, 0.f, 0.f};

#pragma unroll
  for (int ch = 0; ch < 2; ++ch) {
    const int m0 = ch * 128;
    __syncthreads();
    {
      const int dq = tid >> 5, mq = (tid & 31) * 4;
      const float4 r0 = *(const float4*)(kv + kbh + (size_t)(4 * dq + 0) * 256 + m0 + mq);
      const float4 r1 = *(const float4*)(kv + kbh + (size_t)(4 * dq + 1) * 256 + m0 + mq);
      const float4 r2 = *(const float4*)(kv + kbh + (size_t)(4 * dq + 2) * 256 + m0 + mq);
      const float4 r3 = *(const float4*)(kv + kbh + (size_t)(4 * dq + 3) * 256 + m0 + mq);
      uint4 w0, w1;
      w0.x = packbf(r0.x, r1.x); w0.y = packbf(r2.x, r3.x);
      w0.z = packbf(r0.y, r1.y); w0.w = packbf(r2.y, r3.y);
      w1.x = packbf(r0.z, r1.z); w1.y = packbf(r2.z, r3.z);
      w1.z = packbf(r0.w, r1.w); w1.w = packbf(r2.w, r3.w);
      *(uint4*)(Kp + (dq * 132 + mq) * 2)     = w0;
      *(uint4*)(Kp + (dq * 132 + mq + 2) * 2) = w1;
    }
    {
      const int mq = (tid & 31) * 4;
#pragma unroll
      for (int p = 0; p < 4; ++p) {
        const int d = (tid >> 5) + 16 * p;
        const float4 vv = *(const float4*)(kv + vbh + (size_t)d * 256 + m0 + mq);
        uint2 wv;
        wv.x = packbf(vv.x, vv.y);
        wv.y = packbf(vv.z, vv.w);
        *(uint2*)(Vp + ((mq >> 2) * 66 + d) * 2) = wv;
      }
    }
    __syncthreads();

    f32x4 s[8];
#pragma unroll
    for (int mb = 0; mb < 8; ++mb) s[mb] = (f32x4){0.f, 0.f, 0.f, 0.f};
#pragma unroll
    for (int ks = 0; ks < 2; ++ks) {
      FragU qf;
      {
        const uint2 lo = *(const uint2*)(Qp + ((8 * ks + g) * 132 + w * 16 + nl) * 2);
        const uint2 hi = *(const uint2*)(Qp + ((8 * ks + 4 + g) * 132 + w * 16 + nl) * 2);
        qf.u[0] = lo.x; qf.u[1] = lo.y; qf.u[2] = hi.x; qf.u[3] = hi.y;
      }
#pragma unroll
      for (int mb = 0; mb < 8; ++mb) {
        FragU kf;
        const uint2 lo = *(const uint2*)(Kp + ((8 * ks + g) * 132 + mb * 16 + nl) * 2);
        const uint2 hi = *(const uint2*)(Kp + ((8 * ks + 4 + g) * 132 + mb * 16 + nl) * 2);
        kf.u[0] = lo.x; kf.u[1] = lo.y; kf.u[2] = hi.x; kf.u[3] = hi.y;
        s[mb] = __builtin_amdgcn_mfma_f32_16x16x32_bf16(kf.v, qf.v, s[mb], 0, 0, 0);
      }
    }

    float cm = -1e30f;
#pragma unroll
    for (int mb = 0; mb < 8; ++mb)
#pragma unroll
      for (int r = 0; r < 4; ++r) cm = fmaxf(cm, s[mb][r]);
    cm = fmaxf(cm, __shfl_xor(cm, 16, 64));
    cm = fmaxf(cm, __shfl_xor(cm, 32, 64));
    const float mnew = fmaxf(m_run, cm);
    const float corr = __expf(m_run - mnew);
    m_run = mnew;
    float cs = 0.f;
#pragma unroll
    for (int mb = 0; mb < 8; ++mb)
#pragma unroll
      for (int r = 0; r < 4; ++r) {
        const float p = __expf(s[mb][r] - mnew);
        s[mb][r] = p;
        cs += p;
      }
    cs += __shfl_xor(cs, 16, 64);
    cs += __shfl_xor(cs, 32, 64);
    l_run = l_run * corr + cs;
#pragma unroll
    for (int db = 0; db < 4; ++db)
#pragma unroll
      for (int r = 0; r < 4; ++r) o[db][r] *= corr;

#pragma unroll
    for (int ks = 0; ks < 4; ++ks) {
      FragU pf;
      pf.u[0] = packbf(s[2 * ks][0],     s[2 * ks][1]);
      pf.u[1] = packbf(s[2 * ks][2],     s[2 * ks][3]);
      pf.u[2] = packbf(s[2 * ks + 1][0], s[2 * ks + 1][1]);
      pf.u[3] = packbf(s[2 * ks + 1][2], s[2 * ks + 1][3]);
#pragma unroll
      for (int db = 0; db < 4; ++db) {
        FragU vf;
        const uint2 lo = *(const uint2*)(Vp + ((8 * ks + g) * 66 + db * 16 + nl) * 2);
        const uint2 hi = *(const uint2*)(Vp + ((8 * ks + 4 + g) * 66 + db * 16 + nl) * 2);
        vf.u[0] = lo.x; vf.u[1] = lo.y; vf.u[2] = hi.x; vf.u[3] = hi.y;
        o[db] = __builtin_amdgcn_mfma_f32_16x16x32_bf16(vf.v, pf.v, o[db], 0, 0, 0);
      }
    }
  }

  const float inv = 1.f / l_run;
  __syncthreads();
#pragma unroll
  for (int db = 0; db < 4; ++db)
#pragma unroll
    for (int r = 0; r < 4; ++r)
      Osm[(db * 16 + 4 * g + r) * 130 + w * 16 + nl] = o[db][r] * inv;
  __syncthreads();

  {
    const int n = tid & 127;
#pragma unroll
    for (int i = 0; i < 16; ++i) {
      const int d = (tid >> 7) + 4 * i;
      const int c2 = h * 64 + d;
      const size_t off = ((size_t)b * 512 + c2) * 4096 + n0 + n;
      out[off] = Osm[d * 130 + n] + gate[b * 512 + c2] * x[off];
    }
  }
}

// ---------------------------------------------------------------------------
extern "C" void kernel_launch(void* const* d_in, const int* in_sizes, int n_in,
                              void* d_out, int out_size, void* d_ws, size_t ws_size,
                              hipStream_t stream)
{
  const float* x    = (const float*)d_in[0];
  const float* w01  = (const float*)d_in[1];
  const float* s01  = (const float*)d_in[2];
  const float* b01  = (const float*)d_in[3];
  const float* w02  = (const float*)d_in[4];
  const float* s02  = (const float*)d_in[5];
  const float* b02  = (const float*)d_in[6];
  const float* w03  = (const float*)d_in[7];
  const float* s03  = (const float*)d_in[8];
  const float* b03  = (const float*)d_in[9];
  const float* w12  = (const float*)d_in[10];
  const float* s12  = (const float*)d_in[11];
  const float* b12  = (const float*)d_in[12];
  const float* w13  = (const float*)d_in[13];
  const float* s13  = (const float*)d_in[14];
  const float* b13  = (const float*)d_in[15];
  const float* w22  = (const float*)d_in[16];
  const float* s22  = (const float*)d_in[17];
  const float* b22  = (const float*)d_in[18];
  const float* w23  = (const float*)d_in[19];
  const float* s23  = (const float*)d_in[20];
  const float* b23  = (const float*)d_in[21];
  const float* w3   = (const float*)d_in[22];
  const float* s3   = (const float*)d_in[23];
  const float* b3   = (const float*)d_in[24];
  const float* wkv  = (const float*)d_in[25];
  const float* skv  = (const float*)d_in[26];
  const float* bkv  = (const float*)d_in[27];
  const float* wfc1 = (const float*)d_in[28];
  const float* bfc1 = (const float*)d_in[29];
  const float* wfc2 = (const float*)d_in[30];
  const float* bfc2 = (const float*)d_in[31];

  float* out = (float*)d_out;
  float* wsf = (float*)d_ws;

  float* T      = wsf;                 // 3*8*128*4096 = 12,582,912 floats
  float* pooled = wsf + 12582912;      // 8*512*256
  float* kvbuf  = wsf + 13631488;      // 8*1024*256
  float* gapb   = wsf + 15728640;      // 4096
  float* gateb  = wsf + 15732736;      // 4096

  float* a01 = out;   // [8,128,4096], dead once T is built
  float* B   = out;   // [8,512,4096], dead once pooled is built

  // 1. a01 = silu(s01*(w01@x)+b01)
  gemm_bf16_silu_kernel<<<dim3(32, 1, 8), 512, 0, stream>>>(x, w01, s01, b01, a01, 512, 128, 4096);
  // 2. depthwise dilated branches
  dwconv_out_kernel<<<dim3(16, 1024, 3), 256, 0, stream>>>(a01, T,
      w02, s02, b02, w12, s12, b12, w22, s22, b22);
  // 3. B = sum of three 128->512 CBS branches
  gemm3branch_bf16_kernel<<<dim3(32, 4, 8), 512, 0, stream>>>(T, w03, w13, w23,
      s03, s13, s23, b03, b13, b23, B);
  // 4. pooled = blockmean(silu(s3*(w3@B)+b3) * x)
  hipMemsetAsync(pooled, 0, (size_t)1048576 * sizeof(float), stream);
  gemm_pool_bf16_kernel<<<dim3(32, 4, 8), 512, 0, stream>>>(B, w3, s3, b3, x, pooled);
  // 5. kv = silu(skv*(wkv@pooled)+bkv)
  gemm_bf16_silu_kernel<<<dim3(2, 8, 8), 512, 0, stream>>>(pooled, wkv, skv, bkv, kvbuf, 512, 1024, 256);
  // 6. SE gate
  gap_kernel<<<4096, 256, 0, stream>>>(x, gapb);
  se_kernel<<<8, 512, 0, stream>>>(gapb, wfc1, bfc1, wfc2, bfc2, gateb);
  // 7. attention + gate*x residual -> final output
  attn_mfma_kernel<<<dim3(32, 8, 8), 512, 0, stream>>>(x, kvbuf, gateb, out);
}

// Round 4
// 297.772 us; speedup vs baseline: 4.1269x; 1.3724x over previous
//
#include <hip/hip_runtime.h>
#include <cstddef>

// ---------------------------------------------------------------------------
// _Mutilscal_MHSA — round 4: bf16 "img-tile" pipeline.
// Every GEMM operand tile is a 4096-word (16 KB) image in the exact LDS
// layout the MFMA consumer reads: word addr = (r4*128+pos)*4 + sub*2 + j,
// where kq = (r4&3) + sub*4 + (r4>>2)*8, word j = bf16 pair (k=4kq+2j, +1).
// One fragment = one ds_read_b128 at (r4*128+pos)*4 (bank-balanced).
// Producers write img tiles directly; consumers stage with pure uint4 copies.
// Weights prepacked once per launch. Intermediates all bf16.
// ---------------------------------------------------------------------------

static __device__ __forceinline__ float silu_f(float v) {
  return v / (1.f + __expf(-v));
}

typedef __attribute__((ext_vector_type(8))) short short8v;   // bf16x8 frag
typedef __attribute__((ext_vector_type(4))) float f32x4;     // MFMA acc

union FragU { unsigned u[4]; short8v v; uint4 q; };

static __device__ __forceinline__ unsigned short f2bf(float f) {
  unsigned u = __builtin_bit_cast(unsigned, f);
  u += 0x7fffu + ((u >> 16) & 1u);           // round-to-nearest-even
  return (unsigned short)(u >> 16);
}
static __device__ __forceinline__ unsigned packbf(float lo, float hi) {
  return (unsigned)f2bf(lo) | ((unsigned)f2bf(hi) << 16);
}

// one fragment = one b128 read
static __device__ __forceinline__ short8v load_frag4(const unsigned* P, int ksg, int pos) {
  FragU f;
  f.q = *(const uint4*)(P + (((ksg << 7) + pos) << 2));
  return f.v;
}

// copy one 4096-word img tile into LDS (512 threads, 2 x uint4 each)
static __device__ __forceinline__ void stage_copy_tile(const unsigned* __restrict__ src,
                                                       unsigned* dst, int tid) {
  *(uint4*)(dst + 4 * tid)         = *(const uint4*)(src + 4 * tid);
  *(uint4*)(dst + 4 * (tid + 512)) = *(const uint4*)(src + 4 * (tid + 512));
}

// stage a 64k x 128pos fp32 operand into LDS img layout (pack on the fly)
static __device__ __forceinline__ void stage_x_pack(const float* __restrict__ src, int ld,
                                                    unsigned* Xp, int tid) {
  const int pos = tid & 127, kg = tid >> 7;          // kg: k rows kg*16..+15
  const float* p = src + pos + (size_t)(kg * 16) * ld;
  float v[16];
#pragma unroll
  for (int i = 0; i < 16; ++i) v[i] = p[(size_t)i * ld];
#pragma unroll
  for (int i2 = 0; i2 < 4; ++i2) {
    const int kq = kg * 4 + i2;
    const int r4 = (kq & 3) + ((kq >> 3) << 2);
    const int sub = (kq >> 2) & 1;
    uint2 wv;
    wv.x = packbf(v[i2 * 4 + 0], v[i2 * 4 + 1]);
    wv.y = packbf(v[i2 * 4 + 2], v[i2 * 4 + 3]);
    *(uint2*)(Xp + (((r4 << 7) + pos) << 2) + sub * 2) = wv;
  }
}

#define GEMM_IDS                                            \
  const int tid = threadIdx.x;                              \
  const int w = tid >> 6, lane = tid & 63;                  \
  const int g = lane >> 4, nl = lane & 15;                  \
  const int wr = w >> 1, wc = w & 1;

#define GEMM_KSTEP(ACC)                                                            \
  _Pragma("unroll")                                                                \
  for (int ks = 0; ks < 2; ++ks) {                                                 \
    const short8v a0 = load_frag4(Wp, ks * 4 + g, wr * 32 + nl);                   \
    const short8v a1 = load_frag4(Wp, ks * 4 + g, wr * 32 + 16 + nl);              \
    _Pragma("unroll")                                                              \
    for (int jj = 0; jj < 4; ++jj) {                                               \
      const short8v bfr = load_frag4(Xp, ks * 4 + g, wc * 64 + jj * 16 + nl);      \
      ACC[0][jj] = __builtin_amdgcn_mfma_f32_16x16x32_bf16(a0, bfr, ACC[0][jj], 0, 0, 0); \
      ACC[1][jj] = __builtin_amdgcn_mfma_f32_16x16x32_bf16(a1, bfr, ACC[1][jj], 0, 0, 0); \
    }                                                                              \
  }

// ---------------------------------------------------------------------------
// Weight prepack: fp32 W[OC][K] -> img tiles (tile = to*(K/64)+tk).
// 128 blocks cover: w01(8), w03(8), w13(8), w23(8), w3(32), wkv(64).
__global__ __launch_bounds__(256)
void prepack_w_kernel(const float* __restrict__ w01, const float* __restrict__ w03,
                      const float* __restrict__ w13, const float* __restrict__ w23,
                      const float* __restrict__ w3, const float* __restrict__ wkv,
                      unsigned* __restrict__ img)
{
  const int t = blockIdx.x;
  const float* W; int K; int tile; unsigned* base;
  if (t < 8)       { W = w01; K = 512; tile = t;      base = img; }
  else if (t < 16) { W = w03; K = 128; tile = t - 8;  base = img + 32768; }
  else if (t < 24) { W = w13; K = 128; tile = t - 16; base = img + 65536; }
  else if (t < 32) { W = w23; K = 128; tile = t - 24; base = img + 98304; }
  else if (t < 64) { W = w3;  K = 512; tile = t - 32; base = img + 131072; }
  else             { W = wkv; K = 512; tile = t - 64; base = img + 262144; }
  const int nk = K >> 6;
  const int to = tile / nk, tk = tile - to * nk;
  unsigned* dst = base + (size_t)tile * 4096;
  for (int wi = threadIdx.x; wi < 4096; wi += 256) {
    const int r4 = wi >> 9, pos = (wi >> 2) & 127, sub = (wi >> 1) & 1, j = wi & 1;
    const int kq = (r4 & 3) + sub * 4 + ((r4 >> 2) << 3);
    const int k = tk * 64 + 4 * kq + 2 * j;
    const int oc = to * 128 + pos;
    dst[wi] = packbf(W[(size_t)oc * K + k], W[(size_t)oc * K + k + 1]);
  }
}

// ---------------------------------------------------------------------------
// a01 = silu(s01*(w01@x)+b01), written as packed bf16 pairs A01p[b][c2][p]
// (word = channels 2*c2, 2*c2+1). grid (32, 1, 8), block 512.
__global__ __launch_bounds__(512)
void gemm_a01_kernel(const float* __restrict__ X, const unsigned* __restrict__ Wimg,
                     const float* __restrict__ sc, const float* __restrict__ bi,
                     unsigned* __restrict__ A01p)
{
  const int b = blockIdx.z, p0 = blockIdx.x * 128;
  GEMM_IDS
  __shared__ unsigned Xp[4096], Wp[4096];

  f32x4 acc[2][4];
#pragma unroll
  for (int i = 0; i < 2; ++i)
#pragma unroll
    for (int jj = 0; jj < 4; ++jj) acc[i][jj] = (f32x4){0.f, 0.f, 0.f, 0.f};

  for (int ks8 = 0; ks8 < 8; ++ks8) {
    __syncthreads();
    stage_x_pack(X + (size_t)b * 512 * 4096 + (size_t)(ks8 * 64) * 4096 + p0, 4096, Xp, tid);
    stage_copy_tile(Wimg + (size_t)ks8 * 4096, Wp, tid);
    __syncthreads();
    GEMM_KSTEP(acc)
  }

#pragma unroll
  for (int i = 0; i < 2; ++i) {
    const int base = wr * 32 + i * 16 + 4 * g;       // oc base (mult of 4)
    const float s0_ = sc[base + 0], b0_ = bi[base + 0];
    const float s1_ = sc[base + 1], b1_ = bi[base + 1];
    const float s2_ = sc[base + 2], b2_ = bi[base + 2];
    const float s3_ = sc[base + 3], b3_ = bi[base + 3];
#pragma unroll
    for (int jj = 0; jj < 4; ++jj) {
      const int pos = p0 + wc * 64 + jj * 16 + nl;
      const float v0 = silu_f(s0_ * acc[i][jj][0] + b0_);
      const float v1 = silu_f(s1_ * acc[i][jj][1] + b1_);
      const float v2 = silu_f(s2_ * acc[i][jj][2] + b2_);
      const float v3 = silu_f(s3_ * acc[i][jj][3] + b3_);
      A01p[((size_t)b * 64 + (base >> 1)) * 4096 + pos]       = packbf(v0, v1);
      A01p[((size_t)b * 64 + (base >> 1) + 1) * 4096 + pos]   = packbf(v2, v3);
    }
  }
}

// ---------------------------------------------------------------------------
// Depthwise dilated 3x3 + SiLU on packed a01; writes T img tiles directly.
// Thread = 1 pixel x 8 channels (both subs of one r4 row) -> uint4 store.
// grid (16, 128, 3): y = b*16 + kstep*8 + mm. block 256.
__global__ __launch_bounds__(256)
void dwconv_pack_kernel(const unsigned* __restrict__ A01p, unsigned* __restrict__ Timg,
                        const float* __restrict__ w02, const float* __restrict__ s02, const float* __restrict__ b02,
                        const float* __restrict__ w12, const float* __restrict__ s12, const float* __restrict__ b12,
                        const float* __restrict__ w22, const float* __restrict__ s22, const float* __restrict__ b22)
{
  const int br = blockIdx.z;
  const int yb = blockIdx.y;
  const int b = yb >> 4, t16 = yb & 15, kstep = t16 >> 3, mm = t16 & 7;
  const int kq = (mm & 3) + ((mm >> 2) << 3);
  const int cbase = kstep * 64 + kq * 4;             // channels cbase..+3, +16..+19
  const int p = blockIdx.x * 256 + threadIdx.x;
  const int y = p >> 6, xx = p & 63;
  const int d = 3 + 2 * br;

  const float* wsel = br == 0 ? w02 : (br == 1 ? w12 : w22);
  const float* ssel = br == 0 ? s02 : (br == 1 ? s12 : s22);
  const float* bsel = br == 0 ? b02 : (br == 1 ? b12 : b22);

  float sum[8] = {};
  const unsigned* plane0 = A01p + ((size_t)b * 64 + (cbase >> 1)) * 4096;

#pragma unroll
  for (int u = -1; u <= 1; ++u) {
    const int yv = y + u * d;
    if ((unsigned)yv < 64u) {
#pragma unroll
      for (int v = -1; v <= 1; ++v) {
        const int xv = xx + v * d;
        if ((unsigned)xv < 64u) {
          const int idx = yv * 64 + xv;
          const int tap = (u + 1) * 3 + (v + 1);
#pragma unroll
          for (int q = 0; q < 4; ++q) {              // q = sub*2 + jw
            const int sub = q >> 1, jw = q & 1;
            const unsigned wv = plane0[(size_t)(sub * 8 + jw) * 4096 + idx];
            const float lo = __builtin_bit_cast(float, wv << 16);
            const float hi = __builtin_bit_cast(float, wv & 0xffff0000u);
            const int ch = cbase + sub * 16 + jw * 2;
            sum[q * 2 + 0] += wsel[(ch + 0) * 9 + tap] * lo;
            sum[q * 2 + 1] += wsel[(ch + 1) * 9 + tap] * hi;
          }
        }
      }
    }
  }

  unsigned wout[4];
#pragma unroll
  for (int h = 0; h < 4; ++h) {                      // h = sub*2 + jw
    const int ch = cbase + (h >> 1) * 16 + (h & 1) * 2;
    const float va = silu_f(ssel[ch] * sum[h * 2] + bsel[ch]);
    const float vb = silu_f(ssel[ch + 1] * sum[h * 2 + 1] + bsel[ch + 1]);
    wout[h] = packbf(va, vb);
  }
  const int tile = ((br * 8 + b) * 2 + kstep) * 32 + (p >> 7);
  *(uint4*)(Timg + (size_t)tile * 4096 + (((mm << 7) + (p & 127)) << 2)) = *(uint4*)wout;
}

// ---------------------------------------------------------------------------
// B = sum_i silu(s_i*(W_i @ t_i)+b_i), written as B img tiles.
// grid (32, 4, 8), block 512.
__global__ __launch_bounds__(512)
void gemm3branch_img_kernel(const unsigned* __restrict__ Timg, const unsigned* __restrict__ Wimg3,
                            const float* __restrict__ s0, const float* __restrict__ s1, const float* __restrict__ s2,
                            const float* __restrict__ b0, const float* __restrict__ b1, const float* __restrict__ b2,
                            unsigned* __restrict__ Bimg)
{
  const int b = blockIdx.z, pt = blockIdx.x, oc0 = blockIdx.y * 128;
  GEMM_IDS
  __shared__ unsigned Xp[4096], Wp[4096];

  float sum[2][4][4] = {};

#pragma unroll
  for (int brn = 0; brn < 3; ++brn) {
    const float* ss = brn == 0 ? s0 : (brn == 1 ? s1 : s2);
    const float* bs = brn == 0 ? b0 : (brn == 1 ? b1 : b2);

    f32x4 acc[2][4];
#pragma unroll
    for (int i = 0; i < 2; ++i)
#pragma unroll
      for (int jj = 0; jj < 4; ++jj) acc[i][jj] = (f32x4){0.f, 0.f, 0.f, 0.f};

#pragma unroll
    for (int ksx = 0; ksx < 2; ++ksx) {
      __syncthreads();
      stage_copy_tile(Timg + (((size_t)(brn * 8 + b) * 2 + ksx) * 32 + pt) * 4096, Xp, tid);
      stage_copy_tile(Wimg3 + (size_t)brn * 32768 + ((size_t)(oc0 >> 7) * 2 + ksx) * 4096, Wp, tid);
      __syncthreads();
      GEMM_KSTEP(acc)
    }

#pragma unroll
    for (int i = 0; i < 2; ++i) {
      const int base = oc0 + wr * 32 + i * 16 + 4 * g;
#pragma unroll
      for (int r = 0; r < 4; ++r) {
        const float s = ss[base + r], bb = bs[base + r];
#pragma unroll
        for (int jj = 0; jj < 4; ++jj)
          sum[i][jj][r] += silu_f(s * acc[i][jj][r] + bb);
      }
    }
  }

#pragma unroll
  for (int i = 0; i < 2; ++i) {
    const int ol = wr * 32 + i * 16 + 4 * g;
    const int kstep_g = (oc0 + ol) >> 6;
    const int kin = ol & 63;
    const int kq2 = kin >> 2;
    const int r4 = (kq2 & 3) + ((kq2 >> 3) << 2);
    const int sub = (kq2 >> 2) & 1;
#pragma unroll
    for (int jj = 0; jj < 4; ++jj) {
      const int pos = wc * 64 + jj * 16 + nl;
      uint2 wv;
      wv.x = packbf(sum[i][jj][0], sum[i][jj][1]);
      wv.y = packbf(sum[i][jj][2], sum[i][jj][3]);
      *(uint2*)(Bimg + ((size_t)(b * 8 + kstep_g) * 32 + pt) * 4096 + (((r4 << 7) + pos) << 2) + sub * 2) = wv;
    }
  }
}

// ---------------------------------------------------------------------------
// w3 GEMM (512->512) from B img + fused silu*x + 4x4 block-mean pool.
// grid (32, 4, 8), block 512.
__global__ __launch_bounds__(512)
void gemm_pool_img_kernel(const unsigned* __restrict__ Bimg, const unsigned* __restrict__ W3img,
                          const float* __restrict__ sc, const float* __restrict__ bi,
                          const float* __restrict__ xin, float* __restrict__ pooled)
{
  const int b = blockIdx.z, pt = blockIdx.x, oc0 = blockIdx.y * 128;
  const int p0 = pt * 128;
  const float* xb = xin + (size_t)b * 512 * 4096;
  GEMM_IDS
  __shared__ unsigned Xp[4096], Wp[4096];

  f32x4 acc[2][4];
#pragma unroll
  for (int i = 0; i < 2; ++i)
#pragma unroll
    for (int jj = 0; jj < 4; ++jj) acc[i][jj] = (f32x4){0.f, 0.f, 0.f, 0.f};

  for (int ks8 = 0; ks8 < 8; ++ks8) {
    __syncthreads();
    stage_copy_tile(Bimg + ((size_t)(b * 8 + ks8) * 32 + pt) * 4096, Xp, tid);
    stage_copy_tile(W3img + ((size_t)(oc0 >> 7) * 8 + ks8) * 4096, Wp, tid);
    __syncthreads();
    GEMM_KSTEP(acc)
  }

#pragma unroll
  for (int i = 0; i < 2; ++i)
#pragma unroll
    for (int r = 0; r < 4; ++r) {
      const int oc = oc0 + wr * 32 + i * 16 + 4 * g + r;
      const float s = sc[oc], bb = bi[oc];
#pragma unroll
      for (int jj = 0; jj < 4; ++jj) {
        const int p = p0 + wc * 64 + jj * 16 + nl;
        float val = silu_f(s * acc[i][jj][r] + bb) * xb[(size_t)oc * 4096 + p];
        val += __shfl_xor(val, 1, 64);
        val += __shfl_xor(val, 2, 64);
        if ((nl & 3) == 0) {
          const int y = p >> 6, col = p & 63;
          atomicAdd(&pooled[((size_t)b * 512 + oc) * 256 + (y >> 2) * 16 + (col >> 2)],
                    val * (1.f / 16.f));
        }
      }
    }
}

// ---------------------------------------------------------------------------
// kv = silu(skv*(wkv@pooled)+bkv), fp32 out. grid (2, 8, 8), block 512.
__global__ __launch_bounds__(512)
void gemm_kv_kernel(const float* __restrict__ X, const unsigned* __restrict__ WKVimg,
                    const float* __restrict__ sc, const float* __restrict__ bi,
                    float* __restrict__ O)
{
  const int b = blockIdx.z, p0 = blockIdx.x * 128, oc0 = blockIdx.y * 128;
  const float* Xb = X + (size_t)b * 512 * 256;
  float* Ob = O + (size_t)b * 1024 * 256;
  GEMM_IDS
  __shared__ unsigned Xp[4096], Wp[4096];

  f32x4 acc[2][4];
#pragma unroll
  for (int i = 0; i < 2; ++i)
#pragma unroll
    for (int jj = 0; jj < 4; ++jj) acc[i][jj] = (f32x4){0.f, 0.f, 0.f, 0.f};

  for (int ks8 = 0; ks8 < 8; ++ks8) {
    __syncthreads();
    stage_x_pack(Xb + (size_t)(ks8 * 64) * 256 + p0, 256, Xp, tid);
    stage_copy_tile(WKVimg + ((size_t)(oc0 >> 7) * 8 + ks8) * 4096, Wp, tid);
    __syncthreads();
    GEMM_KSTEP(acc)
  }

#pragma unroll
  for (int i = 0; i < 2; ++i)
#pragma unroll
    for (int r = 0; r < 4; ++r) {
      const int oc = oc0 + wr * 32 + i * 16 + 4 * g + r;
      const float s = sc[oc], bb = bi[oc];
#pragma unroll
      for (int jj = 0; jj < 4; ++jj) {
        const int pos = p0 + wc * 64 + jj * 16 + nl;
        Ob[(size_t)oc * 256 + pos] = silu_f(s * acc[i][jj][r] + bb);
      }
    }
}

// ---------------------------------------------------------------------------
__global__ __launch_bounds__(256)
void gap_kernel(const float* __restrict__ x, float* __restrict__ gap)
{
  const int bc = blockIdx.x;
  const int tid = threadIdx.x;
  const float* p = x + (size_t)bc * 4096;
  float v = 0.f;
#pragma unroll
  for (int j = 0; j < 16; ++j) v += p[j * 256 + tid];
#pragma unroll
  for (int off = 32; off >= 1; off >>= 1) v += __shfl_down(v, off, 64);
  __shared__ float red[4];
  if ((tid & 63) == 0) red[tid >> 6] = v;
  __syncthreads();
  if (tid == 0) gap[bc] = (red[0] + red[1] + red[2] + red[3]) * (1.f / 4096.f);
}

// ---------------------------------------------------------------------------
__global__ __launch_bounds__(512)
void se_kernel(const float* __restrict__ gap,
               const float* __restrict__ wfc1, const float* __restrict__ bfc1,
               const float* __restrict__ wfc2, const float* __restrict__ bfc2,
               float* __restrict__ gate)
{
  const int b = blockIdx.x, tid = threadIdx.x;
  __shared__ float ylds[128];
  if (tid < 128) {
    float a = 0.f;
    for (int c = 0; c < 512; ++c) a += gap[b * 512 + c] * wfc1[tid * 512 + c];
    a += bfc1[tid];
    ylds[tid] = fminf(fmaxf(a, 0.f), 6.f);
  }
  __syncthreads();
  float g = 0.f;
  for (int j = 0; j < 128; ++j) g += ylds[j] * wfc2[tid * 128 + j];
  g += bfc2[tid];
  gate[b * 512 + tid] = 1.f / (1.f + __expf(-g));
}

// ---------------------------------------------------------------------------
// MFMA bf16 attention (swapped-QK^T, lane-local softmax, P-in-register PV),
// fused SE residual epilogue. Unchanged from round 2 (verified).
__global__ __launch_bounds__(512)
void attn_mfma_kernel(const float* __restrict__ x, const float* __restrict__ kv,
                      const float* __restrict__ gate, float* __restrict__ out)
{
  const int b = blockIdx.z, h = blockIdx.y;
  const int n0 = blockIdx.x * 128;
  const int tid = threadIdx.x;
  const int w = tid >> 6, lane = tid & 63;
  const int g = lane >> 4, nl = lane & 15;

  __shared__ unsigned lds[16 * 132 * 2 * 2 + 32 * 66 * 2];
  unsigned* Kp = lds;
  unsigned* Qp = lds + 16 * 132 * 2;
  unsigned* Vp = lds + 2 * 16 * 132 * 2;
  float* Osm = (float*)lds;

  const size_t xbh = ((size_t)b * 512 + h * 64) * 4096 + n0;
  const size_t kbh = ((size_t)b * 1024 + h * 64) * 256;
  const size_t vbh = ((size_t)b * 1024 + 512 + h * 64) * 256;

  {
    const int dq = tid >> 5, nq = (tid & 31) * 4;
    const float4 r0 = *(const float4*)(x + xbh + (size_t)(4 * dq + 0) * 4096 + nq);
    const float4 r1 = *(const float4*)(x + xbh + (size_t)(4 * dq + 1) * 4096 + nq);
    const float4 r2 = *(const float4*)(x + xbh + (size_t)(4 * dq + 2) * 4096 + nq);
    const float4 r3 = *(const float4*)(x + xbh + (size_t)(4 * dq + 3) * 4096 + nq);
    const float sc = 0.125f;
    uint4 w0, w1;
    w0.x = packbf(r0.x * sc, r1.x * sc); w0.y = packbf(r2.x * sc, r3.x * sc);
    w0.z = packbf(r0.y * sc, r1.y * sc); w0.w = packbf(r2.y * sc, r3.y * sc);
    w1.x = packbf(r0.z * sc, r1.z * sc); w1.y = packbf(r2.z * sc, r3.z * sc);
    w1.z = packbf(r0.w * sc, r1.w * sc); w1.w = packbf(r2.w * sc, r3.w * sc);
    *(uint4*)(Qp + (dq * 132 + nq) * 2)     = w0;
    *(uint4*)(Qp + (dq * 132 + nq + 2) * 2) = w1;
  }

  float m_run = -1e30f, l_run = 0.f;
  f32x4 o[4];
#pragma unroll
  for (int i = 0; i < 4; ++i) o[i] = (f32x4){0.f, 0.f, 0.f, 0.f};

#pragma unroll
  for (int ch = 0; ch < 2; ++ch) {
    const int m0 = ch * 128;
    __syncthreads();
    {
      const int dq = tid >> 5, mq = (tid & 31) * 4;
      const float4 r0 = *(const float4*)(kv + kbh + (size_t)(4 * dq + 0) * 256 + m0 + mq);
      const float4 r1 = *(const float4*)(kv + kbh + (size_t)(4 * dq + 1) * 256 + m0 + mq);
      const float4 r2 = *(const float4*)(kv + kbh + (size_t)(4 * dq + 2) * 256 + m0 + mq);
      const float4 r3 = *(const float4*)(kv + kbh + (size_t)(4 * dq + 3) * 256 + m0 + mq);
      uint4 w0, w1;
      w0.x = packbf(r0.x, r1.x); w0.y = packbf(r2.x, r3.x);
      w0.z = packbf(r0.y, r1.y); w0.w = packbf(r2.y, r3.y);
      w1.x = packbf(r0.z, r1.z); w1.y = packbf(r2.z, r3.z);
      w1.z = packbf(r0.w, r1.w); w1.w = packbf(r2.w, r3.w);
      *(uint4*)(Kp + (dq * 132 + mq) * 2)     = w0;
      *(uint4*)(Kp + (dq * 132 + mq + 2) * 2) = w1;
    }
    {
      const int mq = (tid & 31) * 4;
#pragma unroll
      for (int p = 0; p < 4; ++p) {
        const int d = (tid >> 5) + 16 * p;
        const float4 vv = *(const float4*)(kv + vbh + (size_t)d * 256 + m0 + mq);
        uint2 wv;
        wv.x = packbf(vv.x, vv.y);
        wv.y = packbf(vv.z, vv.w);
        *(uint2*)(Vp + ((mq >> 2) * 66 + d) * 2) = wv;
      }
    }
    __syncthreads();

    f32x4 s[8];
#pragma unroll
    for (int mb = 0; mb < 8; ++mb) s[mb] = (f32x4){0.f, 0.f, 0.f, 0.f};
#pragma unroll
    for (int ks = 0; ks < 2; ++ks) {
      FragU qf;
      {
        const uint2 lo = *(const uint2*)(Qp + ((8 * ks + g) * 132 + w * 16 + nl) * 2);
        const uint2 hi = *(const uint2*)(Qp + ((8 * ks + 4 + g) * 132 + w * 16 + nl) * 2);
        qf.u[0] = lo.x; qf.u[1] = lo.y; qf.u[2] = hi.x; qf.u[3] = hi.y;
      }
#pragma unroll
      for (int mb = 0; mb < 8; ++mb) {
        FragU kf;
        const uint2 lo = *(const uint2*)(Kp + ((8 * ks + g) * 132 + mb * 16 + nl) * 2);
        const uint2 hi = *(const uint2*)(Kp + ((8 * ks + 4 + g) * 132 + mb * 16 + nl) * 2);
        kf.u[0] = lo.x; kf.u[1] = lo.y; kf.u[2] = hi.x; kf.u[3] = hi.y;
        s[mb] = __builtin_amdgcn_mfma_f32_16x16x32_bf16(kf.v, qf.v, s[mb], 0, 0, 0);
      }
    }

    float cm = -1e30f;
#pragma unroll
    for (int mb = 0; mb < 8; ++mb)
#pragma unroll
      for (int r = 0; r < 4; ++r) cm = fmaxf(cm, s[mb][r]);
    cm = fmaxf(cm, __shfl_xor(cm, 16, 64));
    cm = fmaxf(cm, __shfl_xor(cm, 32, 64));
    const float mnew = fmaxf(m_run, cm);
    const float corr = __expf(m_run - mnew);
    m_run = mnew;
    float cs = 0.f;
#pragma unroll
    for (int mb = 0; mb < 8; ++mb)
#pragma unroll
      for (int r = 0; r < 4; ++r) {
        const float p = __expf(s[mb][r] - mnew);
        s[mb][r] = p;
        cs += p;
      }
    cs += __shfl_xor(cs, 16, 64);
    cs += __shfl_xor(cs, 32, 64);
    l_run = l_run * corr + cs;
#pragma unroll
    for (int db = 0; db < 4; ++db)
#pragma unroll
      for (int r = 0; r < 4; ++r) o[db][r] *= corr;

#pragma unroll
    for (int ks = 0; ks < 4; ++ks) {
      FragU pf;
      pf.u[0] = packbf(s[2 * ks][0],     s[2 * ks][1]);
      pf.u[1] = packbf(s[2 * ks][2],     s[2 * ks][3]);
      pf.u[2] = packbf(s[2 * ks + 1][0], s[2 * ks + 1][1]);
      pf.u[3] = packbf(s[2 * ks + 1][2], s[2 * ks + 1][3]);
#pragma unroll
      for (int db = 0; db < 4; ++db) {
        FragU vf;
        const uint2 lo = *(const uint2*)(Vp + ((8 * ks + g) * 66 + db * 16 + nl) * 2);
        const uint2 hi = *(const uint2*)(Vp + ((8 * ks + 4 + g) * 66 + db * 16 + nl) * 2);
        vf.u[0] = lo.x; vf.u[1] = lo.y; vf.u[2] = hi.x; vf.u[3] = hi.y;
        o[db] = __builtin_amdgcn_mfma_f32_16x16x32_bf16(vf.v, pf.v, o[db], 0, 0, 0);
      }
    }
  }

  const float inv = 1.f / l_run;
  __syncthreads();
#pragma unroll
  for (int db = 0; db < 4; ++db)
#pragma unroll
    for (int r = 0; r < 4; ++r)
      Osm[(db * 16 + 4 * g + r) * 130 + w * 16 + nl] = o[db][r] * inv;
  __syncthreads();

  {
    const int n = tid & 127;
#pragma unroll
    for (int i = 0; i < 16; ++i) {
      const int d = (tid >> 7) + 4 * i;
      const int c2 = h * 64 + d;
      const size_t off = ((size_t)b * 512 + c2) * 4096 + n0 + n;
      out[off] = Osm[d * 130 + n] + gate[b * 512 + c2] * x[off];
    }
  }
}

// ---------------------------------------------------------------------------
extern "C" void kernel_launch(void* const* d_in, const int* in_sizes, int n_in,
                              void* d_out, int out_size, void* d_ws, size_t ws_size,
                              hipStream_t stream)
{
  const float* x    = (const float*)d_in[0];
  const float* w01  = (const float*)d_in[1];
  const float* s01  = (const float*)d_in[2];
  const float* b01  = (const float*)d_in[3];
  const float* w02  = (const float*)d_in[4];
  const float* s02  = (const float*)d_in[5];
  const float* b02  = (const float*)d_in[6];
  const float* w03  = (const float*)d_in[7];
  const float* s03  = (const float*)d_in[8];
  const float* b03  = (const float*)d_in[9];
  const float* w12  = (const float*)d_in[10];
  const float* s12  = (const float*)d_in[11];
  const float* b12  = (const float*)d_in[12];
  const float* w13  = (const float*)d_in[13];
  const float* s13  = (const float*)d_in[14];
  const float* b13  = (const float*)d_in[15];
  const float* w22  = (const float*)d_in[16];
  const float* s22  = (const float*)d_in[17];
  const float* b22  = (const float*)d_in[18];
  const float* w23  = (const float*)d_in[19];
  const float* s23  = (const float*)d_in[20];
  const float* b23  = (const float*)d_in[21];
  const float* w3   = (const float*)d_in[22];
  const float* s3   = (const float*)d_in[23];
  const float* b3   = (const float*)d_in[24];
  const float* wkv  = (const float*)d_in[25];
  const float* skv  = (const float*)d_in[26];
  const float* bkv  = (const float*)d_in[27];
  const float* wfc1 = (const float*)d_in[28];
  const float* bfc1 = (const float*)d_in[29];
  const float* wfc2 = (const float*)d_in[30];
  const float* bfc2 = (const float*)d_in[31];

  float* out = (float*)d_out;
  unsigned* wsu = (unsigned*)d_ws;

  // ws layout (u32 words):
  unsigned* Timg   = wsu;                    // 1536 tiles * 4096 = 6,291,456
  float*    pooled = (float*)(wsu + 6291456);   // 1,048,576
  float*    kvbuf  = (float*)(wsu + 7340032);   // 2,097,152
  float*    gapb   = (float*)(wsu + 9437184);   // 4096
  float*    gateb  = (float*)(wsu + 9441280);   // 4096
  unsigned* Wimg   = wsu + 9445376;             // 524,288 words

  // d_out aliasing: A01p (8 MiB) then Bimg (32 MiB) then final out (64 MiB)
  unsigned* A01p = (unsigned*)d_out;
  unsigned* Bimg = (unsigned*)d_out;

  prepack_w_kernel<<<128, 256, 0, stream>>>(w01, w03, w13, w23, w3, wkv, Wimg);
  gemm_a01_kernel<<<dim3(32, 1, 8), 512, 0, stream>>>(x, Wimg, s01, b01, A01p);
  dwconv_pack_kernel<<<dim3(16, 128, 3), 256, 0, stream>>>(A01p, Timg,
      w02, s02, b02, w12, s12, b12, w22, s22, b22);
  gemm3branch_img_kernel<<<dim3(32, 4, 8), 512, 0, stream>>>(Timg, Wimg + 32768,
      s03, s13, s23, b03, b13, b23, Bimg);
  hipMemsetAsync(pooled, 0, (size_t)1048576 * sizeof(float), stream);
  gemm_pool_img_kernel<<<dim3(32, 4, 8), 512, 0, stream>>>(Bimg, Wimg + 131072,
      s3, b3, x, pooled);
  gemm_kv_kernel<<<dim3(2, 8, 8), 512, 0, stream>>>(pooled, Wimg + 262144, skv, bkv, kvbuf);
  gap_kernel<<<4096, 256, 0, stream>>>(x, gapb);
  se_kernel<<<8, 512, 0, stream>>>(gapb, wfc1, bfc1, wfc2, bfc2, gateb);
  attn_mfma_kernel<<<dim3(32, 8, 8), 512, 0, stream>>>(x, kvbuf, gateb, out);
}

// Round 5
// 280.021 us; speedup vs baseline: 4.3885x; 1.0634x over previous
//
#include <hip/hip_runtime.h>
#include <cstddef>

// ---------------------------------------------------------------------------
// _Mutilscal_MHSA — round 5: producer-packed attention operands.
// - gemm_kv writes K img tiles (x0.125 folded) + V tiles in PV layout;
//   attn stages K/V via global_load_lds (double-buffered), Q once (img),
//   epilogue reads x back from the Q LDS tile (no second HBM pass).
// - all img-tile staging in GEMMs uses global_load_lds width=16.
// img layout: word ((r4*128+pos)<<2) + sub*2 + j, kq=(r4&3)+sub*4+(r4>>3? see
// code), pair j = bf16 (k=4kq+2j, +1). One fragment = one ds_read_b128.
// ---------------------------------------------------------------------------

static __device__ __forceinline__ float silu_f(float v) {
  return v / (1.f + __expf(-v));
}

typedef __attribute__((ext_vector_type(8))) short short8v;   // bf16x8 frag
typedef __attribute__((ext_vector_type(4))) float f32x4;     // MFMA acc

union FragU { unsigned u[4]; short8v v; uint4 q; };

static __device__ __forceinline__ unsigned short f2bf(float f) {
  unsigned u = __builtin_bit_cast(unsigned, f);
  u += 0x7fffu + ((u >> 16) & 1u);           // round-to-nearest-even
  return (unsigned short)(u >> 16);
}
static __device__ __forceinline__ unsigned packbf(float lo, float hi) {
  return (unsigned)f2bf(lo) | ((unsigned)f2bf(hi) << 16);
}
static __device__ __forceinline__ float bf_lo(unsigned w) {
  return __builtin_bit_cast(float, w << 16);
}
static __device__ __forceinline__ float bf_hi(unsigned w) {
  return __builtin_bit_cast(float, w & 0xffff0000u);
}

// async global->LDS, 16 B per lane (dest must be wave-linear: base + lane*16)
static __device__ __forceinline__ void gload16(const unsigned* gsrc, unsigned* ldst) {
  __builtin_amdgcn_global_load_lds(
      (const __attribute__((address_space(1))) unsigned*)gsrc,
      (__attribute__((address_space(3))) unsigned*)ldst, 16, 0, 0);
}

// stage one 4096-word img tile via global_load_lds (512 threads, 2x16B each)
static __device__ __forceinline__ void stage_tile_g(const unsigned* __restrict__ src,
                                                    unsigned* dst, int tid) {
  gload16(src + 4 * tid, dst + 4 * tid);
  gload16(src + 4 * (tid + 512), dst + 4 * (tid + 512));
}

// one fragment = one b128 read
static __device__ __forceinline__ short8v load_frag4(const unsigned* P, int ksg, int pos) {
  FragU f;
  f.q = *(const uint4*)(P + (((ksg << 7) + pos) << 2));
  return f.v;
}

// stage a 64k x 128pos fp32 operand into LDS img layout (pack on the fly)
static __device__ __forceinline__ void stage_x_pack(const float* __restrict__ src, int ld,
                                                    unsigned* Xp, int tid) {
  const int pos = tid & 127, kg = tid >> 7;          // kg: k rows kg*16..+15
  const float* p = src + pos + (size_t)(kg * 16) * ld;
  float v[16];
#pragma unroll
  for (int i = 0; i < 16; ++i) v[i] = p[(size_t)i * ld];
#pragma unroll
  for (int i2 = 0; i2 < 4; ++i2) {
    const int kq = kg * 4 + i2;
    const int r4 = (kq & 3) + ((kq >> 3) << 2);
    const int sub = (kq >> 2) & 1;
    uint2 wv;
    wv.x = packbf(v[i2 * 4 + 0], v[i2 * 4 + 1]);
    wv.y = packbf(v[i2 * 4 + 2], v[i2 * 4 + 3]);
    *(uint2*)(Xp + (((r4 << 7) + pos) << 2) + sub * 2) = wv;
  }
}

#define GEMM_IDS                                            \
  const int tid = threadIdx.x;                              \
  const int w = tid >> 6, lane = tid & 63;                  \
  const int g = lane >> 4, nl = lane & 15;                  \
  const int wr = w >> 1, wc = w & 1;

#define GEMM_KSTEP(ACC)                                                            \
  _Pragma("unroll")                                                                \
  for (int ks = 0; ks < 2; ++ks) {                                                 \
    const short8v a0 = load_frag4(Wp, ks * 4 + g, wr * 32 + nl);                   \
    const short8v a1 = load_frag4(Wp, ks * 4 + g, wr * 32 + 16 + nl);              \
    _Pragma("unroll")                                                              \
    for (int jj = 0; jj < 4; ++jj) {                                               \
      const short8v bfr = load_frag4(Xp, ks * 4 + g, wc * 64 + jj * 16 + nl);      \
      ACC[0][jj] = __builtin_amdgcn_mfma_f32_16x16x32_bf16(a0, bfr, ACC[0][jj], 0, 0, 0); \
      ACC[1][jj] = __builtin_amdgcn_mfma_f32_16x16x32_bf16(a1, bfr, ACC[1][jj], 0, 0, 0); \
    }                                                                              \
  }

// ---------------------------------------------------------------------------
// Weight prepack: fp32 W[OC][K] -> img tiles (tile = to*(K/64)+tk).
__global__ __launch_bounds__(256)
void prepack_w_kernel(const float* __restrict__ w01, const float* __restrict__ w03,
                      const float* __restrict__ w13, const float* __restrict__ w23,
                      const float* __restrict__ w3, const float* __restrict__ wkv,
                      unsigned* __restrict__ img)
{
  const int t = blockIdx.x;
  const float* W; int K; int tile; unsigned* base;
  if (t < 8)       { W = w01; K = 512; tile = t;      base = img; }
  else if (t < 16) { W = w03; K = 128; tile = t - 8;  base = img + 32768; }
  else if (t < 24) { W = w13; K = 128; tile = t - 16; base = img + 65536; }
  else if (t < 32) { W = w23; K = 128; tile = t - 24; base = img + 98304; }
  else if (t < 64) { W = w3;  K = 512; tile = t - 32; base = img + 131072; }
  else             { W = wkv; K = 512; tile = t - 64; base = img + 262144; }
  const int nk = K >> 6;
  const int to = tile / nk, tk = tile - to * nk;
  unsigned* dst = base + (size_t)tile * 4096;
  for (int wi = threadIdx.x; wi < 4096; wi += 256) {
    const int r4 = wi >> 9, pos = (wi >> 2) & 127, sub = (wi >> 1) & 1, j = wi & 1;
    const int kq = (r4 & 3) + sub * 4 + ((r4 >> 2) << 3);
    const int k = tk * 64 + 4 * kq + 2 * j;
    const int oc = to * 128 + pos;
    dst[wi] = packbf(W[(size_t)oc * K + k], W[(size_t)oc * K + k + 1]);
  }
}

// ---------------------------------------------------------------------------
// a01 = silu(s01*(w01@x)+b01) as packed bf16 pairs A01p[b][c2][p].
__global__ __launch_bounds__(512)
void gemm_a01_kernel(const float* __restrict__ X, const unsigned* __restrict__ Wimg,
                     const float* __restrict__ sc, const float* __restrict__ bi,
                     unsigned* __restrict__ A01p)
{
  const int b = blockIdx.z, p0 = blockIdx.x * 128;
  GEMM_IDS
  __shared__ unsigned Xp[4096], Wp[4096];

  f32x4 acc[2][4];
#pragma unroll
  for (int i = 0; i < 2; ++i)
#pragma unroll
    for (int jj = 0; jj < 4; ++jj) acc[i][jj] = (f32x4){0.f, 0.f, 0.f, 0.f};

  for (int ks8 = 0; ks8 < 8; ++ks8) {
    __syncthreads();
    stage_x_pack(X + (size_t)b * 512 * 4096 + (size_t)(ks8 * 64) * 4096 + p0, 4096, Xp, tid);
    stage_tile_g(Wimg + (size_t)ks8 * 4096, Wp, tid);
    __syncthreads();
    GEMM_KSTEP(acc)
  }

#pragma unroll
  for (int i = 0; i < 2; ++i) {
    const int base = wr * 32 + i * 16 + 4 * g;
    const float s0_ = sc[base + 0], b0_ = bi[base + 0];
    const float s1_ = sc[base + 1], b1_ = bi[base + 1];
    const float s2_ = sc[base + 2], b2_ = bi[base + 2];
    const float s3_ = sc[base + 3], b3_ = bi[base + 3];
#pragma unroll
    for (int jj = 0; jj < 4; ++jj) {
      const int pos = p0 + wc * 64 + jj * 16 + nl;
      const float v0 = silu_f(s0_ * acc[i][jj][0] + b0_);
      const float v1 = silu_f(s1_ * acc[i][jj][1] + b1_);
      const float v2 = silu_f(s2_ * acc[i][jj][2] + b2_);
      const float v3 = silu_f(s3_ * acc[i][jj][3] + b3_);
      A01p[((size_t)b * 64 + (base >> 1)) * 4096 + pos]     = packbf(v0, v1);
      A01p[((size_t)b * 64 + (base >> 1) + 1) * 4096 + pos] = packbf(v2, v3);
    }
  }
}

// ---------------------------------------------------------------------------
// Depthwise dilated 3x3 + SiLU on packed a01; writes T img tiles directly.
__global__ __launch_bounds__(256)
void dwconv_pack_kernel(const unsigned* __restrict__ A01p, unsigned* __restrict__ Timg,
                        const float* __restrict__ w02, const float* __restrict__ s02, const float* __restrict__ b02,
                        const float* __restrict__ w12, const float* __restrict__ s12, const float* __restrict__ b12,
                        const float* __restrict__ w22, const float* __restrict__ s22, const float* __restrict__ b22)
{
  const int br = blockIdx.z;
  const int yb = blockIdx.y;
  const int b = yb >> 4, t16 = yb & 15, kstep = t16 >> 3, mm = t16 & 7;
  const int kq = (mm & 3) + ((mm >> 2) << 3);
  const int cbase = kstep * 64 + kq * 4;
  const int p = blockIdx.x * 256 + threadIdx.x;
  const int y = p >> 6, xx = p & 63;
  const int d = 3 + 2 * br;

  const float* wsel = br == 0 ? w02 : (br == 1 ? w12 : w22);
  const float* ssel = br == 0 ? s02 : (br == 1 ? s12 : s22);
  const float* bsel = br == 0 ? b02 : (br == 1 ? b12 : b22);

  float sum[8] = {};
  const unsigned* plane0 = A01p + ((size_t)b * 64 + (cbase >> 1)) * 4096;

#pragma unroll
  for (int u = -1; u <= 1; ++u) {
    const int yv = y + u * d;
    if ((unsigned)yv < 64u) {
#pragma unroll
      for (int v = -1; v <= 1; ++v) {
        const int xv = xx + v * d;
        if ((unsigned)xv < 64u) {
          const int idx = yv * 64 + xv;
          const int tap = (u + 1) * 3 + (v + 1);
#pragma unroll
          for (int q = 0; q < 4; ++q) {
            const int sub = q >> 1, jw = q & 1;
            const unsigned wv = plane0[(size_t)(sub * 8 + jw) * 4096 + idx];
            const int ch = cbase + sub * 16 + jw * 2;
            sum[q * 2 + 0] += wsel[(ch + 0) * 9 + tap] * bf_lo(wv);
            sum[q * 2 + 1] += wsel[(ch + 1) * 9 + tap] * bf_hi(wv);
          }
        }
      }
    }
  }

  unsigned wout[4];
#pragma unroll
  for (int h = 0; h < 4; ++h) {
    const int ch = cbase + (h >> 1) * 16 + (h & 1) * 2;
    const float va = silu_f(ssel[ch] * sum[h * 2] + bsel[ch]);
    const float vb = silu_f(ssel[ch + 1] * sum[h * 2 + 1] + bsel[ch + 1]);
    wout[h] = packbf(va, vb);
  }
  const int tile = ((br * 8 + b) * 2 + kstep) * 32 + (p >> 7);
  *(uint4*)(Timg + (size_t)tile * 4096 + (((mm << 7) + (p & 127)) << 2)) = *(uint4*)wout;
}

// ---------------------------------------------------------------------------
// B = sum_i silu(s_i*(W_i @ t_i)+b_i), written as B img tiles.
__global__ __launch_bounds__(512)
void gemm3branch_img_kernel(const unsigned* __restrict__ Timg, const unsigned* __restrict__ Wimg3,
                            const float* __restrict__ s0, const float* __restrict__ s1, const float* __restrict__ s2,
                            const float* __restrict__ b0, const float* __restrict__ b1, const float* __restrict__ b2,
                            unsigned* __restrict__ Bimg)
{
  const int b = blockIdx.z, pt = blockIdx.x, oc0 = blockIdx.y * 128;
  GEMM_IDS
  __shared__ unsigned Xp[4096], Wp[4096];

  float sum[2][4][4] = {};

#pragma unroll
  for (int brn = 0; brn < 3; ++brn) {
    const float* ss = brn == 0 ? s0 : (brn == 1 ? s1 : s2);
    const float* bs = brn == 0 ? b0 : (brn == 1 ? b1 : b2);

    f32x4 acc[2][4];
#pragma unroll
    for (int i = 0; i < 2; ++i)
#pragma unroll
      for (int jj = 0; jj < 4; ++jj) acc[i][jj] = (f32x4){0.f, 0.f, 0.f, 0.f};

#pragma unroll
    for (int ksx = 0; ksx < 2; ++ksx) {
      __syncthreads();
      stage_tile_g(Timg + (((size_t)(brn * 8 + b) * 2 + ksx) * 32 + pt) * 4096, Xp, tid);
      stage_tile_g(Wimg3 + (size_t)brn * 32768 + ((size_t)(oc0 >> 7) * 2 + ksx) * 4096, Wp, tid);
      __syncthreads();
      GEMM_KSTEP(acc)
    }

#pragma unroll
    for (int i = 0; i < 2; ++i) {
      const int base = oc0 + wr * 32 + i * 16 + 4 * g;
#pragma unroll
      for (int r = 0; r < 4; ++r) {
        const float s = ss[base + r], bb = bs[base + r];
#pragma unroll
        for (int jj = 0; jj < 4; ++jj)
          sum[i][jj][r] += silu_f(s * acc[i][jj][r] + bb);
      }
    }
  }

#pragma unroll
  for (int i = 0; i < 2; ++i) {
    const int ol = wr * 32 + i * 16 + 4 * g;
    const int kstep_g = (oc0 + ol) >> 6;
    const int kin = ol & 63;
    const int kq2 = kin >> 2;
    const int r4 = (kq2 & 3) + ((kq2 >> 3) << 2);
    const int sub = (kq2 >> 2) & 1;
#pragma unroll
    for (int jj = 0; jj < 4; ++jj) {
      const int pos = wc * 64 + jj * 16 + nl;
      uint2 wv;
      wv.x = packbf(sum[i][jj][0], sum[i][jj][1]);
      wv.y = packbf(sum[i][jj][2], sum[i][jj][3]);
      *(uint2*)(Bimg + ((size_t)(b * 8 + kstep_g) * 32 + pt) * 4096 + (((r4 << 7) + pos) << 2) + sub * 2) = wv;
    }
  }
}

// ---------------------------------------------------------------------------
// w3 GEMM (512->512) from B img + fused silu*x + 4x4 block-mean pool.
__global__ __launch_bounds__(512)
void gemm_pool_img_kernel(const unsigned* __restrict__ Bimg, const unsigned* __restrict__ W3img,
                          const float* __restrict__ sc, const float* __restrict__ bi,
                          const float* __restrict__ xin, float* __restrict__ pooled)
{
  const int b = blockIdx.z, pt = blockIdx.x, oc0 = blockIdx.y * 128;
  const int p0 = pt * 128;
  const float* xb = xin + (size_t)b * 512 * 4096;
  GEMM_IDS
  __shared__ unsigned Xp[4096], Wp[4096];

  f32x4 acc[2][4];
#pragma unroll
  for (int i = 0; i < 2; ++i)
#pragma unroll
    for (int jj = 0; jj < 4; ++jj) acc[i][jj] = (f32x4){0.f, 0.f, 0.f, 0.f};

  for (int ks8 = 0; ks8 < 8; ++ks8) {
    __syncthreads();
    stage_tile_g(Bimg + ((size_t)(b * 8 + ks8) * 32 + pt) * 4096, Xp, tid);
    stage_tile_g(W3img + ((size_t)(oc0 >> 7) * 8 + ks8) * 4096, Wp, tid);
    __syncthreads();
    GEMM_KSTEP(acc)
  }

#pragma unroll
  for (int i = 0; i < 2; ++i)
#pragma unroll
    for (int r = 0; r < 4; ++r) {
      const int oc = oc0 + wr * 32 + i * 16 + 4 * g + r;
      const float s = sc[oc], bb = bi[oc];
#pragma unroll
      for (int jj = 0; jj < 4; ++jj) {
        const int p = p0 + wc * 64 + jj * 16 + nl;
        float val = silu_f(s * acc[i][jj][r] + bb) * xb[(size_t)oc * 4096 + p];
        val += __shfl_xor(val, 1, 64);
        val += __shfl_xor(val, 2, 64);
        if ((nl & 3) == 0) {
          const int y = p >> 6, col = p & 63;
          atomicAdd(&pooled[((size_t)b * 512 + oc) * 256 + (y >> 2) * 16 + (col >> 2)],
                    val * (1.f / 16.f));
        }
      }
    }
}

// ---------------------------------------------------------------------------
// kv GEMM: writes K img tiles (x0.125 folded, attn QK layout) and V tiles
// (attn PV layout [m4][d][pair]). grid (2, 8, 8), block 512.
// K tile (b,h,ch): word ((r4<<7)+ml)<<2 + sub*2 + j  (kq = d>>2)
// V tile (b,h,ch): word (m4*64+d)*2 + s = pair (m=4*m4+2s, +1)
__global__ __launch_bounds__(512)
void gemm_kv_kernel(const float* __restrict__ X, const unsigned* __restrict__ WKVimg,
                    const float* __restrict__ sc, const float* __restrict__ bi,
                    unsigned* __restrict__ Kimg, unsigned* __restrict__ Vimg)
{
  const int b = blockIdx.z, p0 = blockIdx.x * 128, oc0 = blockIdx.y * 128;
  const float* Xb = X + (size_t)b * 512 * 256;
  GEMM_IDS
  __shared__ unsigned Xp[4096], Wp[4096];

  f32x4 acc[2][4];
#pragma unroll
  for (int i = 0; i < 2; ++i)
#pragma unroll
    for (int jj = 0; jj < 4; ++jj) acc[i][jj] = (f32x4){0.f, 0.f, 0.f, 0.f};

  for (int ks8 = 0; ks8 < 8; ++ks8) {
    __syncthreads();
    stage_x_pack(Xb + (size_t)(ks8 * 64) * 256 + p0, 256, Xp, tid);
    stage_tile_g(WKVimg + ((size_t)(oc0 >> 7) * 8 + ks8) * 4096, Wp, tid);
    __syncthreads();
    GEMM_KSTEP(acc)
  }

  const bool isK = (oc0 < 512);
#pragma unroll
  for (int i = 0; i < 2; ++i) {
    const int ocb = oc0 + wr * 32 + i * 16 + 4 * g;     // 4-channel quad base
#pragma unroll
    for (int jj = 0; jj < 4; ++jj) {
      const int pos = p0 + wc * 64 + jj * 16 + nl;
      float v[4];
#pragma unroll
      for (int r = 0; r < 4; ++r)
        v[r] = silu_f(sc[ocb + r] * acc[i][jj][r] + bi[ocb + r]);
      const int ch = pos >> 7, ml = pos & 127;
      if (isK) {
        const int h = ocb >> 6, d0 = ocb & 63;
        const int kq = d0 >> 2, sub = (kq >> 2) & 1;
        const int r4 = (kq & 3) + ((kq >> 3) << 2);
        unsigned* t = Kimg + ((size_t)(b * 8 + h) * 2 + ch) * 4096;
        uint2 wv;
        wv.x = packbf(v[0] * 0.125f, v[1] * 0.125f);
        wv.y = packbf(v[2] * 0.125f, v[3] * 0.125f);
        *(uint2*)(t + (((r4 << 7) + ml) << 2) + sub * 2) = wv;
      } else {
        const int h = (ocb - 512) >> 6, d0 = (ocb - 512) & 63;
        unsigned* t = Vimg + ((size_t)(b * 8 + h) * 2 + ch) * 4096;
        float ov[4];
#pragma unroll
        for (int r = 0; r < 4; ++r) ov[r] = __shfl_xor(v[r], 1, 64);
        if ((nl & 1) == 0) {
          const int s = (ml >> 1) & 1, m4 = ml >> 2;
#pragma unroll
          for (int r = 0; r < 4; ++r)
            t[((m4 * 64 + d0 + r) << 1) + s] = packbf(v[r], ov[r]);
        }
      }
    }
  }
}

// ---------------------------------------------------------------------------
__global__ __launch_bounds__(256)
void gap_kernel(const float* __restrict__ x, float* __restrict__ gap)
{
  const int bc = blockIdx.x;
  const int tid = threadIdx.x;
  const float* p = x + (size_t)bc * 4096;
  float v = 0.f;
#pragma unroll
  for (int j = 0; j < 16; ++j) v += p[j * 256 + tid];
#pragma unroll
  for (int off = 32; off >= 1; off >>= 1) v += __shfl_down(v, off, 64);
  __shared__ float red[4];
  if ((tid & 63) == 0) red[tid >> 6] = v;
  __syncthreads();
  if (tid == 0) gap[bc] = (red[0] + red[1] + red[2] + red[3]) * (1.f / 4096.f);
}

// ---------------------------------------------------------------------------
__global__ __launch_bounds__(512)
void se_kernel(const float* __restrict__ gap,
               const float* __restrict__ wfc1, const float* __restrict__ bfc1,
               const float* __restrict__ wfc2, const float* __restrict__ bfc2,
               float* __restrict__ gate)
{
  const int b = blockIdx.x, tid = threadIdx.x;
  __shared__ float ylds[128];
  if (tid < 128) {
    float a = 0.f;
    for (int c = 0; c < 512; ++c) a += gap[b * 512 + c] * wfc1[tid * 512 + c];
    a += bfc1[tid];
    ylds[tid] = fminf(fmaxf(a, 0.f), 6.f);
  }
  __syncthreads();
  float g = 0.f;
  for (int j = 0; j < 128; ++j) g += ylds[j] * wfc2[tid * 128 + j];
  g += bfc2[tid];
  gate[b * 512 + tid] = 1.f / (1.f + __expf(-g));
}

// ---------------------------------------------------------------------------
// MFMA bf16 attention v3: K/V pre-packed by gemm_kv (K pre-scaled), staged
// via global_load_lds with chunk double-buffer; Q staged once in img layout;
// epilogue reads x back from Q LDS (no 2nd HBM pass). out = O/l + gate*x.
__global__ __launch_bounds__(512)
void attn_mfma_kernel(const float* __restrict__ x, const unsigned* __restrict__ Kimg,
                      const unsigned* __restrict__ Vimg,
                      const float* __restrict__ gate, float* __restrict__ out)
{
  const int b = blockIdx.z, h = blockIdx.y;
  const int n0 = blockIdx.x * 128;
  const int tid = threadIdx.x;
  const int w = tid >> 6, lane = tid & 63;
  const int g = lane >> 4, nl = lane & 15;

  __shared__ unsigned lds[20480];          // Qp | K0 | K1 | V0 | V1 (80 KB)
  unsigned* Qp = lds;
  unsigned* Kb0 = lds + 4096;
  unsigned* Kb1 = lds + 8192;
  unsigned* Vb0 = lds + 12288;
  unsigned* Vb1 = lds + 16384;
  float* Osm = (float*)(lds + 4096);       // [64][132] overlay on K0/K1/V0-head

  const size_t tbase = (size_t)(b * 8 + h) * 2 * 4096;

  // issue chunk-0 K/V loads, stage Q (unscaled bf16, img layout)
  stage_tile_g(Kimg + tbase, Kb0, tid);
  stage_tile_g(Vimg + tbase, Vb0, tid);
  stage_x_pack(x + ((size_t)b * 512 + h * 64) * 4096 + n0, 4096, Qp, tid);
  __syncthreads();
  // prefetch chunk-1 while computing chunk 0
  stage_tile_g(Kimg + tbase + 4096, Kb1, tid);
  stage_tile_g(Vimg + tbase + 4096, Vb1, tid);

  float m_run = -1e30f, l_run = 0.f;
  f32x4 o[4];
#pragma unroll
  for (int i = 0; i < 4; ++i) o[i] = (f32x4){0.f, 0.f, 0.f, 0.f};

#pragma unroll
  for (int ch = 0; ch < 2; ++ch) {
    const unsigned* Kp = ch ? Kb1 : Kb0;
    const unsigned* Vp = ch ? Vb1 : Vb0;

    // ---- S^T = K . Q^T ----
    f32x4 s[8];
#pragma unroll
    for (int mb = 0; mb < 8; ++mb) s[mb] = (f32x4){0.f, 0.f, 0.f, 0.f};
#pragma unroll
    for (int ks = 0; ks < 2; ++ks) {
      const short8v qf = load_frag4(Qp, ks * 4 + g, w * 16 + nl);
#pragma unroll
      for (int mb = 0; mb < 8; ++mb) {
        const short8v kf = load_frag4(Kp, ks * 4 + g, mb * 16 + nl);
        s[mb] = __builtin_amdgcn_mfma_f32_16x16x32_bf16(kf, qf, s[mb], 0, 0, 0);
      }
    }

    // ---- online softmax (lane owns q-col) ----
    float cm = -1e30f;
#pragma unroll
    for (int mb = 0; mb < 8; ++mb)
#pragma unroll
      for (int r = 0; r < 4; ++r) cm = fmaxf(cm, s[mb][r]);
    cm = fmaxf(cm, __shfl_xor(cm, 16, 64));
    cm = fmaxf(cm, __shfl_xor(cm, 32, 64));
    const float mnew = fmaxf(m_run, cm);
    const float corr = __expf(m_run - mnew);
    m_run = mnew;
    float cs = 0.f;
#pragma unroll
    for (int mb = 0; mb < 8; ++mb)
#pragma unroll
      for (int r = 0; r < 4; ++r) {
        const float p = __expf(s[mb][r] - mnew);
        s[mb][r] = p;
        cs += p;
      }
    cs += __shfl_xor(cs, 16, 64);
    cs += __shfl_xor(cs, 32, 64);
    l_run = l_run * corr + cs;
#pragma unroll
    for (int db = 0; db < 4; ++db)
#pragma unroll
      for (int r = 0; r < 4; ++r) o[db][r] *= corr;

    // ---- O^T += V^T . P^T ----
#pragma unroll
    for (int ks = 0; ks < 4; ++ks) {
      FragU pf;
      pf.u[0] = packbf(s[2 * ks][0],     s[2 * ks][1]);
      pf.u[1] = packbf(s[2 * ks][2],     s[2 * ks][3]);
      pf.u[2] = packbf(s[2 * ks + 1][0], s[2 * ks + 1][1]);
      pf.u[3] = packbf(s[2 * ks + 1][2], s[2 * ks + 1][3]);
#pragma unroll
      for (int db = 0; db < 4; ++db) {
        FragU vf;
        const uint2 lo = *(const uint2*)(Vp + ((8 * ks + g) * 64 + db * 16 + nl) * 2);
        const uint2 hi = *(const uint2*)(Vp + ((8 * ks + 4 + g) * 64 + db * 16 + nl) * 2);
        vf.u[0] = lo.x; vf.u[1] = lo.y; vf.u[2] = hi.x; vf.u[3] = hi.y;
        o[db] = __builtin_amdgcn_mfma_f32_16x16x32_bf16(vf.v, pf.v, o[db], 0, 0, 0);
      }
    }
    __syncthreads();   // ch0: chunk-1 staged (vmcnt drained); ch1: guard Osm
  }

  // ---- O^T -> Osm (coalescing), epilogue x from Qp ----
  const float inv = 1.f / l_run;
#pragma unroll
  for (int db = 0; db < 4; ++db)
#pragma unroll
    for (int r = 0; r < 4; ++r)
      Osm[(db * 16 + 4 * g + r) * 132 + w * 16 + nl] = o[db][r] * inv;
  __syncthreads();

  {
    const int n = tid & 127, t7 = tid >> 7;
    const int jw = t7 >> 1, half = t7 & 1;
#pragma unroll
    for (int i = 0; i < 16; ++i) {
      const int d = t7 + 4 * i;                 // kq = i
      const int r4 = (i & 3) + ((i >> 3) << 2);
      const int sub = (i >> 2) & 1;
      const unsigned xw = Qp[(((r4 << 7) + n) << 2) + sub * 2 + jw];
      const float xv = half ? bf_hi(xw) : bf_lo(xw);
      const int c2 = h * 64 + d;
      const size_t off = ((size_t)b * 512 + c2) * 4096 + n0 + n;
      out[off] = Osm[d * 132 + n] + gate[b * 512 + c2] * xv;
    }
  }
}

// ---------------------------------------------------------------------------
extern "C" void kernel_launch(void* const* d_in, const int* in_sizes, int n_in,
                              void* d_out, int out_size, void* d_ws, size_t ws_size,
                              hipStream_t stream)
{
  const float* x    = (const float*)d_in[0];
  const float* w01  = (const float*)d_in[1];
  const float* s01  = (const float*)d_in[2];
  const float* b01  = (const float*)d_in[3];
  const float* w02  = (const float*)d_in[4];
  const float* s02  = (const float*)d_in[5];
  const float* b02  = (const float*)d_in[6];
  const float* w03  = (const float*)d_in[7];
  const float* s03  = (const float*)d_in[8];
  const float* b03  = (const float*)d_in[9];
  const float* w12  = (const float*)d_in[10];
  const float* s12  = (const float*)d_in[11];
  const float* b12  = (const float*)d_in[12];
  const float* w13  = (const float*)d_in[13];
  const float* s13  = (const float*)d_in[14];
  const float* b13  = (const float*)d_in[15];
  const float* w22  = (const float*)d_in[16];
  const float* s22  = (const float*)d_in[17];
  const float* b22  = (const float*)d_in[18];
  const float* w23  = (const float*)d_in[19];
  const float* s23  = (const float*)d_in[20];
  const float* b23  = (const float*)d_in[21];
  const float* w3   = (const float*)d_in[22];
  const float* s3   = (const float*)d_in[23];
  const float* b3   = (const float*)d_in[24];
  const float* wkv  = (const float*)d_in[25];
  const float* skv  = (const float*)d_in[26];
  const float* bkv  = (const float*)d_in[27];
  const float* wfc1 = (const float*)d_in[28];
  const float* bfc1 = (const float*)d_in[29];
  const float* wfc2 = (const float*)d_in[30];
  const float* bfc2 = (const float*)d_in[31];

  float* out = (float*)d_out;
  unsigned* wsu = (unsigned*)d_ws;

  // ws layout (u32 words):
  unsigned* Timg   = wsu;                        // 1536*4096 = 6,291,456
  float*    pooled = (float*)(wsu + 6291456);    // 1,048,576
  unsigned* Kimg   = wsu + 7340032;              //   524,288
  unsigned* Vimg   = wsu + 7864320;              //   524,288
  float*    gapb   = (float*)(wsu + 8388608);    //     4,096
  float*    gateb  = (float*)(wsu + 8392704);    //     4,096
  unsigned* Wimg   = wsu + 8396800;              //   524,288  (end 8,921,088 w = 34 MiB)

  unsigned* A01p = (unsigned*)d_out;   // [8,64,4096] packed, dead after dwconv
  unsigned* Bimg = (unsigned*)d_out;   // 256 img tiles, dead after pool

  prepack_w_kernel<<<128, 256, 0, stream>>>(w01, w03, w13, w23, w3, wkv, Wimg);
  gemm_a01_kernel<<<dim3(32, 1, 8), 512, 0, stream>>>(x, Wimg, s01, b01, A01p);
  dwconv_pack_kernel<<<dim3(16, 128, 3), 256, 0, stream>>>(A01p, Timg,
      w02, s02, b02, w12, s12, b12, w22, s22, b22);
  gemm3branch_img_kernel<<<dim3(32, 4, 8), 512, 0, stream>>>(Timg, Wimg + 32768,
      s03, s13, s23, b03, b13, b23, Bimg);
  hipMemsetAsync(pooled, 0, (size_t)1048576 * sizeof(float), stream);
  gemm_pool_img_kernel<<<dim3(32, 4, 8), 512, 0, stream>>>(Bimg, Wimg + 131072,
      s3, b3, x, pooled);
  gemm_kv_kernel<<<dim3(2, 8, 8), 512, 0, stream>>>(pooled, Wimg + 262144, skv, bkv, Kimg, Vimg);
  gap_kernel<<<4096, 256, 0, stream>>>(x, gapb);
  se_kernel<<<8, 512, 0, stream>>>(gapb, wfc1, bfc1, wfc2, bfc2, gateb);
  attn_mfma_kernel<<<dim3(32, 8, 8), 512, 0, stream>>>(x, Kimg, Vimg, gateb, out);
}

// Round 6
// 256.340 us; speedup vs baseline: 4.7939x; 1.0924x over previous
//
#include <hip/hip_runtime.h>
#include <cstddef>

// ---------------------------------------------------------------------------
// _Mutilscal_MHSA — round 6: 2-phase double-buffered staging in all MFMA
// GEMMs (issue next-tile global_load_lds BEFORE current K-step's MFMAs; one
// barrier per step). Reg-staged fp32 operands use issue-early/write-late.
// Everything else identical to round 5 (verified).
// ---------------------------------------------------------------------------

static __device__ __forceinline__ float silu_f(float v) {
  return v / (1.f + __expf(-v));
}

typedef __attribute__((ext_vector_type(8))) short short8v;   // bf16x8 frag
typedef __attribute__((ext_vector_type(4))) float f32x4;     // MFMA acc

union FragU { unsigned u[4]; short8v v; uint4 q; };

static __device__ __forceinline__ unsigned short f2bf(float f) {
  unsigned u = __builtin_bit_cast(unsigned, f);
  u += 0x7fffu + ((u >> 16) & 1u);           // round-to-nearest-even
  return (unsigned short)(u >> 16);
}
static __device__ __forceinline__ unsigned packbf(float lo, float hi) {
  return (unsigned)f2bf(lo) | ((unsigned)f2bf(hi) << 16);
}
static __device__ __forceinline__ float bf_lo(unsigned w) {
  return __builtin_bit_cast(float, w << 16);
}
static __device__ __forceinline__ float bf_hi(unsigned w) {
  return __builtin_bit_cast(float, w & 0xffff0000u);
}

// async global->LDS, 16 B per lane (dest wave-linear: base + lane*16)
static __device__ __forceinline__ void gload16(const unsigned* gsrc, unsigned* ldst) {
  __builtin_amdgcn_global_load_lds(
      (const __attribute__((address_space(1))) unsigned*)gsrc,
      (__attribute__((address_space(3))) unsigned*)ldst, 16, 0, 0);
}

// stage one 4096-word img tile via global_load_lds (512 threads, 2x16B each)
static __device__ __forceinline__ void stage_tile_g(const unsigned* __restrict__ src,
                                                    unsigned* dst, int tid) {
  gload16(src + 4 * tid, dst + 4 * tid);
  gload16(src + 4 * (tid + 512), dst + 4 * (tid + 512));
}

// one fragment = one b128 read
static __device__ __forceinline__ short8v load_frag4(const unsigned* P, int ksg, int pos) {
  FragU f;
  f.q = *(const uint4*)(P + (((ksg << 7) + pos) << 2));
  return f.v;
}

// reg-staged fp32 operand: issue loads (early) ...
static __device__ __forceinline__ void xload16(const float* __restrict__ src, int ld,
                                               int tid, float v[16]) {
  const int pos = tid & 127, kg = tid >> 7;
  const float* p = src + pos + (size_t)(kg * 16) * ld;
#pragma unroll
  for (int i = 0; i < 16; ++i) v[i] = p[(size_t)i * ld];
}
// ... pack + LDS write (late)
static __device__ __forceinline__ void xwrite16(const float v[16], unsigned* Xp, int tid) {
  const int pos = tid & 127, kg = tid >> 7;
#pragma unroll
  for (int i2 = 0; i2 < 4; ++i2) {
    const int kq = kg * 4 + i2;
    const int r4 = (kq & 3) + ((kq >> 3) << 2);
    const int sub = (kq >> 2) & 1;
    uint2 wv;
    wv.x = packbf(v[i2 * 4 + 0], v[i2 * 4 + 1]);
    wv.y = packbf(v[i2 * 4 + 2], v[i2 * 4 + 3]);
    *(uint2*)(Xp + (((r4 << 7) + pos) << 2) + sub * 2) = wv;
  }
}

// legacy single-shot pack-stage (attn Q)
static __device__ __forceinline__ void stage_x_pack(const float* __restrict__ src, int ld,
                                                    unsigned* Xp, int tid) {
  float v[16];
  xload16(src, ld, tid, v);
  xwrite16(v, Xp, tid);
}

#define GEMM_IDS                                            \
  const int tid = threadIdx.x;                              \
  const int w = tid >> 6, lane = tid & 63;                  \
  const int g = lane >> 4, nl = lane & 15;                  \
  const int wr = w >> 1, wc = w & 1;

#define GEMM_KSTEP_B(ACC, XB, WB)                                                  \
  _Pragma("unroll")                                                                \
  for (int ks = 0; ks < 2; ++ks) {                                                 \
    const short8v a0 = load_frag4(WB, ks * 4 + g, wr * 32 + nl);                   \
    const short8v a1 = load_frag4(WB, ks * 4 + g, wr * 32 + 16 + nl);              \
    _Pragma("unroll")                                                              \
    for (int jj = 0; jj < 4; ++jj) {                                               \
      const short8v bfr = load_frag4(XB, ks * 4 + g, wc * 64 + jj * 16 + nl);      \
      ACC[0][jj] = __builtin_amdgcn_mfma_f32_16x16x32_bf16(a0, bfr, ACC[0][jj], 0, 0, 0); \
      ACC[1][jj] = __builtin_amdgcn_mfma_f32_16x16x32_bf16(a1, bfr, ACC[1][jj], 0, 0, 0); \
    }                                                                              \
  }

// ---------------------------------------------------------------------------
// Weight prepack: fp32 W[OC][K] -> img tiles (tile = to*(K/64)+tk).
__global__ __launch_bounds__(256)
void prepack_w_kernel(const float* __restrict__ w01, const float* __restrict__ w03,
                      const float* __restrict__ w13, const float* __restrict__ w23,
                      const float* __restrict__ w3, const float* __restrict__ wkv,
                      unsigned* __restrict__ img)
{
  const int t = blockIdx.x;
  const float* W; int K; int tile; unsigned* base;
  if (t < 8)       { W = w01; K = 512; tile = t;      base = img; }
  else if (t < 16) { W = w03; K = 128; tile = t - 8;  base = img + 32768; }
  else if (t < 24) { W = w13; K = 128; tile = t - 16; base = img + 65536; }
  else if (t < 32) { W = w23; K = 128; tile = t - 24; base = img + 98304; }
  else if (t < 64) { W = w3;  K = 512; tile = t - 32; base = img + 131072; }
  else             { W = wkv; K = 512; tile = t - 64; base = img + 262144; }
  const int nk = K >> 6;
  const int to = tile / nk, tk = tile - to * nk;
  unsigned* dst = base + (size_t)tile * 4096;
  for (int wi = threadIdx.x; wi < 4096; wi += 256) {
    const int r4 = wi >> 9, pos = (wi >> 2) & 127, sub = (wi >> 1) & 1, j = wi & 1;
    const int kq = (r4 & 3) + sub * 4 + ((r4 >> 2) << 3);
    const int k = tk * 64 + 4 * kq + 2 * j;
    const int oc = to * 128 + pos;
    dst[wi] = packbf(W[(size_t)oc * K + k], W[(size_t)oc * K + k + 1]);
  }
}

// ---------------------------------------------------------------------------
// a01 = silu(s01*(w01@x)+b01) as packed bf16 pairs A01p[b][c2][p].
// 2-phase: x reg-staged (issue-early/write-late), W via global_load_lds dbuf.
__global__ __launch_bounds__(512)
void gemm_a01_kernel(const float* __restrict__ X, const unsigned* __restrict__ Wimg,
                     const float* __restrict__ sc, const float* __restrict__ bi,
                     unsigned* __restrict__ A01p)
{
  const int b = blockIdx.z, p0 = blockIdx.x * 128;
  GEMM_IDS
  __shared__ unsigned Xp[2][4096], Wp[2][4096];
  const float* Xbase = X + (size_t)b * 512 * 4096 + p0;

  f32x4 acc[2][4];
#pragma unroll
  for (int i = 0; i < 2; ++i)
#pragma unroll
    for (int jj = 0; jj < 4; ++jj) acc[i][jj] = (f32x4){0.f, 0.f, 0.f, 0.f};

  {
    float vx[16];
    xload16(Xbase, 4096, tid, vx);
    stage_tile_g(Wimg, Wp[0], tid);
    xwrite16(vx, Xp[0], tid);
  }
  __syncthreads();

  for (int st = 0; st < 8; ++st) {
    const int cur = st & 1;
    float vn[16];
    if (st < 7) {
      xload16(Xbase + (size_t)((st + 1) * 64) * 4096, 4096, tid, vn);
      stage_tile_g(Wimg + (size_t)(st + 1) * 4096, Wp[cur ^ 1], tid);
    }
    GEMM_KSTEP_B(acc, Xp[cur], Wp[cur])
    if (st < 7) xwrite16(vn, Xp[cur ^ 1], tid);
    __syncthreads();
  }

#pragma unroll
  for (int i = 0; i < 2; ++i) {
    const int base = wr * 32 + i * 16 + 4 * g;
    const float s0_ = sc[base + 0], b0_ = bi[base + 0];
    const float s1_ = sc[base + 1], b1_ = bi[base + 1];
    const float s2_ = sc[base + 2], b2_ = bi[base + 2];
    const float s3_ = sc[base + 3], b3_ = bi[base + 3];
#pragma unroll
    for (int jj = 0; jj < 4; ++jj) {
      const int pos = p0 + wc * 64 + jj * 16 + nl;
      const float v0 = silu_f(s0_ * acc[i][jj][0] + b0_);
      const float v1 = silu_f(s1_ * acc[i][jj][1] + b1_);
      const float v2 = silu_f(s2_ * acc[i][jj][2] + b2_);
      const float v3 = silu_f(s3_ * acc[i][jj][3] + b3_);
      A01p[((size_t)b * 64 + (base >> 1)) * 4096 + pos]     = packbf(v0, v1);
      A01p[((size_t)b * 64 + (base >> 1) + 1) * 4096 + pos] = packbf(v2, v3);
    }
  }
}

// ---------------------------------------------------------------------------
// Depthwise dilated 3x3 + SiLU on packed a01; writes T img tiles directly.
__global__ __launch_bounds__(256)
void dwconv_pack_kernel(const unsigned* __restrict__ A01p, unsigned* __restrict__ Timg,
                        const float* __restrict__ w02, const float* __restrict__ s02, const float* __restrict__ b02,
                        const float* __restrict__ w12, const float* __restrict__ s12, const float* __restrict__ b12,
                        const float* __restrict__ w22, const float* __restrict__ s22, const float* __restrict__ b22)
{
  const int br = blockIdx.z;
  const int yb = blockIdx.y;
  const int b = yb >> 4, t16 = yb & 15, kstep = t16 >> 3, mm = t16 & 7;
  const int kq = (mm & 3) + ((mm >> 2) << 3);
  const int cbase = kstep * 64 + kq * 4;
  const int p = blockIdx.x * 256 + threadIdx.x;
  const int y = p >> 6, xx = p & 63;
  const int d = 3 + 2 * br;

  const float* wsel = br == 0 ? w02 : (br == 1 ? w12 : w22);
  const float* ssel = br == 0 ? s02 : (br == 1 ? s12 : s22);
  const float* bsel = br == 0 ? b02 : (br == 1 ? b12 : b22);

  float sum[8] = {};
  const unsigned* plane0 = A01p + ((size_t)b * 64 + (cbase >> 1)) * 4096;

#pragma unroll
  for (int u = -1; u <= 1; ++u) {
    const int yv = y + u * d;
    if ((unsigned)yv < 64u) {
#pragma unroll
      for (int v = -1; v <= 1; ++v) {
        const int xv = xx + v * d;
        if ((unsigned)xv < 64u) {
          const int idx = yv * 64 + xv;
          const int tap = (u + 1) * 3 + (v + 1);
#pragma unroll
          for (int q = 0; q < 4; ++q) {
            const int sub = q >> 1, jw = q & 1;
            const unsigned wv = plane0[(size_t)(sub * 8 + jw) * 4096 + idx];
            const int ch = cbase + sub * 16 + jw * 2;
            sum[q * 2 + 0] += wsel[(ch + 0) * 9 + tap] * bf_lo(wv);
            sum[q * 2 + 1] += wsel[(ch + 1) * 9 + tap] * bf_hi(wv);
          }
        }
      }
    }
  }

  unsigned wout[4];
#pragma unroll
  for (int h = 0; h < 4; ++h) {
    const int ch = cbase + (h >> 1) * 16 + (h & 1) * 2;
    const float va = silu_f(ssel[ch] * sum[h * 2] + bsel[ch]);
    const float vb = silu_f(ssel[ch + 1] * sum[h * 2 + 1] + bsel[ch + 1]);
    wout[h] = packbf(va, vb);
  }
  const int tile = ((br * 8 + b) * 2 + kstep) * 32 + (p >> 7);
  *(uint4*)(Timg + (size_t)tile * 4096 + (((mm << 7) + (p & 127)) << 2)) = *(uint4*)wout;
}

// ---------------------------------------------------------------------------
// B = sum_i silu(s_i*(W_i @ t_i)+b_i), 2-phase dbuf over 6 staged steps.
__global__ __launch_bounds__(512)
void gemm3branch_img_kernel(const unsigned* __restrict__ Timg, const unsigned* __restrict__ Wimg3,
                            const float* __restrict__ s0, const float* __restrict__ s1, const float* __restrict__ s2,
                            const float* __restrict__ b0, const float* __restrict__ b1, const float* __restrict__ b2,
                            unsigned* __restrict__ Bimg)
{
  const int b = blockIdx.z, pt = blockIdx.x, oc0 = blockIdx.y * 128;
  GEMM_IDS
  __shared__ unsigned Xp[2][4096], Wp[2][4096];

  float sum[2][4][4] = {};
  f32x4 acc[2][4];
#pragma unroll
  for (int i = 0; i < 2; ++i)
#pragma unroll
    for (int jj = 0; jj < 4; ++jj) acc[i][jj] = (f32x4){0.f, 0.f, 0.f, 0.f};

#define SRC_X3(st) (Timg + (((size_t)(((st) >> 1) * 8 + b) * 2 + ((st) & 1)) * 32 + pt) * 4096)
#define SRC_W3(st) (Wimg3 + (size_t)((st) >> 1) * 32768 + ((size_t)(oc0 >> 7) * 2 + ((st) & 1)) * 4096)

  stage_tile_g(SRC_X3(0), Xp[0], tid);
  stage_tile_g(SRC_W3(0), Wp[0], tid);
  __syncthreads();

  for (int st = 0; st < 6; ++st) {
    const int cur = st & 1;
    if (st < 5) {
      stage_tile_g(SRC_X3(st + 1), Xp[cur ^ 1], tid);
      stage_tile_g(SRC_W3(st + 1), Wp[cur ^ 1], tid);
    }
    GEMM_KSTEP_B(acc, Xp[cur], Wp[cur])
    if (st & 1) {
      const int brn = st >> 1;
      const float* ss = brn == 0 ? s0 : (brn == 1 ? s1 : s2);
      const float* bs = brn == 0 ? b0 : (brn == 1 ? b1 : b2);
#pragma unroll
      for (int i = 0; i < 2; ++i) {
        const int base = oc0 + wr * 32 + i * 16 + 4 * g;
#pragma unroll
        for (int r = 0; r < 4; ++r) {
          const float s = ss[base + r], bb = bs[base + r];
#pragma unroll
          for (int jj = 0; jj < 4; ++jj) {
            sum[i][jj][r] += silu_f(s * acc[i][jj][r] + bb);
            acc[i][jj][r] = 0.f;
          }
        }
      }
    }
    __syncthreads();
  }
#undef SRC_X3
#undef SRC_W3

#pragma unroll
  for (int i = 0; i < 2; ++i) {
    const int ol = wr * 32 + i * 16 + 4 * g;
    const int kstep_g = (oc0 + ol) >> 6;
    const int kin = ol & 63;
    const int kq2 = kin >> 2;
    const int r4 = (kq2 & 3) + ((kq2 >> 3) << 2);
    const int sub = (kq2 >> 2) & 1;
#pragma unroll
    for (int jj = 0; jj < 4; ++jj) {
      const int pos = wc * 64 + jj * 16 + nl;
      uint2 wv;
      wv.x = packbf(sum[i][jj][0], sum[i][jj][1]);
      wv.y = packbf(sum[i][jj][2], sum[i][jj][3]);
      *(uint2*)(Bimg + ((size_t)(b * 8 + kstep_g) * 32 + pt) * 4096 + (((r4 << 7) + pos) << 2) + sub * 2) = wv;
    }
  }
}

// ---------------------------------------------------------------------------
// w3 GEMM (512->512) from B img + fused silu*x + 4x4 pool, 2-phase dbuf.
__global__ __launch_bounds__(512)
void gemm_pool_img_kernel(const unsigned* __restrict__ Bimg, const unsigned* __restrict__ W3img,
                          const float* __restrict__ sc, const float* __restrict__ bi,
                          const float* __restrict__ xin, float* __restrict__ pooled)
{
  const int b = blockIdx.z, pt = blockIdx.x, oc0 = blockIdx.y * 128;
  const int p0 = pt * 128;
  const float* xb = xin + (size_t)b * 512 * 4096;
  GEMM_IDS
  __shared__ unsigned Xp[2][4096], Wp[2][4096];

  f32x4 acc[2][4];
#pragma unroll
  for (int i = 0; i < 2; ++i)
#pragma unroll
    for (int jj = 0; jj < 4; ++jj) acc[i][jj] = (f32x4){0.f, 0.f, 0.f, 0.f};

#define SRC_XP(st) (Bimg + ((size_t)(b * 8 + (st)) * 32 + pt) * 4096)
#define SRC_WP(st) (W3img + ((size_t)(oc0 >> 7) * 8 + (st)) * 4096)

  stage_tile_g(SRC_XP(0), Xp[0], tid);
  stage_tile_g(SRC_WP(0), Wp[0], tid);
  __syncthreads();

  for (int st = 0; st < 8; ++st) {
    const int cur = st & 1;
    if (st < 7) {
      stage_tile_g(SRC_XP(st + 1), Xp[cur ^ 1], tid);
      stage_tile_g(SRC_WP(st + 1), Wp[cur ^ 1], tid);
    }
    GEMM_KSTEP_B(acc, Xp[cur], Wp[cur])
    __syncthreads();
  }
#undef SRC_XP
#undef SRC_WP

#pragma unroll
  for (int i = 0; i < 2; ++i)
#pragma unroll
    for (int r = 0; r < 4; ++r) {
      const int oc = oc0 + wr * 32 + i * 16 + 4 * g + r;
      const float s = sc[oc], bb = bi[oc];
#pragma unroll
      for (int jj = 0; jj < 4; ++jj) {
        const int p = p0 + wc * 64 + jj * 16 + nl;
        float val = silu_f(s * acc[i][jj][r] + bb) * xb[(size_t)oc * 4096 + p];
        val += __shfl_xor(val, 1, 64);
        val += __shfl_xor(val, 2, 64);
        if ((nl & 3) == 0) {
          const int y = p >> 6, col = p & 63;
          atomicAdd(&pooled[((size_t)b * 512 + oc) * 256 + (y >> 2) * 16 + (col >> 2)],
                    val * (1.f / 16.f));
        }
      }
    }
}

// ---------------------------------------------------------------------------
// kv GEMM (pooled fp32 -> K img + V PV-layout tiles), 2-phase dbuf.
__global__ __launch_bounds__(512)
void gemm_kv_kernel(const float* __restrict__ X, const unsigned* __restrict__ WKVimg,
                    const float* __restrict__ sc, const float* __restrict__ bi,
                    unsigned* __restrict__ Kimg, unsigned* __restrict__ Vimg)
{
  const int b = blockIdx.z, p0 = blockIdx.x * 128, oc0 = blockIdx.y * 128;
  const float* Xb = X + (size_t)b * 512 * 256 + p0;
  GEMM_IDS
  __shared__ unsigned Xp[2][4096], Wp[2][4096];

  f32x4 acc[2][4];
#pragma unroll
  for (int i = 0; i < 2; ++i)
#pragma unroll
    for (int jj = 0; jj < 4; ++jj) acc[i][jj] = (f32x4){0.f, 0.f, 0.f, 0.f};

  {
    float vx[16];
    xload16(Xb, 256, tid, vx);
    stage_tile_g(WKVimg + (size_t)(oc0 >> 7) * 8 * 4096, Wp[0], tid);
    xwrite16(vx, Xp[0], tid);
  }
  __syncthreads();

  for (int st = 0; st < 8; ++st) {
    const int cur = st & 1;
    float vn[16];
    if (st < 7) {
      xload16(Xb + (size_t)((st + 1) * 64) * 256, 256, tid, vn);
      stage_tile_g(WKVimg + ((size_t)(oc0 >> 7) * 8 + st + 1) * 4096, Wp[cur ^ 1], tid);
    }
    GEMM_KSTEP_B(acc, Xp[cur], Wp[cur])
    if (st < 7) xwrite16(vn, Xp[cur ^ 1], tid);
    __syncthreads();
  }

  const bool isK = (oc0 < 512);
#pragma unroll
  for (int i = 0; i < 2; ++i) {
    const int ocb = oc0 + wr * 32 + i * 16 + 4 * g;
#pragma unroll
    for (int jj = 0; jj < 4; ++jj) {
      const int pos = p0 + wc * 64 + jj * 16 + nl;
      float v[4];
#pragma unroll
      for (int r = 0; r < 4; ++r)
        v[r] = silu_f(sc[ocb + r] * acc[i][jj][r] + bi[ocb + r]);
      const int ch = pos >> 7, ml = pos & 127;
      if (isK) {
        const int h = ocb >> 6, d0 = ocb & 63;
        const int kq = d0 >> 2, sub = (kq >> 2) & 1;
        const int r4 = (kq & 3) + ((kq >> 3) << 2);
        unsigned* t = Kimg + ((size_t)(b * 8 + h) * 2 + ch) * 4096;
        uint2 wv;
        wv.x = packbf(v[0] * 0.125f, v[1] * 0.125f);
        wv.y = packbf(v[2] * 0.125f, v[3] * 0.125f);
        *(uint2*)(t + (((r4 << 7) + ml) << 2) + sub * 2) = wv;
      } else {
        const int h = (ocb - 512) >> 6, d0 = (ocb - 512) & 63;
        unsigned* t = Vimg + ((size_t)(b * 8 + h) * 2 + ch) * 4096;
        float ov[4];
#pragma unroll
        for (int r = 0; r < 4; ++r) ov[r] = __shfl_xor(v[r], 1, 64);
        if ((nl & 1) == 0) {
          const int s = (ml >> 1) & 1, m4 = ml >> 2;
#pragma unroll
          for (int r = 0; r < 4; ++r)
            t[((m4 * 64 + d0 + r) << 1) + s] = packbf(v[r], ov[r]);
        }
      }
    }
  }
}

// ---------------------------------------------------------------------------
__global__ __launch_bounds__(256)
void gap_kernel(const float* __restrict__ x, float* __restrict__ gap)
{
  const int bc = blockIdx.x;
  const int tid = threadIdx.x;
  const float* p = x + (size_t)bc * 4096;
  float v = 0.f;
#pragma unroll
  for (int j = 0; j < 16; ++j) v += p[j * 256 + tid];
#pragma unroll
  for (int off = 32; off >= 1; off >>= 1) v += __shfl_down(v, off, 64);
  __shared__ float red[4];
  if ((tid & 63) == 0) red[tid >> 6] = v;
  __syncthreads();
  if (tid == 0) gap[bc] = (red[0] + red[1] + red[2] + red[3]) * (1.f / 4096.f);
}

// ---------------------------------------------------------------------------
__global__ __launch_bounds__(512)
void se_kernel(const float* __restrict__ gap,
               const float* __restrict__ wfc1, const float* __restrict__ bfc1,
               const float* __restrict__ wfc2, const float* __restrict__ bfc2,
               float* __restrict__ gate)
{
  const int b = blockIdx.x, tid = threadIdx.x;
  __shared__ float ylds[128];
  if (tid < 128) {
    float a = 0.f;
    for (int c = 0; c < 512; ++c) a += gap[b * 512 + c] * wfc1[tid * 512 + c];
    a += bfc1[tid];
    ylds[tid] = fminf(fmaxf(a, 0.f), 6.f);
  }
  __syncthreads();
  float g = 0.f;
  for (int j = 0; j < 128; ++j) g += ylds[j] * wfc2[tid * 128 + j];
  g += bfc2[tid];
  gate[b * 512 + tid] = 1.f / (1.f + __expf(-g));
}

// ---------------------------------------------------------------------------
// MFMA bf16 attention v3 (unchanged from round 5, verified).
__global__ __launch_bounds__(512)
void attn_mfma_kernel(const float* __restrict__ x, const unsigned* __restrict__ Kimg,
                      const unsigned* __restrict__ Vimg,
                      const float* __restrict__ gate, float* __restrict__ out)
{
  const int b = blockIdx.z, h = blockIdx.y;
  const int n0 = blockIdx.x * 128;
  const int tid = threadIdx.x;
  const int w = tid >> 6, lane = tid & 63;
  const int g = lane >> 4, nl = lane & 15;

  __shared__ unsigned lds[20480];          // Qp | K0 | K1 | V0 | V1 (80 KB)
  unsigned* Qp = lds;
  unsigned* Kb0 = lds + 4096;
  unsigned* Kb1 = lds + 8192;
  unsigned* Vb0 = lds + 12288;
  unsigned* Vb1 = lds + 16384;
  float* Osm = (float*)(lds + 4096);       // [64][132] overlay

  const size_t tbase = (size_t)(b * 8 + h) * 2 * 4096;

  stage_tile_g(Kimg + tbase, Kb0, tid);
  stage_tile_g(Vimg + tbase, Vb0, tid);
  stage_x_pack(x + ((size_t)b * 512 + h * 64) * 4096 + n0, 4096, Qp, tid);
  __syncthreads();
  stage_tile_g(Kimg + tbase + 4096, Kb1, tid);
  stage_tile_g(Vimg + tbase + 4096, Vb1, tid);

  float m_run = -1e30f, l_run = 0.f;
  f32x4 o[4];
#pragma unroll
  for (int i = 0; i < 4; ++i) o[i] = (f32x4){0.f, 0.f, 0.f, 0.f};

#pragma unroll
  for (int ch = 0; ch < 2; ++ch) {
    const unsigned* Kp = ch ? Kb1 : Kb0;
    const unsigned* Vp = ch ? Vb1 : Vb0;

    f32x4 s[8];
#pragma unroll
    for (int mb = 0; mb < 8; ++mb) s[mb] = (f32x4){0.f, 0.f, 0.f, 0.f};
#pragma unroll
    for (int ks = 0; ks < 2; ++ks) {
      const short8v qf = load_frag4(Qp, ks * 4 + g, w * 16 + nl);
#pragma unroll
      for (int mb = 0; mb < 8; ++mb) {
        const short8v kf = load_frag4(Kp, ks * 4 + g, mb * 16 + nl);
        s[mb] = __builtin_amdgcn_mfma_f32_16x16x32_bf16(kf, qf, s[mb], 0, 0, 0);
      }
    }

    float cm = -1e30f;
#pragma unroll
    for (int mb = 0; mb < 8; ++mb)
#pragma unroll
      for (int r = 0; r < 4; ++r) cm = fmaxf(cm, s[mb][r]);
    cm = fmaxf(cm, __shfl_xor(cm, 16, 64));
    cm = fmaxf(cm, __shfl_xor(cm, 32, 64));
    const float mnew = fmaxf(m_run, cm);
    const float corr = __expf(m_run - mnew);
    m_run = mnew;
    float cs = 0.f;
#pragma unroll
    for (int mb = 0; mb < 8; ++mb)
#pragma unroll
      for (int r = 0; r < 4; ++r) {
        const float p = __expf(s[mb][r] - mnew);
        s[mb][r] = p;
        cs += p;
      }
    cs += __shfl_xor(cs, 16, 64);
    cs += __shfl_xor(cs, 32, 64);
    l_run = l_run * corr + cs;
#pragma unroll
    for (int db = 0; db < 4; ++db)
#pragma unroll
      for (int r = 0; r < 4; ++r) o[db][r] *= corr;

#pragma unroll
    for (int ks = 0; ks < 4; ++ks) {
      FragU pf;
      pf.u[0] = packbf(s[2 * ks][0],     s[2 * ks][1]);
      pf.u[1] = packbf(s[2 * ks][2],     s[2 * ks][3]);
      pf.u[2] = packbf(s[2 * ks + 1][0], s[2 * ks + 1][1]);
      pf.u[3] = packbf(s[2 * ks + 1][2], s[2 * ks + 1][3]);
#pragma unroll
      for (int db = 0; db < 4; ++db) {
        FragU vf;
        const uint2 lo = *(const uint2*)(Vp + ((8 * ks + g) * 64 + db * 16 + nl) * 2);
        const uint2 hi = *(const uint2*)(Vp + ((8 * ks + 4 + g) * 64 + db * 16 + nl) * 2);
        vf.u[0] = lo.x; vf.u[1] = lo.y; vf.u[2] = hi.x; vf.u[3] = hi.y;
        o[db] = __builtin_amdgcn_mfma_f32_16x16x32_bf16(vf.v, pf.v, o[db], 0, 0, 0);
      }
    }
    __syncthreads();
  }

  const float inv = 1.f / l_run;
#pragma unroll
  for (int db = 0; db < 4; ++db)
#pragma unroll
    for (int r = 0; r < 4; ++r)
      Osm[(db * 16 + 4 * g + r) * 132 + w * 16 + nl] = o[db][r] * inv;
  __syncthreads();

  {
    const int n = tid & 127, t7 = tid >> 7;
    const int jw = t7 >> 1, half = t7 & 1;
#pragma unroll
    for (int i = 0; i < 16; ++i) {
      const int d = t7 + 4 * i;
      const int r4 = (i & 3) + ((i >> 3) << 2);
      const int sub = (i >> 2) & 1;
      const unsigned xw = Qp[(((r4 << 7) + n) << 2) + sub * 2 + jw];
      const float xv = half ? bf_hi(xw) : bf_lo(xw);
      const int c2 = h * 64 + d;
      const size_t off = ((size_t)b * 512 + c2) * 4096 + n0 + n;
      out[off] = Osm[d * 132 + n] + gate[b * 512 + c2] * xv;
    }
  }
}

// ---------------------------------------------------------------------------
extern "C" void kernel_launch(void* const* d_in, const int* in_sizes, int n_in,
                              void* d_out, int out_size, void* d_ws, size_t ws_size,
                              hipStream_t stream)
{
  const float* x    = (const float*)d_in[0];
  const float* w01  = (const float*)d_in[1];
  const float* s01  = (const float*)d_in[2];
  const float* b01  = (const float*)d_in[3];
  const float* w02  = (const float*)d_in[4];
  const float* s02  = (const float*)d_in[5];
  const float* b02  = (const float*)d_in[6];
  const float* w03  = (const float*)d_in[7];
  const float* s03  = (const float*)d_in[8];
  const float* b03  = (const float*)d_in[9];
  const float* w12  = (const float*)d_in[10];
  const float* s12  = (const float*)d_in[11];
  const float* b12  = (const float*)d_in[12];
  const float* w13  = (const float*)d_in[13];
  const float* s13  = (const float*)d_in[14];
  const float* b13  = (const float*)d_in[15];
  const float* w22  = (const float*)d_in[16];
  const float* s22  = (const float*)d_in[17];
  const float* b22  = (const float*)d_in[18];
  const float* w23  = (const float*)d_in[19];
  const float* s23  = (const float*)d_in[20];
  const float* b23  = (const float*)d_in[21];
  const float* w3   = (const float*)d_in[22];
  const float* s3   = (const float*)d_in[23];
  const float* b3   = (const float*)d_in[24];
  const float* wkv  = (const float*)d_in[25];
  const float* skv  = (const float*)d_in[26];
  const float* bkv  = (const float*)d_in[27];
  const float* wfc1 = (const float*)d_in[28];
  const float* bfc1 = (const float*)d_in[29];
  const float* wfc2 = (const float*)d_in[30];
  const float* bfc2 = (const float*)d_in[31];

  float* out = (float*)d_out;
  unsigned* wsu = (unsigned*)d_ws;

  // ws layout (u32 words):
  unsigned* Timg   = wsu;                        // 1536*4096 = 6,291,456
  float*    pooled = (float*)(wsu + 6291456);    // 1,048,576
  unsigned* Kimg   = wsu + 7340032;              //   524,288
  unsigned* Vimg   = wsu + 7864320;              //   524,288
  float*    gapb   = (float*)(wsu + 8388608);    //     4,096
  float*    gateb  = (float*)(wsu + 8392704);    //     4,096
  unsigned* Wimg   = wsu + 8396800;              //   524,288  (end 8,921,088 w = 34 MiB)

  unsigned* A01p = (unsigned*)d_out;   // [8,64,4096] packed, dead after dwconv
  unsigned* Bimg = (unsigned*)d_out;   // 256 img tiles, dead after pool

  prepack_w_kernel<<<128, 256, 0, stream>>>(w01, w03, w13, w23, w3, wkv, Wimg);
  gemm_a01_kernel<<<dim3(32, 1, 8), 512, 0, stream>>>(x, Wimg, s01, b01, A01p);
  dwconv_pack_kernel<<<dim3(16, 128, 3), 256, 0, stream>>>(A01p, Timg,
      w02, s02, b02, w12, s12, b12, w22, s22, b22);
  gemm3branch_img_kernel<<<dim3(32, 4, 8), 512, 0, stream>>>(Timg, Wimg + 32768,
      s03, s13, s23, b03, b13, b23, Bimg);
  hipMemsetAsync(pooled, 0, (size_t)1048576 * sizeof(float), stream);
  gemm_pool_img_kernel<<<dim3(32, 4, 8), 512, 0, stream>>>(Bimg, Wimg + 131072,
      s3, b3, x, pooled);
  gemm_kv_kernel<<<dim3(2, 8, 8), 512, 0, stream>>>(pooled, Wimg + 262144, skv, bkv, Kimg, Vimg);
  gap_kernel<<<4096, 256, 0, stream>>>(x, gapb);
  se_kernel<<<8, 512, 0, stream>>>(gapb, wfc1, bfc1, wfc2, bfc2, gateb);
  attn_mfma_kernel<<<dim3(32, 8, 8), 512, 0, stream>>>(x, Kimg, Vimg, gateb, out);
}

// Round 7
// 235.949 us; speedup vs baseline: 5.2082x; 1.0864x over previous
//
#include <hip/hip_runtime.h>
#include <cstddef>

// ---------------------------------------------------------------------------
// _Mutilscal_MHSA — round 7: gemm_pool epilogue rewritten atomic-free.
// Each block LDS-reduces its pool contributions (2 image rows) and stores
// them to pooled[pt&1] with plain coalesced stores (disjoint ownership, no
// memset, no device atomics — round 6 showed 33.5 MB of cross-XCD atomic
// RMW write traffic = the hidden 50 us). gemm_kv sums the two partials.
// Everything else identical to round 6.
// ---------------------------------------------------------------------------

static __device__ __forceinline__ float silu_f(float v) {
  return v / (1.f + __expf(-v));
}

typedef __attribute__((ext_vector_type(8))) short short8v;   // bf16x8 frag
typedef __attribute__((ext_vector_type(4))) float f32x4;     // MFMA acc

union FragU { unsigned u[4]; short8v v; uint4 q; };

static __device__ __forceinline__ unsigned short f2bf(float f) {
  unsigned u = __builtin_bit_cast(unsigned, f);
  u += 0x7fffu + ((u >> 16) & 1u);           // round-to-nearest-even
  return (unsigned short)(u >> 16);
}
static __device__ __forceinline__ unsigned packbf(float lo, float hi) {
  return (unsigned)f2bf(lo) | ((unsigned)f2bf(hi) << 16);
}
static __device__ __forceinline__ float bf_lo(unsigned w) {
  return __builtin_bit_cast(float, w << 16);
}
static __device__ __forceinline__ float bf_hi(unsigned w) {
  return __builtin_bit_cast(float, w & 0xffff0000u);
}

// async global->LDS, 16 B per lane (dest wave-linear: base + lane*16)
static __device__ __forceinline__ void gload16(const unsigned* gsrc, unsigned* ldst) {
  __builtin_amdgcn_global_load_lds(
      (const __attribute__((address_space(1))) unsigned*)gsrc,
      (__attribute__((address_space(3))) unsigned*)ldst, 16, 0, 0);
}

// stage one 4096-word img tile via global_load_lds (512 threads, 2x16B each)
static __device__ __forceinline__ void stage_tile_g(const unsigned* __restrict__ src,
                                                    unsigned* dst, int tid) {
  gload16(src + 4 * tid, dst + 4 * tid);
  gload16(src + 4 * (tid + 512), dst + 4 * (tid + 512));
}

// one fragment = one b128 read
static __device__ __forceinline__ short8v load_frag4(const unsigned* P, int ksg, int pos) {
  FragU f;
  f.q = *(const uint4*)(P + (((ksg << 7) + pos) << 2));
  return f.v;
}

// reg-staged fp32 operand: issue loads (early) ...
static __device__ __forceinline__ void xload16(const float* __restrict__ src, int ld,
                                               int tid, float v[16]) {
  const int pos = tid & 127, kg = tid >> 7;
  const float* p = src + pos + (size_t)(kg * 16) * ld;
#pragma unroll
  for (int i = 0; i < 16; ++i) v[i] = p[(size_t)i * ld];
}
// sum of two fp32 arrays (pooled partials)
static __device__ __forceinline__ void xload16_sum2(const float* __restrict__ a,
                                                    const float* __restrict__ b2, int ld,
                                                    int tid, float v[16]) {
  const int pos = tid & 127, kg = tid >> 7;
  const float* pA = a + pos + (size_t)(kg * 16) * ld;
  const float* pB = b2 + pos + (size_t)(kg * 16) * ld;
#pragma unroll
  for (int i = 0; i < 16; ++i) v[i] = pA[(size_t)i * ld] + pB[(size_t)i * ld];
}
// ... pack + LDS write (late)
static __device__ __forceinline__ void xwrite16(const float v[16], unsigned* Xp, int tid) {
  const int pos = tid & 127, kg = tid >> 7;
#pragma unroll
  for (int i2 = 0; i2 < 4; ++i2) {
    const int kq = kg * 4 + i2;
    const int r4 = (kq & 3) + ((kq >> 3) << 2);
    const int sub = (kq >> 2) & 1;
    uint2 wv;
    wv.x = packbf(v[i2 * 4 + 0], v[i2 * 4 + 1]);
    wv.y = packbf(v[i2 * 4 + 2], v[i2 * 4 + 3]);
    *(uint2*)(Xp + (((r4 << 7) + pos) << 2) + sub * 2) = wv;
  }
}

// legacy single-shot pack-stage (attn Q)
static __device__ __forceinline__ void stage_x_pack(const float* __restrict__ src, int ld,
                                                    unsigned* Xp, int tid) {
  float v[16];
  xload16(src, ld, tid, v);
  xwrite16(v, Xp, tid);
}

#define GEMM_IDS                                            \
  const int tid = threadIdx.x;                              \
  const int w = tid >> 6, lane = tid & 63;                  \
  const int g = lane >> 4, nl = lane & 15;                  \
  const int wr = w >> 1, wc = w & 1;

#define GEMM_KSTEP_B(ACC, XB, WB)                                                  \
  _Pragma("unroll")                                                                \
  for (int ks = 0; ks < 2; ++ks) {                                                 \
    const short8v a0 = load_frag4(WB, ks * 4 + g, wr * 32 + nl);                   \
    const short8v a1 = load_frag4(WB, ks * 4 + g, wr * 32 + 16 + nl);              \
    _Pragma("unroll")                                                              \
    for (int jj = 0; jj < 4; ++jj) {                                               \
      const short8v bfr = load_frag4(XB, ks * 4 + g, wc * 64 + jj * 16 + nl);      \
      ACC[0][jj] = __builtin_amdgcn_mfma_f32_16x16x32_bf16(a0, bfr, ACC[0][jj], 0, 0, 0); \
      ACC[1][jj] = __builtin_amdgcn_mfma_f32_16x16x32_bf16(a1, bfr, ACC[1][jj], 0, 0, 0); \
    }                                                                              \
  }

// ---------------------------------------------------------------------------
// Weight prepack: fp32 W[OC][K] -> img tiles (tile = to*(K/64)+tk).
__global__ __launch_bounds__(256)
void prepack_w_kernel(const float* __restrict__ w01, const float* __restrict__ w03,
                      const float* __restrict__ w13, const float* __restrict__ w23,
                      const float* __restrict__ w3, const float* __restrict__ wkv,
                      unsigned* __restrict__ img)
{
  const int t = blockIdx.x;
  const float* W; int K; int tile; unsigned* base;
  if (t < 8)       { W = w01; K = 512; tile = t;      base = img; }
  else if (t < 16) { W = w03; K = 128; tile = t - 8;  base = img + 32768; }
  else if (t < 24) { W = w13; K = 128; tile = t - 16; base = img + 65536; }
  else if (t < 32) { W = w23; K = 128; tile = t - 24; base = img + 98304; }
  else if (t < 64) { W = w3;  K = 512; tile = t - 32; base = img + 131072; }
  else             { W = wkv; K = 512; tile = t - 64; base = img + 262144; }
  const int nk = K >> 6;
  const int to = tile / nk, tk = tile - to * nk;
  unsigned* dst = base + (size_t)tile * 4096;
  for (int wi = threadIdx.x; wi < 4096; wi += 256) {
    const int r4 = wi >> 9, pos = (wi >> 2) & 127, sub = (wi >> 1) & 1, j = wi & 1;
    const int kq = (r4 & 3) + sub * 4 + ((r4 >> 2) << 3);
    const int k = tk * 64 + 4 * kq + 2 * j;
    const int oc = to * 128 + pos;
    dst[wi] = packbf(W[(size_t)oc * K + k], W[(size_t)oc * K + k + 1]);
  }
}

// ---------------------------------------------------------------------------
// a01 = silu(s01*(w01@x)+b01) as packed bf16 pairs A01p[b][c2][p].
__global__ __launch_bounds__(512)
void gemm_a01_kernel(const float* __restrict__ X, const unsigned* __restrict__ Wimg,
                     const float* __restrict__ sc, const float* __restrict__ bi,
                     unsigned* __restrict__ A01p)
{
  const int b = blockIdx.z, p0 = blockIdx.x * 128;
  GEMM_IDS
  __shared__ unsigned Xp[2][4096], Wp[2][4096];
  const float* Xbase = X + (size_t)b * 512 * 4096 + p0;

  f32x4 acc[2][4];
#pragma unroll
  for (int i = 0; i < 2; ++i)
#pragma unroll
    for (int jj = 0; jj < 4; ++jj) acc[i][jj] = (f32x4){0.f, 0.f, 0.f, 0.f};

  {
    float vx[16];
    xload16(Xbase, 4096, tid, vx);
    stage_tile_g(Wimg, Wp[0], tid);
    xwrite16(vx, Xp[0], tid);
  }
  __syncthreads();

  for (int st = 0; st < 8; ++st) {
    const int cur = st & 1;
    float vn[16];
    if (st < 7) {
      xload16(Xbase + (size_t)((st + 1) * 64) * 4096, 4096, tid, vn);
      stage_tile_g(Wimg + (size_t)(st + 1) * 4096, Wp[cur ^ 1], tid);
    }
    GEMM_KSTEP_B(acc, Xp[cur], Wp[cur])
    if (st < 7) xwrite16(vn, Xp[cur ^ 1], tid);
    __syncthreads();
  }

#pragma unroll
  for (int i = 0; i < 2; ++i) {
    const int base = wr * 32 + i * 16 + 4 * g;
    const float s0_ = sc[base + 0], b0_ = bi[base + 0];
    const float s1_ = sc[base + 1], b1_ = bi[base + 1];
    const float s2_ = sc[base + 2], b2_ = bi[base + 2];
    const float s3_ = sc[base + 3], b3_ = bi[base + 3];
#pragma unroll
    for (int jj = 0; jj < 4; ++jj) {
      const int pos = p0 + wc * 64 + jj * 16 + nl;
      const float v0 = silu_f(s0_ * acc[i][jj][0] + b0_);
      const float v1 = silu_f(s1_ * acc[i][jj][1] + b1_);
      const float v2 = silu_f(s2_ * acc[i][jj][2] + b2_);
      const float v3 = silu_f(s3_ * acc[i][jj][3] + b3_);
      A01p[((size_t)b * 64 + (base >> 1)) * 4096 + pos]     = packbf(v0, v1);
      A01p[((size_t)b * 64 + (base >> 1) + 1) * 4096 + pos] = packbf(v2, v3);
    }
  }
}

// ---------------------------------------------------------------------------
// Depthwise dilated 3x3 + SiLU on packed a01; writes T img tiles directly.
__global__ __launch_bounds__(256)
void dwconv_pack_kernel(const unsigned* __restrict__ A01p, unsigned* __restrict__ Timg,
                        const float* __restrict__ w02, const float* __restrict__ s02, const float* __restrict__ b02,
                        const float* __restrict__ w12, const float* __restrict__ s12, const float* __restrict__ b12,
                        const float* __restrict__ w22, const float* __restrict__ s22, const float* __restrict__ b22)
{
  const int br = blockIdx.z;
  const int yb = blockIdx.y;
  const int b = yb >> 4, t16 = yb & 15, kstep = t16 >> 3, mm = t16 & 7;
  const int kq = (mm & 3) + ((mm >> 2) << 3);
  const int cbase = kstep * 64 + kq * 4;
  const int p = blockIdx.x * 256 + threadIdx.x;
  const int y = p >> 6, xx = p & 63;
  const int d = 3 + 2 * br;

  const float* wsel = br == 0 ? w02 : (br == 1 ? w12 : w22);
  const float* ssel = br == 0 ? s02 : (br == 1 ? s12 : s22);
  const float* bsel = br == 0 ? b02 : (br == 1 ? b12 : b22);

  float sum[8] = {};
  const unsigned* plane0 = A01p + ((size_t)b * 64 + (cbase >> 1)) * 4096;

#pragma unroll
  for (int u = -1; u <= 1; ++u) {
    const int yv = y + u * d;
    if ((unsigned)yv < 64u) {
#pragma unroll
      for (int v = -1; v <= 1; ++v) {
        const int xv = xx + v * d;
        if ((unsigned)xv < 64u) {
          const int idx = yv * 64 + xv;
          const int tap = (u + 1) * 3 + (v + 1);
#pragma unroll
          for (int q = 0; q < 4; ++q) {
            const int sub = q >> 1, jw = q & 1;
            const unsigned wv = plane0[(size_t)(sub * 8 + jw) * 4096 + idx];
            const int ch = cbase + sub * 16 + jw * 2;
            sum[q * 2 + 0] += wsel[(ch + 0) * 9 + tap] * bf_lo(wv);
            sum[q * 2 + 1] += wsel[(ch + 1) * 9 + tap] * bf_hi(wv);
          }
        }
      }
    }
  }

  unsigned wout[4];
#pragma unroll
  for (int h = 0; h < 4; ++h) {
    const int ch = cbase + (h >> 1) * 16 + (h & 1) * 2;
    const float va = silu_f(ssel[ch] * sum[h * 2] + bsel[ch]);
    const float vb = silu_f(ssel[ch + 1] * sum[h * 2 + 1] + bsel[ch + 1]);
    wout[h] = packbf(va, vb);
  }
  const int tile = ((br * 8 + b) * 2 + kstep) * 32 + (p >> 7);
  *(uint4*)(Timg + (size_t)tile * 4096 + (((mm << 7) + (p & 127)) << 2)) = *(uint4*)wout;
}

// ---------------------------------------------------------------------------
// B = sum_i silu(s_i*(W_i @ t_i)+b_i), 2-phase dbuf over 6 staged steps.
__global__ __launch_bounds__(512)
void gemm3branch_img_kernel(const unsigned* __restrict__ Timg, const unsigned* __restrict__ Wimg3,
                            const float* __restrict__ s0, const float* __restrict__ s1, const float* __restrict__ s2,
                            const float* __restrict__ b0, const float* __restrict__ b1, const float* __restrict__ b2,
                            unsigned* __restrict__ Bimg)
{
  const int b = blockIdx.z, pt = blockIdx.x, oc0 = blockIdx.y * 128;
  GEMM_IDS
  __shared__ unsigned Xp[2][4096], Wp[2][4096];

  float sum[2][4][4] = {};
  f32x4 acc[2][4];
#pragma unroll
  for (int i = 0; i < 2; ++i)
#pragma unroll
    for (int jj = 0; jj < 4; ++jj) acc[i][jj] = (f32x4){0.f, 0.f, 0.f, 0.f};

#define SRC_X3(st) (Timg + (((size_t)(((st) >> 1) * 8 + b) * 2 + ((st) & 1)) * 32 + pt) * 4096)
#define SRC_W3(st) (Wimg3 + (size_t)((st) >> 1) * 32768 + ((size_t)(oc0 >> 7) * 2 + ((st) & 1)) * 4096)

  stage_tile_g(SRC_X3(0), Xp[0], tid);
  stage_tile_g(SRC_W3(0), Wp[0], tid);
  __syncthreads();

  for (int st = 0; st < 6; ++st) {
    const int cur = st & 1;
    if (st < 5) {
      stage_tile_g(SRC_X3(st + 1), Xp[cur ^ 1], tid);
      stage_tile_g(SRC_W3(st + 1), Wp[cur ^ 1], tid);
    }
    GEMM_KSTEP_B(acc, Xp[cur], Wp[cur])
    if (st & 1) {
      const int brn = st >> 1;
      const float* ss = brn == 0 ? s0 : (brn == 1 ? s1 : s2);
      const float* bs = brn == 0 ? b0 : (brn == 1 ? b1 : b2);
#pragma unroll
      for (int i = 0; i < 2; ++i) {
        const int base = oc0 + wr * 32 + i * 16 + 4 * g;
#pragma unroll
        for (int r = 0; r < 4; ++r) {
          const float s = ss[base + r], bb = bs[base + r];
#pragma unroll
          for (int jj = 0; jj < 4; ++jj) {
            sum[i][jj][r] += silu_f(s * acc[i][jj][r] + bb);
            acc[i][jj][r] = 0.f;
          }
        }
      }
    }
    __syncthreads();
  }
#undef SRC_X3
#undef SRC_W3

#pragma unroll
  for (int i = 0; i < 2; ++i) {
    const int ol = wr * 32 + i * 16 + 4 * g;
    const int kstep_g = (oc0 + ol) >> 6;
    const int kin = ol & 63;
    const int kq2 = kin >> 2;
    const int r4 = (kq2 & 3) + ((kq2 >> 3) << 2);
    const int sub = (kq2 >> 2) & 1;
#pragma unroll
    for (int jj = 0; jj < 4; ++jj) {
      const int pos = wc * 64 + jj * 16 + nl;
      uint2 wv;
      wv.x = packbf(sum[i][jj][0], sum[i][jj][1]);
      wv.y = packbf(sum[i][jj][2], sum[i][jj][3]);
      *(uint2*)(Bimg + ((size_t)(b * 8 + kstep_g) * 32 + pt) * 4096 + (((r4 << 7) + pos) << 2) + sub * 2) = wv;
    }
  }
}

// ---------------------------------------------------------------------------
// w3 GEMM (512->512) from B img + fused silu*x + 4x4 pool.
// ATOMIC-FREE epilogue: LDS-reduce this block's 2 image rows -> plain stores
// into pooled partial buffer selected by pt&1 (disjoint ownership).
__global__ __launch_bounds__(512)
void gemm_pool_img_kernel(const unsigned* __restrict__ Bimg, const unsigned* __restrict__ W3img,
                          const float* __restrict__ sc, const float* __restrict__ bi,
                          const float* __restrict__ xin, float* __restrict__ pooled2)
{
  const int b = blockIdx.z, pt = blockIdx.x, oc0 = blockIdx.y * 128;
  const int p0 = pt * 128;
  const float* xb = xin + (size_t)b * 512 * 4096;
  GEMM_IDS
  __shared__ unsigned Xp[2][4096], Wp[2][4096];

  f32x4 acc[2][4];
#pragma unroll
  for (int i = 0; i < 2; ++i)
#pragma unroll
    for (int jj = 0; jj < 4; ++jj) acc[i][jj] = (f32x4){0.f, 0.f, 0.f, 0.f};

#define SRC_XP(st) (Bimg + ((size_t)(b * 8 + (st)) * 32 + pt) * 4096)
#define SRC_WP(st) (W3img + ((size_t)(oc0 >> 7) * 8 + (st)) * 4096)

  stage_tile_g(SRC_XP(0), Xp[0], tid);
  stage_tile_g(SRC_WP(0), Wp[0], tid);
  __syncthreads();

  for (int st = 0; st < 8; ++st) {
    const int cur = st & 1;
    if (st < 7) {
      stage_tile_g(SRC_XP(st + 1), Xp[cur ^ 1], tid);
      stage_tile_g(SRC_WP(st + 1), Wp[cur ^ 1], tid);
    }
    GEMM_KSTEP_B(acc, Xp[cur], Wp[cur])
    __syncthreads();
  }
#undef SRC_XP
#undef SRC_WP

  // ---- LDS pool reduction: red[128 oc][16 pw] over this block's 2 rows ----
  float* red = (float*)Wp[0];            // 2048 floats, safe after last barrier
  for (int e = tid; e < 2048; e += 512) red[e] = 0.f;
  __syncthreads();

#pragma unroll
  for (int i = 0; i < 2; ++i)
#pragma unroll
    for (int r = 0; r < 4; ++r) {
      const int ol = wr * 32 + i * 16 + 4 * g + r;      // local oc 0..127
      const int oc = oc0 + ol;
      const float s = sc[oc], bb = bi[oc];
#pragma unroll
      for (int jj = 0; jj < 4; ++jj) {
        const int p = p0 + wc * 64 + jj * 16 + nl;
        float val = silu_f(s * acc[i][jj][r] + bb) * xb[(size_t)oc * 4096 + p];
        val += __shfl_xor(val, 1, 64);
        val += __shfl_xor(val, 2, 64);
        if ((nl & 3) == 0) {
          const int col = p & 63;
          atomicAdd(&red[ol * 16 + (col >> 2)], val);   // LDS atomic (XCD-local)
        }
      }
    }
  __syncthreads();

  {
    const int ph = pt >> 1;
    float* pdst = pooled2 + (size_t)(pt & 1) * (8ull * 512 * 256);
    for (int e = tid; e < 2048; e += 512) {
      const int ol = e >> 4, pw = e & 15;
      pdst[((size_t)b * 512 + oc0 + ol) * 256 + ph * 16 + pw] = red[e] * (1.f / 16.f);
    }
  }
}

// ---------------------------------------------------------------------------
// kv GEMM (pooledA+pooledB fp32 -> K img + V PV-layout tiles), 2-phase dbuf.
__global__ __launch_bounds__(512)
void gemm_kv_kernel(const float* __restrict__ pooled2, const unsigned* __restrict__ WKVimg,
                    const float* __restrict__ sc, const float* __restrict__ bi,
                    unsigned* __restrict__ Kimg, unsigned* __restrict__ Vimg)
{
  const int b = blockIdx.z, p0 = blockIdx.x * 128, oc0 = blockIdx.y * 128;
  const float* XbA = pooled2 + (size_t)b * 512 * 256 + p0;
  const float* XbB = XbA + 8ull * 512 * 256;
  GEMM_IDS
  __shared__ unsigned Xp[2][4096], Wp[2][4096];

  f32x4 acc[2][4];
#pragma unroll
  for (int i = 0; i < 2; ++i)
#pragma unroll
    for (int jj = 0; jj < 4; ++jj) acc[i][jj] = (f32x4){0.f, 0.f, 0.f, 0.f};

  {
    float vx[16];
    xload16_sum2(XbA, XbB, 256, tid, vx);
    stage_tile_g(WKVimg + (size_t)(oc0 >> 7) * 8 * 4096, Wp[0], tid);
    xwrite16(vx, Xp[0], tid);
  }
  __syncthreads();

  for (int st = 0; st < 8; ++st) {
    const int cur = st & 1;
    float vn[16];
    if (st < 7) {
      xload16_sum2(XbA + (size_t)((st + 1) * 64) * 256, XbB + (size_t)((st + 1) * 64) * 256,
                   256, tid, vn);
      stage_tile_g(WKVimg + ((size_t)(oc0 >> 7) * 8 + st + 1) * 4096, Wp[cur ^ 1], tid);
    }
    GEMM_KSTEP_B(acc, Xp[cur], Wp[cur])
    if (st < 7) xwrite16(vn, Xp[cur ^ 1], tid);
    __syncthreads();
  }

  const bool isK = (oc0 < 512);
#pragma unroll
  for (int i = 0; i < 2; ++i) {
    const int ocb = oc0 + wr * 32 + i * 16 + 4 * g;
#pragma unroll
    for (int jj = 0; jj < 4; ++jj) {
      const int pos = p0 + wc * 64 + jj * 16 + nl;
      float v[4];
#pragma unroll
      for (int r = 0; r < 4; ++r)
        v[r] = silu_f(sc[ocb + r] * acc[i][jj][r] + bi[ocb + r]);
      const int ch = pos >> 7, ml = pos & 127;
      if (isK) {
        const int h = ocb >> 6, d0 = ocb & 63;
        const int kq = d0 >> 2, sub = (kq >> 2) & 1;
        const int r4 = (kq & 3) + ((kq >> 3) << 2);
        unsigned* t = Kimg + ((size_t)(b * 8 + h) * 2 + ch) * 4096;
        uint2 wv;
        wv.x = packbf(v[0] * 0.125f, v[1] * 0.125f);
        wv.y = packbf(v[2] * 0.125f, v[3] * 0.125f);
        *(uint2*)(t + (((r4 << 7) + ml) << 2) + sub * 2) = wv;
      } else {
        const int h = (ocb - 512) >> 6, d0 = (ocb - 512) & 63;
        unsigned* t = Vimg + ((size_t)(b * 8 + h) * 2 + ch) * 4096;
        float ov[4];
#pragma unroll
        for (int r = 0; r < 4; ++r) ov[r] = __shfl_xor(v[r], 1, 64);
        if ((nl & 1) == 0) {
          const int s = (ml >> 1) & 1, m4 = ml >> 2;
#pragma unroll
          for (int r = 0; r < 4; ++r)
            t[((m4 * 64 + d0 + r) << 1) + s] = packbf(v[r], ov[r]);
        }
      }
    }
  }
}

// ---------------------------------------------------------------------------
__global__ __launch_bounds__(256)
void gap_kernel(const float* __restrict__ x, float* __restrict__ gap)
{
  const int bc = blockIdx.x;
  const int tid = threadIdx.x;
  const float* p = x + (size_t)bc * 4096;
  float v = 0.f;
#pragma unroll
  for (int j = 0; j < 16; ++j) v += p[j * 256 + tid];
#pragma unroll
  for (int off = 32; off >= 1; off >>= 1) v += __shfl_down(v, off, 64);
  __shared__ float red[4];
  if ((tid & 63) == 0) red[tid >> 6] = v;
  __syncthreads();
  if (tid == 0) gap[bc] = (red[0] + red[1] + red[2] + red[3]) * (1.f / 4096.f);
}

// ---------------------------------------------------------------------------
__global__ __launch_bounds__(512)
void se_kernel(const float* __restrict__ gap,
               const float* __restrict__ wfc1, const float* __restrict__ bfc1,
               const float* __restrict__ wfc2, const float* __restrict__ bfc2,
               float* __restrict__ gate)
{
  const int b = blockIdx.x, tid = threadIdx.x;
  __shared__ float ylds[128];
  if (tid < 128) {
    float a = 0.f;
    for (int c = 0; c < 512; ++c) a += gap[b * 512 + c] * wfc1[tid * 512 + c];
    a += bfc1[tid];
    ylds[tid] = fminf(fmaxf(a, 0.f), 6.f);
  }
  __syncthreads();
  float g = 0.f;
  for (int j = 0; j < 128; ++j) g += ylds[j] * wfc2[tid * 128 + j];
  g += bfc2[tid];
  gate[b * 512 + tid] = 1.f / (1.f + __expf(-g));
}

// ---------------------------------------------------------------------------
// MFMA bf16 attention v3 (unchanged, verified).
__global__ __launch_bounds__(512)
void attn_mfma_kernel(const float* __restrict__ x, const unsigned* __restrict__ Kimg,
                      const unsigned* __restrict__ Vimg,
                      const float* __restrict__ gate, float* __restrict__ out)
{
  const int b = blockIdx.z, h = blockIdx.y;
  const int n0 = blockIdx.x * 128;
  const int tid = threadIdx.x;
  const int w = tid >> 6, lane = tid & 63;
  const int g = lane >> 4, nl = lane & 15;

  __shared__ unsigned lds[20480];          // Qp | K0 | K1 | V0 | V1 (80 KB)
  unsigned* Qp = lds;
  unsigned* Kb0 = lds + 4096;
  unsigned* Kb1 = lds + 8192;
  unsigned* Vb0 = lds + 12288;
  unsigned* Vb1 = lds + 16384;
  float* Osm = (float*)(lds + 4096);       // [64][132] overlay

  const size_t tbase = (size_t)(b * 8 + h) * 2 * 4096;

  stage_tile_g(Kimg + tbase, Kb0, tid);
  stage_tile_g(Vimg + tbase, Vb0, tid);
  stage_x_pack(x + ((size_t)b * 512 + h * 64) * 4096 + n0, 4096, Qp, tid);
  __syncthreads();
  stage_tile_g(Kimg + tbase + 4096, Kb1, tid);
  stage_tile_g(Vimg + tbase + 4096, Vb1, tid);

  float m_run = -1e30f, l_run = 0.f;
  f32x4 o[4];
#pragma unroll
  for (int i = 0; i < 4; ++i) o[i] = (f32x4){0.f, 0.f, 0.f, 0.f};

#pragma unroll
  for (int ch = 0; ch < 2; ++ch) {
    const unsigned* Kp = ch ? Kb1 : Kb0;
    const unsigned* Vp = ch ? Vb1 : Vb0;

    f32x4 s[8];
#pragma unroll
    for (int mb = 0; mb < 8; ++mb) s[mb] = (f32x4){0.f, 0.f, 0.f, 0.f};
#pragma unroll
    for (int ks = 0; ks < 2; ++ks) {
      const short8v qf = load_frag4(Qp, ks * 4 + g, w * 16 + nl);
#pragma unroll
      for (int mb = 0; mb < 8; ++mb) {
        const short8v kf = load_frag4(Kp, ks * 4 + g, mb * 16 + nl);
        s[mb] = __builtin_amdgcn_mfma_f32_16x16x32_bf16(kf, qf, s[mb], 0, 0, 0);
      }
    }

    float cm = -1e30f;
#pragma unroll
    for (int mb = 0; mb < 8; ++mb)
#pragma unroll
      for (int r = 0; r < 4; ++r) cm = fmaxf(cm, s[mb][r]);
    cm = fmaxf(cm, __shfl_xor(cm, 16, 64));
    cm = fmaxf(cm, __shfl_xor(cm, 32, 64));
    const float mnew = fmaxf(m_run, cm);
    const float corr = __expf(m_run - mnew);
    m_run = mnew;
    float cs = 0.f;
#pragma unroll
    for (int mb = 0; mb < 8; ++mb)
#pragma unroll
      for (int r = 0; r < 4; ++r) {
        const float p = __expf(s[mb][r] - mnew);
        s[mb][r] = p;
        cs += p;
      }
    cs += __shfl_xor(cs, 16, 64);
    cs += __shfl_xor(cs, 32, 64);
    l_run = l_run * corr + cs;
#pragma unroll
    for (int db = 0; db < 4; ++db)
#pragma unroll
      for (int r = 0; r < 4; ++r) o[db][r] *= corr;

#pragma unroll
    for (int ks = 0; ks < 4; ++ks) {
      FragU pf;
      pf.u[0] = packbf(s[2 * ks][0],     s[2 * ks][1]);
      pf.u[1] = packbf(s[2 * ks][2],     s[2 * ks][3]);
      pf.u[2] = packbf(s[2 * ks + 1][0], s[2 * ks + 1][1]);
      pf.u[3] = packbf(s[2 * ks + 1][2], s[2 * ks + 1][3]);
#pragma unroll
      for (int db = 0; db < 4; ++db) {
        FragU vf;
        const uint2 lo = *(const uint2*)(Vp + ((8 * ks + g) * 64 + db * 16 + nl) * 2);
        const uint2 hi = *(const uint2*)(Vp + ((8 * ks + 4 + g) * 64 + db * 16 + nl) * 2);
        vf.u[0] = lo.x; vf.u[1] = lo.y; vf.u[2] = hi.x; vf.u[3] = hi.y;
        o[db] = __builtin_amdgcn_mfma_f32_16x16x32_bf16(vf.v, pf.v, o[db], 0, 0, 0);
      }
    }
    __syncthreads();
  }

  const float inv = 1.f / l_run;
#pragma unroll
  for (int db = 0; db < 4; ++db)
#pragma unroll
    for (int r = 0; r < 4; ++r)
      Osm[(db * 16 + 4 * g + r) * 132 + w * 16 + nl] = o[db][r] * inv;
  __syncthreads();

  {
    const int n = tid & 127, t7 = tid >> 7;
    const int jw = t7 >> 1, half = t7 & 1;
#pragma unroll
    for (int i = 0; i < 16; ++i) {
      const int d = t7 + 4 * i;
      const int r4 = (i & 3) + ((i >> 3) << 2);
      const int sub = (i >> 2) & 1;
      const unsigned xw = Qp[(((r4 << 7) + n) << 2) + sub * 2 + jw];
      const float xv = half ? bf_hi(xw) : bf_lo(xw);
      const int c2 = h * 64 + d;
      const size_t off = ((size_t)b * 512 + c2) * 4096 + n0 + n;
      out[off] = Osm[d * 132 + n] + gate[b * 512 + c2] * xv;
    }
  }
}

// ---------------------------------------------------------------------------
extern "C" void kernel_launch(void* const* d_in, const int* in_sizes, int n_in,
                              void* d_out, int out_size, void* d_ws, size_t ws_size,
                              hipStream_t stream)
{
  const float* x    = (const float*)d_in[0];
  const float* w01  = (const float*)d_in[1];
  const float* s01  = (const float*)d_in[2];
  const float* b01  = (const float*)d_in[3];
  const float* w02  = (const float*)d_in[4];
  const float* s02  = (const float*)d_in[5];
  const float* b02  = (const float*)d_in[6];
  const float* w03  = (const float*)d_in[7];
  const float* s03  = (const float*)d_in[8];
  const float* b03  = (const float*)d_in[9];
  const float* w12  = (const float*)d_in[10];
  const float* s12  = (const float*)d_in[11];
  const float* b12  = (const float*)d_in[12];
  const float* w13  = (const float*)d_in[13];
  const float* s13  = (const float*)d_in[14];
  const float* b13  = (const float*)d_in[15];
  const float* w22  = (const float*)d_in[16];
  const float* s22  = (const float*)d_in[17];
  const float* b22  = (const float*)d_in[18];
  const float* w23  = (const float*)d_in[19];
  const float* s23  = (const float*)d_in[20];
  const float* b23  = (const float*)d_in[21];
  const float* w3   = (const float*)d_in[22];
  const float* s3   = (const float*)d_in[23];
  const float* b3   = (const float*)d_in[24];
  const float* wkv  = (const float*)d_in[25];
  const float* skv  = (const float*)d_in[26];
  const float* bkv  = (const float*)d_in[27];
  const float* wfc1 = (const float*)d_in[28];
  const float* bfc1 = (const float*)d_in[29];
  const float* wfc2 = (const float*)d_in[30];
  const float* bfc2 = (const float*)d_in[31];

  float* out = (float*)d_out;
  unsigned* wsu = (unsigned*)d_ws;

  // ws layout (u32 words):
  unsigned* Timg    = wsu;                        // 1536*4096 = 6,291,456
  float*    pooled2 = (float*)(wsu + 6291456);    // 2 x 1,048,576 = 2,097,152
  unsigned* Kimg    = wsu + 8388608;              //   524,288
  unsigned* Vimg    = wsu + 8912896;              //   524,288
  float*    gapb    = (float*)(wsu + 9437184);    //     4,096
  float*    gateb   = (float*)(wsu + 9441280);    //     4,096
  unsigned* Wimg    = wsu + 9445376;              //   524,288 (end 9,969,664 w = 38 MiB)

  unsigned* A01p = (unsigned*)d_out;   // [8,64,4096] packed, dead after dwconv
  unsigned* Bimg = (unsigned*)d_out;   // 256 img tiles, dead after pool

  prepack_w_kernel<<<128, 256, 0, stream>>>(w01, w03, w13, w23, w3, wkv, Wimg);
  gemm_a01_kernel<<<dim3(32, 1, 8), 512, 0, stream>>>(x, Wimg, s01, b01, A01p);
  dwconv_pack_kernel<<<dim3(16, 128, 3), 256, 0, stream>>>(A01p, Timg,
      w02, s02, b02, w12, s12, b12, w22, s22, b22);
  gemm3branch_img_kernel<<<dim3(32, 4, 8), 512, 0, stream>>>(Timg, Wimg + 32768,
      s03, s13, s23, b03, b13, b23, Bimg);
  gemm_pool_img_kernel<<<dim3(32, 4, 8), 512, 0, stream>>>(Bimg, Wimg + 131072,
      s3, b3, x, pooled2);
  gemm_kv_kernel<<<dim3(2, 8, 8), 512, 0, stream>>>(pooled2, Wimg + 262144, skv, bkv, Kimg, Vimg);
  gap_kernel<<<4096, 256, 0, stream>>>(x, gapb);
  se_kernel<<<8, 512, 0, stream>>>(gapb, wfc1, bfc1, wfc2, bfc2, gateb);
  attn_mfma_kernel<<<dim3(32, 8, 8), 512, 0, stream>>>(x, Kimg, Vimg, gateb, out);
}